// Round 2
// baseline (6469.376 us; speedup 1.0000x reference)
//
#include <hip/hip_runtime.h>
#include <hip/hip_bf16.h>

static const int kN = 50000;   // nodes
static const int kE = 300000;  // edges
static const int kH = 256;     // hidden
static const int kG = 2048;    // graphs
static const int kT = 19;      // targets

#define BM 128
#define BN 128
#define BK 16

__device__ __forceinline__ float cvt_f(float v) { return v; }
__device__ __forceinline__ float cvt_f(__hip_bfloat16 v) { return __bfloat162float(v); }
__device__ __forceinline__ void st_c(float* p, float v) { *p = v; }
__device__ __forceinline__ void st_c(__hip_bfloat16* p, float v) { *p = __float2bfloat16(v); }

// ---------------------------------------------------------------------------
// Tiled GEMM: C = op( (A [+A2]) @ B ) with optional BN+ReLU on A elements,
// optional bias / C-accumulate / final ReLU. A:[M,K] (lda), B:[K,*] (ldb),
// C:[M,*] (ldc). Template picks dtypes and fused ops at compile time.
// ---------------------------------------------------------------------------
template<typename TA, typename TC, bool HasA2, bool HasBN, bool Accum, bool ReluOut, bool HasBias>
__global__ __launch_bounds__(256) void k_gemm(
    const TA* __restrict__ A, const float* __restrict__ A2, int lda,
    const float* __restrict__ B, int ldb,
    TC* __restrict__ C, int ldc,
    int M, int K,
    const float* __restrict__ bias,
    const float* __restrict__ scl, const float* __restrict__ shf)
{
    const int m0 = blockIdx.x * BM;
    const int n0 = blockIdx.y * BN;

    __shared__ float As[BK][BM + 4];
    __shared__ float Bs[BK][BN];

    const int tid = threadIdx.x;
    const int tx = tid & 15;   // 8 output cols each
    const int ty = tid >> 4;   // 8 output rows each

    float acc[8][8];
#pragma unroll
    for (int i = 0; i < 8; ++i)
#pragma unroll
        for (int j = 0; j < 8; ++j) acc[i][j] = 0.f;

    for (int kt = 0; kt < K; kt += BK) {
        // A tile: 128 rows x 16 k (transposed into LDS)
#pragma unroll
        for (int i = 0; i < 8; ++i) {
            int idx = tid + i * 256;
            int row = idx >> 4;
            int kk  = idx & 15;
            int gm = m0 + row, gk = kt + kk;
            float v = 0.f;
            if (gm < M && gk < K) {
                v = cvt_f(A[(long)gm * lda + gk]);
                if (HasA2) v += A2[(long)gm * lda + gk];
                if (HasBN) v = fmaxf(0.f, fmaf(v, scl[gk], shf[gk]));
            }
            As[kk][row] = v;
        }
        // B tile: 16 k x 128 cols
#pragma unroll
        for (int i = 0; i < 8; ++i) {
            int idx = tid + i * 256;
            int kk  = idx >> 7;
            int col = idx & 127;
            int gk = kt + kk;
            float v = 0.f;
            if (gk < K) v = B[(long)gk * ldb + (n0 + col)];
            Bs[kk][col] = v;
        }
        __syncthreads();

#pragma unroll
        for (int kk = 0; kk < BK; ++kk) {
            float a[8], b[8];
            float4 a0 = *(const float4*)&As[kk][ty * 8];
            float4 a1 = *(const float4*)&As[kk][ty * 8 + 4];
            a[0]=a0.x; a[1]=a0.y; a[2]=a0.z; a[3]=a0.w;
            a[4]=a1.x; a[5]=a1.y; a[6]=a1.z; a[7]=a1.w;
            float4 b0 = *(const float4*)&Bs[kk][tx * 8];
            float4 b1 = *(const float4*)&Bs[kk][tx * 8 + 4];
            b[0]=b0.x; b[1]=b0.y; b[2]=b0.z; b[3]=b0.w;
            b[4]=b1.x; b[5]=b1.y; b[6]=b1.z; b[7]=b1.w;
#pragma unroll
            for (int i = 0; i < 8; ++i)
#pragma unroll
                for (int j = 0; j < 8; ++j)
                    acc[i][j] = fmaf(a[i], b[j], acc[i][j]);
        }
        __syncthreads();
    }

#pragma unroll
    for (int i = 0; i < 8; ++i) {
        int gm = m0 + ty * 8 + i;
        if (gm >= M) break;
#pragma unroll
        for (int j = 0; j < 8; ++j) {
            int gn = n0 + tx * 8 + j;
            float v = acc[i][j];
            if (HasBias) v += bias[gn];
            if (Accum)   v += cvt_f(C[(long)gm * ldc + gn]);
            if (ReluOut) v = fmaxf(v, 0.f);
            st_c(&C[(long)gm * ldc + gn], v);
        }
    }
}

// per-relation scatter, fin=256: one block (256 threads) per edge
__global__ void k_scatter256(float* __restrict__ agg, const float* __restrict__ x,
                             const int* __restrict__ ei, const int* __restrict__ et, int r)
{
    int e = blockIdx.x;
    if (et[e] != r) return;
    int src = ei[e];
    int dst = ei[kE + e];
    int c = threadIdx.x;
    atomicAdd(&agg[((long)dst << 8) + c], x[((long)src << 8) + c]);
}

// per-relation scatter, fin=11: thread = (edge, k) with k padded to 16
__global__ void k_scatter11(float* __restrict__ agg, const float* __restrict__ x,
                            const int* __restrict__ ei, const int* __restrict__ et, int r)
{
    long gid = (long)blockIdx.x * 256 + threadIdx.x;
    int e = (int)(gid >> 4);
    int k = (int)(gid & 15);
    if (e >= kE || k >= 11) return;
    if (et[e] != r) return;
    atomicAdd(&agg[(long)ei[kE + e] * 11 + k], x[(long)ei[e] * 11 + k]);
}

// column sums / sums of squares of bf16 H1 [N,1024]
__global__ void k_colstats(const __hip_bfloat16* __restrict__ h1,
                           float* __restrict__ sums, float* __restrict__ sumsq)
{
    int c4 = threadIdx.x * 4;
    float s[4] = {0,0,0,0}, q[4] = {0,0,0,0};
    for (int v = blockIdx.x; v < kN; v += gridDim.x) {
        const __hip_bfloat162* p = (const __hip_bfloat162*)&h1[(long)v * 1024 + c4];
        __hip_bfloat162 p0 = p[0], p1 = p[1];
        float a = __bfloat162float(p0.x), b = __bfloat162float(p0.y);
        float c = __bfloat162float(p1.x), d = __bfloat162float(p1.y);
        s[0]+=a; q[0]+=a*a; s[1]+=b; q[1]+=b*b;
        s[2]+=c; q[2]+=c*c; s[3]+=d; q[3]+=d*d;
    }
#pragma unroll
    for (int i = 0; i < 4; ++i) {
        atomicAdd(&sums[c4 + i],  s[i]);
        atomicAdd(&sumsq[c4 + i], q[i]);
    }
}

// scale = g*rsqrt(var+eps), shift = bt - mu*scale
__global__ void k_bn_params(const float* __restrict__ sums, const float* __restrict__ sumsq,
                            const float* __restrict__ g, const float* __restrict__ bt,
                            float* __restrict__ scl, float* __restrict__ shf)
{
    int c = blockIdx.x * 256 + threadIdx.x;  // < 1024
    const float invN = 1.0f / (float)kN;
    float mu  = sums[c] * invN;
    float var = sumsq[c] * invN - mu * mu;
    float sc  = g[c] * rsqrtf(var + 1e-5f);
    scl[c] = sc;
    shf[c] = bt[c] - mu * sc;
}

// btt[l] = sb_l + sum_r b2_l[r]
__global__ void k_bias_total(const float* sb0, const float* b20,
                             const float* sb1, const float* b21,
                             const float* sb2, const float* b22,
                             float* __restrict__ btt)
{
    int l = blockIdx.x, j = threadIdx.x;
    const float* sb = (l == 0) ? sb0 : (l == 1) ? sb1 : sb2;
    const float* b2 = (l == 0) ? b20 : (l == 1) ? b21 : b22;
    float v = sb[j];
#pragma unroll
    for (int r = 0; r < 4; ++r) v += b2[r * 256 + j];
    btt[l * 256 + j] = v;
}

// mean-pool accumulate
__global__ void k_pool(const float* __restrict__ h, const int* __restrict__ batch,
                       float* __restrict__ pooled, float* __restrict__ counts)
{
    int v = blockIdx.x;
    int c = threadIdx.x;
    int g = batch[v];
    atomicAdd(&pooled[((long)g << 8) + c], h[((long)v << 8) + c]);
    if (c == 0) atomicAdd(&counts[g], 1.0f);
}

// head: out[g] = (pooled[g]/max(cnt,1)) @ lin_w + lin_b   (one wave per graph)
__global__ __launch_bounds__(64) void k_head(const float* __restrict__ pooled,
                                             const float* __restrict__ counts,
                                             const float* __restrict__ lw,
                                             const float* __restrict__ lb,
                                             float* __restrict__ out)
{
    int g = blockIdx.x;
    int l = threadIdx.x;
    float inv = 1.0f / fmaxf(counts[g], 1.0f);
    float acc[kT];
#pragma unroll
    for (int t = 0; t < kT; ++t) acc[t] = 0.f;
    for (int k = l; k < kH; k += 64) {
        float p = pooled[((long)g << 8) + k] * inv;
#pragma unroll
        for (int t = 0; t < kT; ++t) acc[t] = fmaf(p, lw[k * kT + t], acc[t]);
    }
#pragma unroll
    for (int off = 32; off > 0; off >>= 1)
#pragma unroll
        for (int t = 0; t < kT; ++t) acc[t] += __shfl_down(acc[t], off);
    if (l == 0) {
#pragma unroll
        for (int t = 0; t < kT; ++t) out[(long)g * kT + t] = acc[t] + lb[t];
    }
}

// ---------------------------------------------------------------------------
static void run_layer(const float* xin, int fin,
                      const float* sw, const float* w1,
                      const float* gmm, const float* btm,
                      const float* w2, const float* btt_l,
                      float* agg, float* xout,
                      __hip_bfloat16* h1, float* sums, float* sumsq,
                      float* scl, float* shf,
                      const int* ei, const int* et, hipStream_t stream)
{
    dim3 gg((kN + BM - 1) / BM, 2);

    for (int r = 0; r < 4; ++r) {
        hipMemsetAsync(agg, 0, (size_t)kN * fin * sizeof(float), stream);
        if (fin == 256)
            k_scatter256<<<kE, 256, 0, stream>>>(agg, xin, ei, et, r);
        else
            k_scatter11<<<(kE * 16 + 255) / 256, 256, 0, stream>>>(agg, xin, ei, et, r);
        // H1[:, r*256:+256] = (x+agg_r) @ w1[r]    (b1 cancels in BN)
        k_gemm<float, __hip_bfloat16, true, false, false, false, false>
            <<<gg, 256, 0, stream>>>(xin, agg, fin,
                                     w1 + (long)r * fin * 256, 256,
                                     h1 + (long)r * 256, 1024,
                                     kN, fin, nullptr, nullptr, nullptr);
    }

    hipMemsetAsync(sums, 0, 2 * 1024 * sizeof(float), stream);  // sums+sumsq contiguous
    k_colstats<<<512, 256, 0, stream>>>(h1, sums, sumsq);
    k_bn_params<<<4, 256, 0, stream>>>(sums, sumsq, gmm, btm, scl, shf);

    // xout = x @ sw + (sb + sum_r b2[r])
    k_gemm<float, float, false, false, false, false, true>
        <<<gg, 256, 0, stream>>>(xin, nullptr, fin,
                                 sw, 256,
                                 xout, 256,
                                 kN, fin, btt_l, nullptr, nullptr);

    // xout = relu( xout + relu(BN(H1)) @ w2_flat[1024,256] )
    k_gemm<__hip_bfloat16, float, false, true, true, true, false>
        <<<gg, 256, 0, stream>>>(h1, nullptr, 1024,
                                 w2, 256,
                                 xout, 256,
                                 kN, 1024, nullptr, scl, shf);
}

extern "C" void kernel_launch(void* const* d_in, const int* in_sizes, int n_in,
                              void* d_out, int out_size, void* d_ws, size_t ws_size,
                              hipStream_t stream)
{
    const float* x     = (const float*)d_in[0];
    const int*   ei    = (const int*)d_in[1];
    const int*   et    = (const int*)d_in[2];
    const int*   batch = (const int*)d_in[3];

    const float *sw[3], *sb[3], *w1[3], *gmm[3], *btm[3], *w2[3], *b2[3];
    for (int l = 0; l < 3; ++l) {
        int b = 4 + l * 8;
        sw[l]  = (const float*)d_in[b + 0];
        sb[l]  = (const float*)d_in[b + 1];
        w1[l]  = (const float*)d_in[b + 2];
        // b+3 = b1 (unused: cancels in BN)
        gmm[l] = (const float*)d_in[b + 4];
        btm[l] = (const float*)d_in[b + 5];
        w2[l]  = (const float*)d_in[b + 6];
        b2[l]  = (const float*)d_in[b + 7];
    }
    const float* lin_w = (const float*)d_in[28];
    const float* lin_b = (const float*)d_in[29];
    float* out = (float*)d_out;
    (void)in_sizes; (void)n_in; (void)out_size;

    // ---- workspace layout (byte offsets, ~207 MB total) ----
    char* wsb = (char*)d_ws;
    size_t off = 0;
    float* P      = (float*)(wsb + off); off += (size_t)kN * 256 * 4;   // 51.2 MB
    float* Q      = (float*)(wsb + off); off += (size_t)kN * 256 * 4;   // 51.2 MB
    __hip_bfloat16* h1 = (__hip_bfloat16*)(wsb + off); off += (size_t)kN * 1024 * 2; // 102.4 MB
    float* sums   = (float*)(wsb + off); off += 1024 * 4;
    float* sumsq  = (float*)(wsb + off); off += 1024 * 4;
    float* scl    = (float*)(wsb + off); off += 1024 * 4;
    float* shf    = (float*)(wsb + off); off += 1024 * 4;
    float* btt    = (float*)(wsb + off); off += 3 * 256 * 4;
    float* pooled = (float*)(wsb + off); off += (size_t)kG * kH * 4;
    float* counts = (float*)(wsb + off); off += kG * 4;
    if (ws_size < off) return;  // diagnostic: clean absmax-fail instead of OOB crash

    k_bias_total<<<3, 256, 0, stream>>>(sb[0], b2[0], sb[1], b2[1], sb[2], b2[2], btt);

    // buffer roles: L1 xin=x,  agg=P, xout=Q
    //               L2 xin=Q,  agg=P, xout=P  (agg dead before xout written)
    //               L3 xin=P,  agg=Q, xout=Q
    run_layer(x,  11,  sw[0], w1[0], gmm[0], btm[0], w2[0], btt + 0,
              P, Q, h1, sums, sumsq, scl, shf, ei, et, stream);
    run_layer(Q,  256, sw[1], w1[1], gmm[1], btm[1], w2[1], btt + 256,
              P, P, h1, sums, sumsq, scl, shf, ei, et, stream);
    run_layer(P,  256, sw[2], w1[2], gmm[2], btm[2], w2[2], btt + 512,
              Q, Q, h1, sums, sumsq, scl, shf, ei, et, stream);

    hipMemsetAsync(pooled, 0, ((size_t)kG * kH + kG) * sizeof(float), stream);
    k_pool<<<kN, 256, 0, stream>>>(Q, batch, pooled, counts);
    k_head<<<kG, 64, 0, stream>>>(pooled, counts, lin_w, lin_b, out);
}

// Round 3
// 2315.194 us; speedup vs baseline: 2.7943x; 2.7943x over previous
//
#include <hip/hip_runtime.h>

static const int kN = 50000;   // nodes
static const int kE = 300000;  // edges
static const int kG = 2048;    // graphs
static const int kT = 19;      // targets

typedef __bf16 bf16;
typedef __bf16 bf16x8 __attribute__((ext_vector_type(8)));
typedef __bf16 bf16x4 __attribute__((ext_vector_type(4)));
typedef float  f32x4  __attribute__((ext_vector_type(4)));

__device__ __forceinline__ float cvt_f(float v) { return v; }
__device__ __forceinline__ float cvt_f(bf16 v)  { return (float)v; }
__device__ __forceinline__ void  st_c(float* p, float v) { *p = v; }
__device__ __forceinline__ void  st_c(bf16* p,  float v) { *p = (bf16)v; }

// ---------------------------------------------------------------------------
// MFMA GEMM (bf16 x bf16 -> fp32):  C = op( A @ Bt^T )
// A:  [M, K] bf16 row-major (K multiple of 64, rows 16B-aligned)
// Bt: [256, K] bf16 row-major  (i.e., B transposed; N fixed at 256)
// Block 256 thr = 4 waves (2x2), 128x128 tile; wave = 64x64 = 4x4 frags of
// 16x16x32. Fragment layouts (m89/m91-verified):
//   A/B: idx = lane&15, k = (lane>>4)*8 + j ;  C/D: row=(lane>>4)*4+reg, col=lane&15
// ---------------------------------------------------------------------------
template<bool HasBias, bool Accum, bool ReluOut, bool StoreBf16>
__global__ __launch_bounds__(256) void k_mfma(
    const bf16* __restrict__ A, const bf16* __restrict__ Bt, int K,
    float* __restrict__ Cf,          // fp32 C in/out, ld 256
    bf16*  __restrict__ Cb, int ldcb,
    int M, const float* __restrict__ bias)
{
    const int tid  = threadIdx.x;
    const int wave = tid >> 6;
    const int lane = tid & 63;
    const int l15  = lane & 15;
    const int lq   = lane >> 4;
    const int m_base = blockIdx.x * 128 + (wave & 1) * 64;
    const int n_base = blockIdx.y * 128 + (wave >> 1) * 64;
    const int koff = lq * 8;

    const bf16* Ap[4];
#pragma unroll
    for (int i = 0; i < 4; ++i) {
        int gm = m_base + i * 16 + l15;
        if (gm >= M) gm = M - 1;              // clamp: safe read, store is guarded
        Ap[i] = A + (long)gm * K + koff;
    }
    const bf16* Bp[4];
#pragma unroll
    for (int j = 0; j < 4; ++j)
        Bp[j] = Bt + (long)(n_base + j * 16 + l15) * K + koff;

    f32x4 acc[4][4];
#pragma unroll
    for (int i = 0; i < 4; ++i)
#pragma unroll
        for (int j = 0; j < 4; ++j) acc[i][j] = (f32x4){0.f, 0.f, 0.f, 0.f};

    bf16x8 a0[4], b0[4], a1[4], b1[4];
#pragma unroll
    for (int i = 0; i < 4; ++i) a0[i] = *(const bf16x8*)(Ap[i]);
#pragma unroll
    for (int j = 0; j < 4; ++j) b0[j] = *(const bf16x8*)(Bp[j]);

    for (int kt = 0; kt < K; kt += 64) {
#pragma unroll
        for (int i = 0; i < 4; ++i) a1[i] = *(const bf16x8*)(Ap[i] + kt + 32);
#pragma unroll
        for (int j = 0; j < 4; ++j) b1[j] = *(const bf16x8*)(Bp[j] + kt + 32);
#pragma unroll
        for (int i = 0; i < 4; ++i)
#pragma unroll
            for (int j = 0; j < 4; ++j)
                acc[i][j] = __builtin_amdgcn_mfma_f32_16x16x32_bf16(a0[i], b0[j], acc[i][j], 0, 0, 0);
        int k2 = kt + 64; if (k2 >= K) k2 = 0;   // dummy last prefetch
#pragma unroll
        for (int i = 0; i < 4; ++i) a0[i] = *(const bf16x8*)(Ap[i] + k2);
#pragma unroll
        for (int j = 0; j < 4; ++j) b0[j] = *(const bf16x8*)(Bp[j] + k2);
#pragma unroll
        for (int i = 0; i < 4; ++i)
#pragma unroll
            for (int j = 0; j < 4; ++j)
                acc[i][j] = __builtin_amdgcn_mfma_f32_16x16x32_bf16(a1[i], b1[j], acc[i][j], 0, 0, 0);
    }

#pragma unroll
    for (int i = 0; i < 4; ++i) {
        int rowb = m_base + i * 16 + lq * 4;
#pragma unroll
        for (int rr = 0; rr < 4; ++rr) {
            int gm = rowb + rr;
            if (gm < M) {
#pragma unroll
                for (int j = 0; j < 4; ++j) {
                    int gn = n_base + j * 16 + l15;
                    float v = acc[i][j][rr];
                    if (HasBias) v += bias[gn];
                    if (Accum)   v += Cf[(long)gm * 256 + gn];
                    if (ReluOut) v = fmaxf(v, 0.f);
                    if (StoreBf16) Cb[(long)gm * ldcb + gn] = (bf16)v;
                    else           Cf[(long)gm * 256 + gn] = v;
                }
            }
        }
    }
}

// ---------------------------------------------------------------------------
// SIMT GEMM (layer-1 small-K only): C = op((A [+A2]) @ B [+bias])
// ---------------------------------------------------------------------------
#define BM 128
#define BN 128
#define BK 16
template<typename TA, typename TC, bool HasA2, bool HasBias>
__global__ __launch_bounds__(256) void k_gemm(
    const TA* __restrict__ A, const float* __restrict__ A2, int lda,
    const float* __restrict__ B, int ldb,
    TC* __restrict__ C, int ldc,
    int M, int K, const float* __restrict__ bias)
{
    const int m0 = blockIdx.x * BM;
    const int n0 = blockIdx.y * BN;
    __shared__ float As[BK][BM + 4];
    __shared__ float Bs[BK][BN];
    const int tid = threadIdx.x;
    const int tx = tid & 15;
    const int ty = tid >> 4;

    float acc[8][8];
#pragma unroll
    for (int i = 0; i < 8; ++i)
#pragma unroll
        for (int j = 0; j < 8; ++j) acc[i][j] = 0.f;

    for (int kt = 0; kt < K; kt += BK) {
#pragma unroll
        for (int i = 0; i < 8; ++i) {
            int idx = tid + i * 256;
            int row = idx >> 4, kk = idx & 15;
            int gm = m0 + row, gk = kt + kk;
            float v = 0.f;
            if (gm < M && gk < K) {
                v = cvt_f(A[(long)gm * lda + gk]);
                if (HasA2) v += A2[(long)gm * lda + gk];
            }
            As[kk][row] = v;
        }
#pragma unroll
        for (int i = 0; i < 8; ++i) {
            int idx = tid + i * 256;
            int kk = idx >> 7, col = idx & 127;
            int gk = kt + kk;
            Bs[kk][col] = (gk < K) ? B[(long)gk * ldb + (n0 + col)] : 0.f;
        }
        __syncthreads();
#pragma unroll
        for (int kk = 0; kk < BK; ++kk) {
            float a[8], b[8];
            float4 A0 = *(const float4*)&As[kk][ty * 8];
            float4 A1 = *(const float4*)&As[kk][ty * 8 + 4];
            a[0]=A0.x; a[1]=A0.y; a[2]=A0.z; a[3]=A0.w; a[4]=A1.x; a[5]=A1.y; a[6]=A1.z; a[7]=A1.w;
            float4 B0 = *(const float4*)&Bs[kk][tx * 8];
            float4 B1 = *(const float4*)&Bs[kk][tx * 8 + 4];
            b[0]=B0.x; b[1]=B0.y; b[2]=B0.z; b[3]=B0.w; b[4]=B1.x; b[5]=B1.y; b[6]=B1.z; b[7]=B1.w;
#pragma unroll
            for (int i = 0; i < 8; ++i)
#pragma unroll
                for (int j = 0; j < 8; ++j) acc[i][j] = fmaf(a[i], b[j], acc[i][j]);
        }
        __syncthreads();
    }
#pragma unroll
    for (int i = 0; i < 8; ++i) {
        int gm = m0 + ty * 8 + i;
        if (gm >= M) break;
#pragma unroll
        for (int j = 0; j < 8; ++j) {
            int gn = n0 + tx * 8 + j;
            float v = acc[i][j];
            if (HasBias) v += bias[gn];
            st_c(&C[(long)gm * ldc + gn], v);
        }
    }
}

// ---------------------------------------------------------------------------
// edge bucketing: elist[r*kE + pos] = e, cnt[r] = count (cnt pre-zeroed)
__global__ void k_bucket(const int* __restrict__ et, int* __restrict__ elist,
                         int* __restrict__ cnt)
{
    __shared__ int lcnt[4], lbase[4];
    int e = blockIdx.x * 256 + threadIdx.x;
    if (threadIdx.x < 4) lcnt[threadIdx.x] = 0;
    __syncthreads();
    int r = 0, pos = 0;
    bool ok = (e < kE);
    if (ok) { r = et[e]; pos = atomicAdd(&lcnt[r], 1); }
    __syncthreads();
    if (threadIdx.x < 4) lbase[threadIdx.x] = atomicAdd(&cnt[threadIdx.x], lcnt[threadIdx.x]);
    __syncthreads();
    if (ok) elist[r * kE + lbase[r] + pos] = e;
}

// per-relation scatter, fin=256: block=256 channels, grid-stride over edges
__global__ void k_scatter_rel(const int* __restrict__ elist, const int* __restrict__ cnt,
                              int r, const int* __restrict__ ei,
                              const float* __restrict__ x, float* __restrict__ agg)
{
    int n = cnt[r];
    const int* lr = elist + r * kE;
    int c = threadIdx.x;
    for (int i = blockIdx.x; i < n; i += gridDim.x) {
        int e = lr[i];
        int src = ei[e], dst = ei[kE + e];
        atomicAdd(&agg[(long)dst * 256 + c], x[(long)src * 256 + c]);
    }
}

// per-relation scatter, fin=11: 16 lanes/edge, 16 edges per block-iter
__global__ void k_scatter_rel11(const int* __restrict__ elist, const int* __restrict__ cnt,
                                int r, const int* __restrict__ ei,
                                const float* __restrict__ x, float* __restrict__ agg)
{
    int n = cnt[r];
    const int* lr = elist + r * kE;
    int lane = threadIdx.x & 15;
    int sub  = threadIdx.x >> 4;
    for (int i = blockIdx.x * 16 + sub; i < n; i += gridDim.x * 16) {
        int e = lr[i];
        int src = ei[e], dst = ei[kE + e];
        if (lane < 11)
            atomicAdd(&agg[(long)dst * 11 + lane], x[(long)src * 11 + lane]);
    }
}

// pack: out_bf16 = bf16(x [+ agg]), float4-vectorized
template<bool HasAgg>
__global__ void k_pack(const float* __restrict__ x, const float* __restrict__ agg,
                       bf16* __restrict__ out, long n4)
{
    long i = (long)blockIdx.x * 256 + threadIdx.x;
    if (i >= n4) return;
    float4 xv = ((const float4*)x)[i];
    if (HasAgg) {
        float4 av = ((const float4*)agg)[i];
        xv.x += av.x; xv.y += av.y; xv.z += av.z; xv.w += av.w;
    }
    bf16x4 o = { (bf16)xv.x, (bf16)xv.y, (bf16)xv.z, (bf16)xv.w };
    ((bf16x4*)out)[i] = o;
}

// in-place BN+ReLU on bf16 h1 [N,1024]
__global__ void k_pack_h1(bf16* __restrict__ h1, const float* __restrict__ scl,
                          const float* __restrict__ shf, long n4)
{
    long i = (long)blockIdx.x * 256 + threadIdx.x;
    if (i >= n4) return;
    int c = (int)((i * 4) & 1023);
    bf16x4 v = ((bf16x4*)h1)[i];
    float4 s = *(const float4*)&scl[c];
    float4 t = *(const float4*)&shf[c];
    bf16x4 o = { (bf16)fmaxf(0.f, fmaf((float)v.x, s.x, t.x)),
                 (bf16)fmaxf(0.f, fmaf((float)v.y, s.y, t.y)),
                 (bf16)fmaxf(0.f, fmaf((float)v.z, s.z, t.z)),
                 (bf16)fmaxf(0.f, fmaf((float)v.w, s.w, t.w)) };
    ((bf16x4*)h1)[i] = o;
}

// weight transpose-pack: in [K,N] fp32 -> out [N,K] bf16
__global__ void k_wt(const float* __restrict__ in, bf16* __restrict__ out, int K, int N)
{
    int i = blockIdx.x * 256 + threadIdx.x;
    if (i >= K * N) return;
    int n = i / K, k = i - n * K;
    out[i] = (bf16)in[(long)k * N + n];
}

// column sums / sumsq of bf16 h1 [N,1024]
__global__ void k_colstats(const bf16* __restrict__ h1,
                           float* __restrict__ sums, float* __restrict__ sumsq)
{
    int c4 = threadIdx.x * 4;
    float s[4] = {0,0,0,0}, q[4] = {0,0,0,0};
    for (int v = blockIdx.x; v < kN; v += gridDim.x) {
        bf16x4 w = *(const bf16x4*)&h1[(long)v * 1024 + c4];
        float a = (float)w.x, b = (float)w.y, c = (float)w.z, d = (float)w.w;
        s[0]+=a; q[0]+=a*a; s[1]+=b; q[1]+=b*b;
        s[2]+=c; q[2]+=c*c; s[3]+=d; q[3]+=d*d;
    }
#pragma unroll
    for (int i = 0; i < 4; ++i) {
        atomicAdd(&sums[c4 + i],  s[i]);
        atomicAdd(&sumsq[c4 + i], q[i]);
    }
}

__global__ void k_bn_params(const float* __restrict__ sums, const float* __restrict__ sumsq,
                            const float* __restrict__ g, const float* __restrict__ bt,
                            float* __restrict__ scl, float* __restrict__ shf)
{
    int c = blockIdx.x * 256 + threadIdx.x;
    const float invN = 1.0f / (float)kN;
    float mu  = sums[c] * invN;
    float var = sumsq[c] * invN - mu * mu;
    float sc  = g[c] * rsqrtf(var + 1e-5f);
    scl[c] = sc;
    shf[c] = bt[c] - mu * sc;
}

__global__ void k_bias_total(const float* sb0, const float* b20,
                             const float* sb1, const float* b21,
                             const float* sb2, const float* b22,
                             float* __restrict__ btt)
{
    int l = blockIdx.x, j = threadIdx.x;
    const float* sb = (l == 0) ? sb0 : (l == 1) ? sb1 : sb2;
    const float* b2 = (l == 0) ? b20 : (l == 1) ? b21 : b22;
    float v = sb[j];
#pragma unroll
    for (int r = 0; r < 4; ++r) v += b2[r * 256 + j];
    btt[l * 256 + j] = v;
}

__global__ void k_pool(const float* __restrict__ h, const int* __restrict__ batch,
                       float* __restrict__ pooled, float* __restrict__ counts)
{
    int v = blockIdx.x;
    int c = threadIdx.x;
    int g = batch[v];
    atomicAdd(&pooled[((long)g << 8) + c], h[((long)v << 8) + c]);
    if (c == 0) atomicAdd(&counts[g], 1.0f);
}

__global__ __launch_bounds__(64) void k_head(const float* __restrict__ pooled,
                                             const float* __restrict__ counts,
                                             const float* __restrict__ lw,
                                             const float* __restrict__ lb,
                                             float* __restrict__ out)
{
    int g = blockIdx.x;
    int l = threadIdx.x;
    float inv = 1.0f / fmaxf(counts[g], 1.0f);
    float acc[kT];
#pragma unroll
    for (int t = 0; t < kT; ++t) acc[t] = 0.f;
    for (int k = l; k < 256; k += 64) {
        float p = pooled[((long)g << 8) + k] * inv;
#pragma unroll
        for (int t = 0; t < kT; ++t) acc[t] = fmaf(p, lw[k * kT + t], acc[t]);
    }
#pragma unroll
    for (int off = 32; off > 0; off >>= 1)
#pragma unroll
        for (int t = 0; t < kT; ++t) acc[t] += __shfl_down(acc[t], off);
    if (l == 0) {
#pragma unroll
        for (int t = 0; t < kT; ++t) out[(long)g * kT + t] = acc[t] + lb[t];
    }
}

// ---------------------------------------------------------------------------
extern "C" void kernel_launch(void* const* d_in, const int* in_sizes, int n_in,
                              void* d_out, int out_size, void* d_ws, size_t ws_size,
                              hipStream_t stream)
{
    const float* x     = (const float*)d_in[0];
    const int*   ei    = (const int*)d_in[1];
    const int*   et    = (const int*)d_in[2];
    const int*   batch = (const int*)d_in[3];

    const float *sw[3], *sb[3], *w1[3], *gmm[3], *btm[3], *w2[3], *b2[3];
    for (int l = 0; l < 3; ++l) {
        int b = 4 + l * 8;
        sw[l]  = (const float*)d_in[b + 0];
        sb[l]  = (const float*)d_in[b + 1];
        w1[l]  = (const float*)d_in[b + 2];
        // b+3 = b1 (cancels in BN)
        gmm[l] = (const float*)d_in[b + 4];
        btm[l] = (const float*)d_in[b + 5];
        w2[l]  = (const float*)d_in[b + 6];
        b2[l]  = (const float*)d_in[b + 7];
    }
    const float* lin_w = (const float*)d_in[28];
    const float* lin_b = (const float*)d_in[29];
    float* out = (float*)d_out;
    (void)in_sizes; (void)n_in; (void)out_size;

    // ---- workspace (~241 MB) ----
    char* wsb = (char*)d_ws;
    size_t off = 0;
    auto alloc = [&](size_t bytes) { void* p = wsb + off; off = (off + bytes + 255) & ~(size_t)255; return p; };
    float* P      = (float*)alloc((size_t)kN * 256 * 4);       // node features (fp32, in-place)
    float* agg    = (float*)alloc((size_t)kN * 256 * 4);
    bf16*  h1     = (bf16*) alloc((size_t)kN * 1024 * 2);
    bf16*  a16    = (bf16*) alloc((size_t)kN * 256 * 2);       // packed bf16 A operand
    bf16*  w1t    = (bf16*) alloc((size_t)3 * 4 * 65536 * 2);  // [l][r][256,256]
    bf16*  swt    = (bf16*) alloc((size_t)3 * 65536 * 2);
    bf16*  w2t    = (bf16*) alloc((size_t)3 * 262144 * 2);     // [l][256,1024]
    int*   elist  = (int*)  alloc((size_t)4 * kE * 4);
    int*   cnt    = (int*)  alloc(256);
    float* stats  = (float*)alloc(2048 * 4);                   // sums | sumsq
    float* scl    = (float*)alloc(1024 * 4);
    float* shf    = (float*)alloc(1024 * 4);
    float* btt    = (float*)alloc(3 * 256 * 4);
    float* pooled = (float*)alloc((size_t)kG * 256 * 4);
    float* counts = (float*)alloc(kG * 4);
    if (ws_size < off) return;  // clean fail instead of OOB crash

    const dim3 gM((kN + 127) / 128, 2);   // MFMA grid
    const long n4f = (long)kN * 256 / 4;  // feature-sized float4 count
    const int  gF  = (int)((n4f + 255) / 256);
    const long n4h = (long)kN * 1024 / 4;
    const int  gH  = (int)((n4h + 255) / 256);

    // one-time-per-call prep
    hipMemsetAsync(cnt, 0, 256, stream);
    k_bucket<<<(kE + 255) / 256, 256, 0, stream>>>(et, elist, cnt);
    k_bias_total<<<3, 256, 0, stream>>>(sb[0], b2[0], sb[1], b2[1], sb[2], b2[2], btt);
    for (int l = 1; l < 3; ++l) {
        for (int r = 0; r < 4; ++r)
            k_wt<<<(65536 + 255) / 256, 256, 0, stream>>>(w1[l] + (long)r * 65536,
                                                          w1t + (long)l * 4 * 65536 + (long)r * 65536, 256, 256);
        k_wt<<<(65536 + 255) / 256, 256, 0, stream>>>(sw[l], swt + (long)l * 65536, 256, 256);
    }
    for (int l = 0; l < 3; ++l)
        k_wt<<<(262144 + 255) / 256, 256, 0, stream>>>(w2[l], w2t + (long)l * 262144, 1024, 256);

    // ---------------- layer 1 (fin = 11, SIMT small-K GEMMs) ----------------
    for (int r = 0; r < 4; ++r) {
        hipMemsetAsync(agg, 0, (size_t)kN * 11 * 4, stream);
        k_scatter_rel11<<<1024, 256, 0, stream>>>(elist, cnt, r, ei, x, agg);
        k_gemm<float, bf16, true, false><<<gM, 256, 0, stream>>>(
            x, agg, 11, w1[0] + (long)r * 11 * 256, 256, h1 + r * 256, 1024, kN, 11, nullptr);
    }
    hipMemsetAsync(stats, 0, 2048 * 4, stream);
    k_colstats<<<512, 256, 0, stream>>>(h1, stats, stats + 1024);
    k_bn_params<<<4, 256, 0, stream>>>(stats, stats + 1024, gmm[0], btm[0], scl, shf);
    k_pack_h1<<<gH, 256, 0, stream>>>(h1, scl, shf, n4h);
    k_gemm<float, float, false, true><<<gM, 256, 0, stream>>>(
        x, nullptr, 11, sw[0], 256, P, 256, kN, 11, btt + 0);
    k_mfma<false, true, true, false><<<gM, 256, 0, stream>>>(
        h1, w2t + 0, 1024, P, nullptr, 0, kN, nullptr);

    // ---------------- layers 2,3 (fin = 256, MFMA) ----------------
    for (int l = 1; l < 3; ++l) {
        for (int r = 0; r < 4; ++r) {
            hipMemsetAsync(agg, 0, (size_t)kN * 256 * 4, stream);
            k_scatter_rel<<<2048, 256, 0, stream>>>(elist, cnt, r, ei, P, agg);
            k_pack<true><<<gF, 256, 0, stream>>>(P, agg, a16, n4f);
            k_mfma<false, false, false, true><<<gM, 256, 0, stream>>>(
                a16, w1t + (long)l * 4 * 65536 + (long)r * 65536, 256,
                nullptr, h1 + r * 256, 1024, kN, nullptr);
        }
        hipMemsetAsync(stats, 0, 2048 * 4, stream);
        k_colstats<<<512, 256, 0, stream>>>(h1, stats, stats + 1024);
        k_bn_params<<<4, 256, 0, stream>>>(stats, stats + 1024, gmm[l], btm[l], scl, shf);
        k_pack_h1<<<gH, 256, 0, stream>>>(h1, scl, shf, n4h);
        k_pack<false><<<gF, 256, 0, stream>>>(P, nullptr, a16, n4f);
        k_mfma<true, false, false, false><<<gM, 256, 0, stream>>>(
            a16, swt + (long)l * 65536, 256, P, nullptr, 0, kN, btt + l * 256);
        k_mfma<false, true, true, false><<<gM, 256, 0, stream>>>(
            h1, w2t + (long)l * 262144, 1024, P, nullptr, 0, kN, nullptr);
    }

    // ---------------- pool + head ----------------
    hipMemsetAsync(pooled, 0, ((size_t)kG * 256 + kG) * sizeof(float), stream);
    k_pool<<<kN, 256, 0, stream>>>(P, batch, pooled, counts);
    k_head<<<kG, 64, 0, stream>>>(pooled, counts, lin_w, lin_b, out);
}

// Round 4
// 1888.321 us; speedup vs baseline: 3.4260x; 1.2261x over previous
//
#include <hip/hip_runtime.h>

static const int kN = 50000;   // nodes
static const int kE = 300000;  // edges
static const int kG = 2048;    // graphs
static const int kT = 19;      // targets
static const int kSeg = kN * 4;  // CSR segments: key = dst*4 + rel

typedef __bf16 bf16;
typedef __bf16 bf16x8 __attribute__((ext_vector_type(8)));
typedef __bf16 bf16x4 __attribute__((ext_vector_type(4)));
typedef float  f32x4  __attribute__((ext_vector_type(4)));

// ---------------------------------------------------------------------------
// Fused MFMA GEMM:  C = op( [A1 | BN?(A2)] @ Bt^T )
// A1: [M,K1] bf16 (lda1), A2: [M,K2] bf16 (lda2), Bt: [256, K1+K2] bf16.
// BNA2: a2 = max(0, a2*scl[k]+shf[k]).  Stats: accumulate column sum/sumsq of
// the bf16-rounded output into stats[cBase+col] / stats[1024+cBase+col].
// Block = 4 waves (2x2), 128x128 tile, wave = 4x4 frags of 16x16x32.
// Layouts (m89/m91-verified): A/B idx=lane&15,k=(lane>>4)*8+j; C/D row=(lane>>4)*4+reg,col=lane&15
// ---------------------------------------------------------------------------
template<bool BNA2, bool Stats, bool HasBias, bool ReluOut>
__global__ __launch_bounds__(256) void k_mfma2(
    const bf16* __restrict__ A1, int lda1, int K1,
    const bf16* __restrict__ A2, int lda2, int K2,
    const bf16* __restrict__ Bt,
    bf16* __restrict__ Cb, int ldcb, int cBase,
    int M, const float* __restrict__ bias,
    const float* __restrict__ scl, const float* __restrict__ shf,
    float* __restrict__ stats)
{
    const int K = K1 + K2;
    const int tid  = threadIdx.x;
    const int wave = tid >> 6;
    const int lane = tid & 63;
    const int l15  = lane & 15;
    const int lq   = lane >> 4;
    const int koff = lq * 8;
    const int m_base = blockIdx.x * 128 + (wave & 1) * 64;
    const int n_base = blockIdx.y * 128 + (wave >> 1) * 64;

    const bf16 *A1p[4], *A2p[4], *Bp[4];
#pragma unroll
    for (int i = 0; i < 4; ++i) {
        int gm = m_base + i * 16 + l15;
        if (gm >= M) gm = M - 1;           // clamped read; stores are guarded
        A1p[i] = A1 + (long)gm * lda1 + koff;
        A2p[i] = (K2 > 0) ? A2 + (long)gm * lda2 + koff : A1p[i];
    }
#pragma unroll
    for (int j = 0; j < 4; ++j)
        Bp[j] = Bt + (long)(n_base + j * 16 + l15) * K + koff;

    f32x4 acc[4][4];
#pragma unroll
    for (int i = 0; i < 4; ++i)
#pragma unroll
        for (int j = 0; j < 4; ++j) acc[i][j] = (f32x4){0.f, 0.f, 0.f, 0.f};

    auto ldA = [&](int kt, bf16x8* dst) {
        if (kt < K1) {
#pragma unroll
            for (int i = 0; i < 4; ++i) dst[i] = *(const bf16x8*)(A1p[i] + kt);
        } else {
            int k2 = kt - K1;
            if (BNA2) {
                float4 s0 = *(const float4*)(scl + k2 + koff);
                float4 s1 = *(const float4*)(scl + k2 + koff + 4);
                float4 t0 = *(const float4*)(shf + k2 + koff);
                float4 t1 = *(const float4*)(shf + k2 + koff + 4);
                float sa[8] = {s0.x,s0.y,s0.z,s0.w,s1.x,s1.y,s1.z,s1.w};
                float ta[8] = {t0.x,t0.y,t0.z,t0.w,t1.x,t1.y,t1.z,t1.w};
#pragma unroll
                for (int i = 0; i < 4; ++i) {
                    bf16x8 v = *(const bf16x8*)(A2p[i] + k2);
                    bf16x8 o;
#pragma unroll
                    for (int u = 0; u < 8; ++u)
                        o[u] = (bf16)fmaxf(0.f, fmaf((float)v[u], sa[u], ta[u]));
                    dst[i] = o;
                }
            } else {
#pragma unroll
                for (int i = 0; i < 4; ++i) dst[i] = *(const bf16x8*)(A2p[i] + k2);
            }
        }
    };
    auto ldB = [&](int kt, bf16x8* dst) {
#pragma unroll
        for (int j = 0; j < 4; ++j) dst[j] = *(const bf16x8*)(Bp[j] + kt);
    };

    bf16x8 a0[4], b0[4], a1[4], b1[4];
    ldA(0, a0); ldB(0, b0);
    for (int kt = 0; kt < K; kt += 64) {
        ldA(kt + 32, a1); ldB(kt + 32, b1);
#pragma unroll
        for (int i = 0; i < 4; ++i)
#pragma unroll
            for (int j = 0; j < 4; ++j)
                acc[i][j] = __builtin_amdgcn_mfma_f32_16x16x32_bf16(a0[i], b0[j], acc[i][j], 0, 0, 0);
        int kn = kt + 64; if (kn >= K) kn = 0;     // dummy final prefetch
        ldA(kn, a0); ldB(kn, b0);
#pragma unroll
        for (int i = 0; i < 4; ++i)
#pragma unroll
            for (int j = 0; j < 4; ++j)
                acc[i][j] = __builtin_amdgcn_mfma_f32_16x16x32_bf16(a1[i], b1[j], acc[i][j], 0, 0, 0);
    }

    float sv[4] = {0,0,0,0}, qv[4] = {0,0,0,0};
#pragma unroll
    for (int i = 0; i < 4; ++i) {
        int rowb = m_base + i * 16 + lq * 4;
#pragma unroll
        for (int rr = 0; rr < 4; ++rr) {
            int gm = rowb + rr;
            if (gm < M) {
#pragma unroll
                for (int j = 0; j < 4; ++j) {
                    int gn = n_base + j * 16 + l15;
                    float v = acc[i][j][rr];
                    if (HasBias) v += bias[gn];
                    if (ReluOut) v = fmaxf(v, 0.f);
                    bf16 bvv = (bf16)v;
                    Cb[(long)gm * ldcb + cBase + gn] = bvv;
                    if (Stats) {
                        float f = (float)bvv;
                        sv[j] += f; qv[j] += f * f;
                    }
                }
            }
        }
    }
    if (Stats) {
#pragma unroll
        for (int j = 0; j < 4; ++j) {
            float s = sv[j], q = qv[j];
            s += __shfl_xor(s, 16); s += __shfl_xor(s, 32);
            q += __shfl_xor(q, 16); q += __shfl_xor(q, 32);
            if (lq == 0) {
                int gn = n_base + j * 16 + l15;
                atomicAdd(&stats[cBase + gn], s);
                atomicAdd(&stats[1024 + cBase + gn], q);
            }
        }
    }
}

// ---------------------------------------------------------------------------
// SIMT GEMM (layer-1 K=11 only): Cb_bf16 = A_f32 @ B_f32
// ---------------------------------------------------------------------------
#define BM 128
#define BN 128
#define BK 16
__global__ __launch_bounds__(256) void k_gemm_s(
    const float* __restrict__ A, int lda,
    const float* __restrict__ B, int ldb,
    bf16* __restrict__ C, int ldc, int cBase,
    int M, int K)
{
    const int m0 = blockIdx.x * BM;
    const int n0 = blockIdx.y * BN;
    __shared__ float As[BK][BM + 4];
    __shared__ float Bs[BK][BN];
    const int tid = threadIdx.x;
    const int tx = tid & 15;
    const int ty = tid >> 4;

    float acc[8][8];
#pragma unroll
    for (int i = 0; i < 8; ++i)
#pragma unroll
        for (int j = 0; j < 8; ++j) acc[i][j] = 0.f;

    for (int kt = 0; kt < K; kt += BK) {
#pragma unroll
        for (int i = 0; i < 8; ++i) {
            int idx = tid + i * 256;
            int row = idx >> 4, kk = idx & 15;
            int gm = m0 + row, gk = kt + kk;
            As[kk][row] = (gm < M && gk < K) ? A[(long)gm * lda + gk] : 0.f;
        }
#pragma unroll
        for (int i = 0; i < 8; ++i) {
            int idx = tid + i * 256;
            int kk = idx >> 7, col = idx & 127;
            int gk = kt + kk;
            Bs[kk][col] = (gk < K) ? B[(long)gk * ldb + (n0 + col)] : 0.f;
        }
        __syncthreads();
#pragma unroll
        for (int kk = 0; kk < BK; ++kk) {
            float a[8], b[8];
            float4 A0 = *(const float4*)&As[kk][ty * 8];
            float4 A1 = *(const float4*)&As[kk][ty * 8 + 4];
            a[0]=A0.x; a[1]=A0.y; a[2]=A0.z; a[3]=A0.w; a[4]=A1.x; a[5]=A1.y; a[6]=A1.z; a[7]=A1.w;
            float4 B0 = *(const float4*)&Bs[kk][tx * 8];
            float4 B1 = *(const float4*)&Bs[kk][tx * 8 + 4];
            b[0]=B0.x; b[1]=B0.y; b[2]=B0.z; b[3]=B0.w; b[4]=B1.x; b[5]=B1.y; b[6]=B1.z; b[7]=B1.w;
#pragma unroll
            for (int i = 0; i < 8; ++i)
#pragma unroll
                for (int j = 0; j < 8; ++j) acc[i][j] = fmaf(a[i], b[j], acc[i][j]);
        }
        __syncthreads();
    }
#pragma unroll
    for (int i = 0; i < 8; ++i) {
        int gm = m0 + ty * 8 + i;
        if (gm >= M) break;
#pragma unroll
        for (int j = 0; j < 8; ++j)
            C[(long)gm * ldc + cBase + n0 + tx * 8 + j] = (bf16)acc[i][j];
    }
}

// ---------------------------------------------------------------------------
// CSR build: key = dst*4 + rel
__global__ void k_hist(const int* __restrict__ ei, const int* __restrict__ et,
                       int* __restrict__ hist)
{
    int e = blockIdx.x * 256 + threadIdx.x;
    if (e >= kE) return;
    atomicAdd(&hist[ei[kE + e] * 4 + et[e]], 1);
}

__global__ __launch_bounds__(1024) void k_scan(const int* __restrict__ hist,
                                               int* __restrict__ row_ptr)
{
    const int CH = 196;  // 1024*196 >= kSeg
    __shared__ int bs[1024];
    int t = threadIdx.x;
    int lo = t * CH, hi = lo + CH; if (hi > kSeg) hi = kSeg; if (lo > kSeg) lo = kSeg;
    int s = 0;
    for (int i = lo; i < hi; ++i) s += hist[i];
    bs[t] = s; __syncthreads();
    for (int ofs = 1; ofs < 1024; ofs <<= 1) {
        int v = (t >= ofs) ? bs[t - ofs] : 0;
        __syncthreads();
        bs[t] += v;
        __syncthreads();
    }
    int pre = (t == 0) ? 0 : bs[t - 1];
    for (int i = lo; i < hi; ++i) { row_ptr[i] = pre; pre += hist[i]; }
    if (t == 1023) row_ptr[kSeg] = pre;
}

__global__ void k_copy(const int* __restrict__ a, int* __restrict__ b, int n)
{
    int i = blockIdx.x * 256 + threadIdx.x;
    if (i < n) b[i] = a[i];
}

__global__ void k_fill(const int* __restrict__ ei, const int* __restrict__ et,
                       int* __restrict__ cursor, int* __restrict__ srcidx)
{
    int e = blockIdx.x * 256 + threadIdx.x;
    if (e >= kE) return;
    int key = ei[kE + e] * 4 + et[e];
    int pos = atomicAdd(&cursor[key], 1);
    srcidx[pos] = ei[e];
}

// ---------------------------------------------------------------------------
// CSR aggregate + self, fin=256, bf16 in/out: a16[d] = Pb[d] + sum_in Pb[src]
__global__ __launch_bounds__(256) void k_agg256(
    const bf16* __restrict__ Pb, const int* __restrict__ srcidx,
    const int* __restrict__ row_ptr, int r, bf16* __restrict__ a16)
{
    int w = threadIdx.x >> 6, lane = threadIdx.x & 63;
    int d = blockIdx.x * 4 + w;
    if (d >= kN) return;
    int seg = d * 4 + r;
    int i0 = row_ptr[seg], i1 = row_ptr[seg + 1];
    bf16x4 sv = ((const bf16x4*)(Pb + (long)d * 256))[lane];
    f32x4 acc = {(float)sv[0], (float)sv[1], (float)sv[2], (float)sv[3]};
    for (int i = i0; i < i1; ++i) {
        int s = srcidx[i];
        bf16x4 v = ((const bf16x4*)(Pb + (long)s * 256))[lane];
        acc[0] += (float)v[0]; acc[1] += (float)v[1];
        acc[2] += (float)v[2]; acc[3] += (float)v[3];
    }
    bf16x4 o = {(bf16)acc[0], (bf16)acc[1], (bf16)acc[2], (bf16)acc[3]};
    ((bf16x4*)(a16 + (long)d * 256))[lane] = o;
}

// CSR aggregate + self, fin=11 fp32, all 4 rels: a11[(d*4+r)*16+ch]
__global__ void k_agg11(const float* __restrict__ x, const int* __restrict__ srcidx,
                        const int* __restrict__ row_ptr, float* __restrict__ a11)
{
    int gid = blockIdx.x * 256 + threadIdx.x;   // (d*4+r)*16 + ch
    if (gid >= kSeg * 16) return;
    int ch = gid & 15;
    int seg = gid >> 4;
    int d = seg >> 2;
    float acc = 0.f;
    if (ch < 11) {
        acc = x[(long)d * 11 + ch];
        int i0 = row_ptr[seg], i1 = row_ptr[seg + 1];
        for (int i = i0; i < i1; ++i) acc += x[(long)srcidx[i] * 11 + ch];
    }
    a11[gid] = acc;
}

// x [N,11] fp32 -> xb1 [N,64] bf16 zero-padded
__global__ void k_xpad(const float* __restrict__ x, bf16* __restrict__ xb1)
{
    int gid = blockIdx.x * 256 + threadIdx.x;
    if (gid >= kN * 64) return;
    int c = gid & 63, d = gid >> 6;
    xb1[gid] = (c < 11) ? (bf16)x[(long)d * 11 + c] : (bf16)0.f;
}

// weight transpose-pack: in [K,N] fp32 -> out[n*ldout + coff + k] bf16
__global__ void k_wt_s(const float* __restrict__ in, bf16* __restrict__ out,
                       int K, int N, int ldout, int coff)
{
    int i = blockIdx.x * 256 + threadIdx.x;
    if (i >= K * N) return;
    int n = i / K, k = i - n * K;
    out[(long)n * ldout + coff + k] = (bf16)in[(long)k * N + n];
}

// column sums/sumsq of bf16 h1 [N,1024] (layer-1 only)
__global__ void k_colstats(const bf16* __restrict__ h1,
                           float* __restrict__ sums, float* __restrict__ sumsq)
{
    int c4 = threadIdx.x * 4;
    float s[4] = {0,0,0,0}, q[4] = {0,0,0,0};
    for (int v = blockIdx.x; v < kN; v += gridDim.x) {
        bf16x4 w = *(const bf16x4*)&h1[(long)v * 1024 + c4];
        float a = (float)w[0], b = (float)w[1], c = (float)w[2], d = (float)w[3];
        s[0]+=a; q[0]+=a*a; s[1]+=b; q[1]+=b*b;
        s[2]+=c; q[2]+=c*c; s[3]+=d; q[3]+=d*d;
    }
#pragma unroll
    for (int i = 0; i < 4; ++i) {
        atomicAdd(&sums[c4 + i],  s[i]);
        atomicAdd(&sumsq[c4 + i], q[i]);
    }
}

__global__ void k_bn_params(const float* __restrict__ stats,
                            const float* __restrict__ g, const float* __restrict__ bt,
                            float* __restrict__ scl, float* __restrict__ shf)
{
    int c = blockIdx.x * 256 + threadIdx.x;  // < 1024
    const float invN = 1.0f / (float)kN;
    float mu  = stats[c] * invN;
    float var = stats[1024 + c] * invN - mu * mu;
    float sc  = g[c] * rsqrtf(var + 1e-5f);
    scl[c] = sc;
    shf[c] = bt[c] - mu * sc;
}

__global__ void k_bias_total(const float* sb0, const float* b20,
                             const float* sb1, const float* b21,
                             const float* sb2, const float* b22,
                             float* __restrict__ btt)
{
    int l = blockIdx.x, j = threadIdx.x;
    const float* sb = (l == 0) ? sb0 : (l == 1) ? sb1 : sb2;
    const float* b2 = (l == 0) ? b20 : (l == 1) ? b21 : b22;
    float v = sb[j];
#pragma unroll
    for (int r = 0; r < 4; ++r) v += b2[r * 256 + j];
    btt[l * 256 + j] = v;
}

__global__ void k_pool(const bf16* __restrict__ h, const int* __restrict__ batch,
                       float* __restrict__ pooled, float* __restrict__ counts)
{
    int v = blockIdx.x;
    int c = threadIdx.x;
    int g = batch[v];
    atomicAdd(&pooled[((long)g << 8) + c], (float)h[((long)v << 8) + c]);
    if (c == 0) atomicAdd(&counts[g], 1.0f);
}

__global__ __launch_bounds__(64) void k_head(const float* __restrict__ pooled,
                                             const float* __restrict__ counts,
                                             const float* __restrict__ lw,
                                             const float* __restrict__ lb,
                                             float* __restrict__ out)
{
    int g = blockIdx.x;
    int l = threadIdx.x;
    float inv = 1.0f / fmaxf(counts[g], 1.0f);
    float acc[kT];
#pragma unroll
    for (int t = 0; t < kT; ++t) acc[t] = 0.f;
    for (int k = l; k < 256; k += 64) {
        float p = pooled[((long)g << 8) + k] * inv;
#pragma unroll
        for (int t = 0; t < kT; ++t) acc[t] = fmaf(p, lw[k * kT + t], acc[t]);
    }
#pragma unroll
    for (int off = 32; off > 0; off >>= 1)
#pragma unroll
        for (int t = 0; t < kT; ++t) acc[t] += __shfl_down(acc[t], off);
    if (l == 0) {
#pragma unroll
        for (int t = 0; t < kT; ++t) out[(long)g * kT + t] = acc[t] + lb[t];
    }
}

// ---------------------------------------------------------------------------
extern "C" void kernel_launch(void* const* d_in, const int* in_sizes, int n_in,
                              void* d_out, int out_size, void* d_ws, size_t ws_size,
                              hipStream_t stream)
{
    const float* x     = (const float*)d_in[0];
    const int*   ei    = (const int*)d_in[1];
    const int*   et    = (const int*)d_in[2];
    const int*   batch = (const int*)d_in[3];

    const float *sw[3], *sb[3], *w1[3], *gmm[3], *btm[3], *w2[3], *b2[3];
    for (int l = 0; l < 3; ++l) {
        int b = 4 + l * 8;
        sw[l]  = (const float*)d_in[b + 0];
        sb[l]  = (const float*)d_in[b + 1];
        w1[l]  = (const float*)d_in[b + 2];
        // b+3 = b1 (cancels inside BatchNorm)
        gmm[l] = (const float*)d_in[b + 4];
        btm[l] = (const float*)d_in[b + 5];
        w2[l]  = (const float*)d_in[b + 6];
        b2[l]  = (const float*)d_in[b + 7];
    }
    const float* lin_w = (const float*)d_in[28];
    const float* lin_b = (const float*)d_in[29];
    float* out = (float*)d_out;
    (void)in_sizes; (void)n_in; (void)out_size;

    // ---- workspace (~207 MB) ----
    char* wsb = (char*)d_ws;
    size_t off = 0;
    auto alloc = [&](size_t bytes) { void* p = wsb + off; off = (off + bytes + 255) & ~(size_t)255; return p; };
    bf16*  Pb0    = (bf16*) alloc((size_t)kN * 256 * 2);
    bf16*  Pb1    = (bf16*) alloc((size_t)kN * 256 * 2);
    bf16*  h1     = (bf16*) alloc((size_t)kN * 1024 * 2);
    bf16*  a16    = (bf16*) alloc((size_t)kN * 256 * 2);
    float* a11    = (float*)alloc((size_t)kSeg * 16 * 4);
    bf16*  xb1    = (bf16*) alloc((size_t)kN * 64 * 2);
    bf16*  w1t    = (bf16*) alloc((size_t)2 * 4 * 65536 * 2);   // l=1,2
    bf16*  Bc0    = (bf16*) alloc((size_t)256 * 1088 * 2);
    bf16*  Bc1    = (bf16*) alloc((size_t)256 * 1280 * 2);
    bf16*  Bc2    = (bf16*) alloc((size_t)256 * 1280 * 2);
    int*   hist   = (int*)  alloc((size_t)(kSeg + 1) * 4);
    int*   row_ptr= (int*)  alloc((size_t)(kSeg + 1) * 4);
    int*   cursor = (int*)  alloc((size_t)kSeg * 4);
    int*   srcidx = (int*)  alloc((size_t)kE * 4);
    float* stats  = (float*)alloc(2048 * 4);
    float* scl    = (float*)alloc(1024 * 4);
    float* shf    = (float*)alloc(1024 * 4);
    float* btt    = (float*)alloc(3 * 256 * 4);
    float* pooled = (float*)alloc((size_t)kG * 256 * 4);
    float* counts = (float*)alloc(kG * 4);
    if (ws_size < off) return;  // clean absmax-fail instead of OOB crash

    const dim3 gM((kN + 127) / 128, 2);

    // ---- CSR build + weight prepack ----
    hipMemsetAsync(hist, 0, (size_t)(kSeg + 1) * 4, stream);
    k_hist<<<(kE + 255) / 256, 256, 0, stream>>>(ei, et, hist);
    k_scan<<<1, 1024, 0, stream>>>(hist, row_ptr);
    k_copy<<<(kSeg + 255) / 256, 256, 0, stream>>>(row_ptr, cursor, kSeg);
    k_fill<<<(kE + 255) / 256, 256, 0, stream>>>(ei, et, cursor, srcidx);

    k_bias_total<<<3, 256, 0, stream>>>(sb[0], b2[0], sb[1], b2[1], sb[2], b2[2], btt);
    k_xpad<<<(kN * 64 + 255) / 256, 256, 0, stream>>>(x, xb1);
    for (int l = 1; l < 3; ++l)
        for (int r = 0; r < 4; ++r)
            k_wt_s<<<256, 256, 0, stream>>>(w1[l] + (long)r * 65536,
                                            w1t + (long)(l - 1) * 4 * 65536 + (long)r * 65536,
                                            256, 256, 256, 0);
    hipMemsetAsync(Bc0, 0, (size_t)256 * 1088 * 2, stream);
    k_wt_s<<<(11 * 256 + 255) / 256, 256, 0, stream>>>(sw[0], Bc0, 11, 256, 1088, 0);
    k_wt_s<<<1024, 256, 0, stream>>>(w2[0], Bc0, 1024, 256, 1088, 64);
    k_wt_s<<<256, 256, 0, stream>>>(sw[1], Bc1, 256, 256, 1280, 0);
    k_wt_s<<<1024, 256, 0, stream>>>(w2[1], Bc1, 1024, 256, 1280, 256);
    k_wt_s<<<256, 256, 0, stream>>>(sw[2], Bc2, 256, 256, 1280, 0);
    k_wt_s<<<1024, 256, 0, stream>>>(w2[2], Bc2, 1024, 256, 1280, 256);

    // ---------------- layer 1 (fin=11) ----------------
    k_agg11<<<(kSeg * 16 + 255) / 256, 256, 0, stream>>>(x, srcidx, row_ptr, a11);
    for (int r = 0; r < 4; ++r)
        k_gemm_s<<<gM, 256, 0, stream>>>(a11 + r * 16, 64, w1[0] + (long)r * 11 * 256, 256,
                                         h1, 1024, r * 256, kN, 11);
    hipMemsetAsync(stats, 0, 2048 * 4, stream);
    k_colstats<<<512, 256, 0, stream>>>(h1, stats, stats + 1024);
    k_bn_params<<<4, 256, 0, stream>>>(stats, gmm[0], btm[0], scl, shf);
    // Pb0 = relu( [xb1 | BN(h1)] @ Bc0^T + btt0 )
    k_mfma2<true, false, true, true><<<gM, 256, 0, stream>>>(
        xb1, 64, 64, h1, 1024, 1024, Bc0, Pb0, 256, 0, kN, btt + 0, scl, shf, nullptr);

    // ---------------- layers 2,3 (fin=256) ----------------
    for (int l = 1; l < 3; ++l) {
        bf16* Pin  = (l == 1) ? Pb0 : Pb1;
        bf16* Pout = (l == 1) ? Pb1 : Pb0;
        const bf16* Bc = (l == 1) ? Bc1 : Bc2;
        hipMemsetAsync(stats, 0, 2048 * 4, stream);
        for (int r = 0; r < 4; ++r) {
            k_agg256<<<kN / 4, 256, 0, stream>>>(Pin, srcidx, row_ptr, r, a16);
            // h1[:, r*256:+256] = a16 @ w1t[l][r]^T  (+ fused column stats)
            k_mfma2<false, true, false, false><<<gM, 256, 0, stream>>>(
                a16, 256, 256, nullptr, 0, 0,
                w1t + (long)(l - 1) * 4 * 65536 + (long)r * 65536,
                h1, 1024, r * 256, kN, nullptr, nullptr, nullptr, stats);
        }
        k_bn_params<<<4, 256, 0, stream>>>(stats, gmm[l], btm[l], scl, shf);
        // Pout = relu( [Pin | BN(h1)] @ Bc^T + btt_l )
        k_mfma2<true, false, true, true><<<gM, 256, 0, stream>>>(
            Pin, 256, 256, h1, 1024, 1024, Bc, Pout, 256, 0, kN, btt + l * 256, scl, shf, nullptr);
    }

    // ---------------- pool + head ----------------
    hipMemsetAsync(pooled, 0, ((size_t)kG * 256 + kG) * sizeof(float), stream);
    k_pool<<<kN, 256, 0, stream>>>(Pb0, batch, pooled, counts);
    k_head<<<kG, 64, 0, stream>>>(pooled, counts, lin_w, lin_b, out);
}

// Round 5
// 1493.185 us; speedup vs baseline: 4.3326x; 1.2646x over previous
//
#include <hip/hip_runtime.h>

static const int kN = 50000;   // nodes
static const int kE = 300000;  // edges
static const int kG = 2048;    // graphs
static const int kT = 19;      // targets
static const int kSeg = kN * 4;  // CSR segments: key = dst*4 + rel
static const int kScanB = (kSeg + 256) / 256;  // 784 blocks covers kSeg+1

typedef __bf16 bf16;
typedef __bf16 bf16x8 __attribute__((ext_vector_type(8)));
typedef __bf16 bf16x4 __attribute__((ext_vector_type(4)));
typedef float  f32x4  __attribute__((ext_vector_type(4)));

// ---------------------------------------------------------------------------
// GEMM1 layers 2/3: aggregate (CSR, +self) into LDS, then MFMA vs w1t[r].
// Grid (ceil(N/128), 4=rel), 512 threads (8 waves, 2m x 4n of 64x64).
// Output h1[:, r*256:+256] bf16 + fused column stats.
// Layouts (m89/m91-verified): A/B idx=lane&15,k=(lane>>4)*8+j;
//                             C/D row=(lane>>4)*4+reg, col=lane&15.
// ---------------------------------------------------------------------------
__global__ __launch_bounds__(512) void k_rgin1(
    const bf16* __restrict__ Pb, const int* __restrict__ srcidx,
    const int* __restrict__ row_ptr, const bf16* __restrict__ w1t,
    bf16* __restrict__ h1, float* __restrict__ stats)
{
    __shared__ bf16 As[128][264];   // row stride 264 bf16 = 132 dwords (pad)
    const int t = threadIdx.x;
    const int r = blockIdx.y;
    const int m0 = blockIdx.x * 128;

    // ---- phase 1: aggregate 128 rows x 256 ch into LDS ----
    {
        int row = t >> 2;            // 0..127
        int q   = t & 3;             // 64-ch chunk
        int dst = m0 + row;
        int dc  = dst < kN ? dst : kN - 1;
        int seg = dc * 4 + r;
        int i0 = row_ptr[seg], i1 = row_ptr[seg + 1];
        const bf16* self = Pb + (long)dc * 256 + q * 64;
#pragma unroll
        for (int g = 0; g < 8; ++g) {
            bf16x8 sv = *(const bf16x8*)(self + g * 8);
            float a[8];
#pragma unroll
            for (int u = 0; u < 8; ++u) a[u] = (float)sv[u];
            for (int i = i0; i < i1; ++i) {
                bf16x8 v = *(const bf16x8*)(Pb + (long)srcidx[i] * 256 + q * 64 + g * 8);
#pragma unroll
                for (int u = 0; u < 8; ++u) a[u] += (float)v[u];
            }
            bf16x8 o;
#pragma unroll
            for (int u = 0; u < 8; ++u) o[u] = (bf16)a[u];
            *(bf16x8*)&As[row][q * 64 + g * 8] = o;
        }
    }
    __syncthreads();

    // ---- phase 2: MFMA from LDS, B direct-load double-buffered ----
    const int wave = t >> 6, lane = t & 63;
    const int l15 = lane & 15, lq = lane >> 4, koff = lq * 8;
    const int wm = (wave & 1) * 64, wn = (wave >> 1) * 64;

    const bf16* Bt = w1t + (long)r * 65536;
    const bf16* Bp[4];
#pragma unroll
    for (int j = 0; j < 4; ++j)
        Bp[j] = Bt + (long)(wn + j * 16 + l15) * 256 + koff;
    const bf16* Ar[4];
#pragma unroll
    for (int i = 0; i < 4; ++i) Ar[i] = &As[wm + i * 16 + l15][koff];

    f32x4 acc[4][4];
#pragma unroll
    for (int i = 0; i < 4; ++i)
#pragma unroll
        for (int j = 0; j < 4; ++j) acc[i][j] = (f32x4){0.f, 0.f, 0.f, 0.f};

    bf16x8 b0[4], b1[4];
#pragma unroll
    for (int j = 0; j < 4; ++j) b0[j] = *(const bf16x8*)(Bp[j]);
#pragma unroll
    for (int kt = 0; kt < 256; kt += 32) {
        int kn = kt + 32; if (kn >= 256) kn = 0;
#pragma unroll
        for (int j = 0; j < 4; ++j) b1[j] = *(const bf16x8*)(Bp[j] + kn);
        bf16x8 a[4];
#pragma unroll
        for (int i = 0; i < 4; ++i) a[i] = *(const bf16x8*)(Ar[i] + kt);
#pragma unroll
        for (int i = 0; i < 4; ++i)
#pragma unroll
            for (int j = 0; j < 4; ++j)
                acc[i][j] = __builtin_amdgcn_mfma_f32_16x16x32_bf16(a[i], b0[j], acc[i][j], 0, 0, 0);
#pragma unroll
        for (int j = 0; j < 4; ++j) b0[j] = b1[j];
    }

    // ---- epilogue: store h1 + fused stats ----
    const int cB = r * 256;
    float sv[4] = {0,0,0,0}, qv[4] = {0,0,0,0};
#pragma unroll
    for (int i = 0; i < 4; ++i) {
        int rowb = m0 + wm + i * 16 + lq * 4;
#pragma unroll
        for (int rr = 0; rr < 4; ++rr) {
            int gm = rowb + rr;
            if (gm < kN) {
#pragma unroll
                for (int j = 0; j < 4; ++j) {
                    int gn = wn + j * 16 + l15;
                    bf16 bv = (bf16)acc[i][j][rr];
                    h1[(long)gm * 1024 + cB + gn] = bv;
                    float f = (float)bv;
                    sv[j] += f; qv[j] += f * f;
                }
            }
        }
    }
#pragma unroll
    for (int j = 0; j < 4; ++j) {
        float s = sv[j], q = qv[j];
        s += __shfl_xor(s, 16); s += __shfl_xor(s, 32);
        q += __shfl_xor(q, 16); q += __shfl_xor(q, 32);
        if (lq == 0) {
            int gn = cB + wn + j * 16 + l15;
            atomicAdd(&stats[gn], s);
            atomicAdd(&stats[1024 + gn], q);
        }
    }
}

// ---------------------------------------------------------------------------
// GEMM1 layer 1: A = a1b[r] [N,32] bf16 (K=32, one MFMA step) + fused stats.
// Grid (ceil(N/128), 4), 512 threads.
// ---------------------------------------------------------------------------
__global__ __launch_bounds__(512) void k_l1gemm(
    const bf16* __restrict__ a1b, const bf16* __restrict__ w1tL1,
    bf16* __restrict__ h1, float* __restrict__ stats)
{
    const int t = threadIdx.x;
    const int r = blockIdx.y;
    const int m0 = blockIdx.x * 128;
    const int wave = t >> 6, lane = t & 63;
    const int l15 = lane & 15, lq = lane >> 4, koff = lq * 8;
    const int wm = (wave & 1) * 64, wn = (wave >> 1) * 64;

    bf16x8 a[4], b[4];
#pragma unroll
    for (int i = 0; i < 4; ++i) {
        int gm = m0 + wm + i * 16 + l15;
        if (gm >= kN) gm = kN - 1;
        a[i] = *(const bf16x8*)(a1b + ((long)r * kN + gm) * 32 + koff);
    }
#pragma unroll
    for (int j = 0; j < 4; ++j)
        b[j] = *(const bf16x8*)(w1tL1 + (long)r * 8192 + (long)(wn + j * 16 + l15) * 32 + koff);

    f32x4 acc[4][4];
#pragma unroll
    for (int i = 0; i < 4; ++i)
#pragma unroll
        for (int j = 0; j < 4; ++j)
            acc[i][j] = __builtin_amdgcn_mfma_f32_16x16x32_bf16(a[i], b[j],
                        (f32x4){0.f, 0.f, 0.f, 0.f}, 0, 0, 0);

    const int cB = r * 256;
    float sv[4] = {0,0,0,0}, qv[4] = {0,0,0,0};
#pragma unroll
    for (int i = 0; i < 4; ++i) {
        int rowb = m0 + wm + i * 16 + lq * 4;
#pragma unroll
        for (int rr = 0; rr < 4; ++rr) {
            int gm = rowb + rr;
            if (gm < kN) {
#pragma unroll
                for (int j = 0; j < 4; ++j) {
                    int gn = wn + j * 16 + l15;
                    bf16 bv = (bf16)acc[i][j][rr];
                    h1[(long)gm * 1024 + cB + gn] = bv;
                    float f = (float)bv;
                    sv[j] += f; qv[j] += f * f;
                }
            }
        }
    }
#pragma unroll
    for (int j = 0; j < 4; ++j) {
        float s = sv[j], q = qv[j];
        s += __shfl_xor(s, 16); s += __shfl_xor(s, 32);
        q += __shfl_xor(q, 16); q += __shfl_xor(q, 32);
        if (lq == 0) {
            int gn = cB + wn + j * 16 + l15;
            atomicAdd(&stats[gn], s);
            atomicAdd(&stats[1024 + gn], q);
        }
    }
}

// ---------------------------------------------------------------------------
// GEMM2: C = relu( [A1 | relu(BN(A2))] @ Bt^T + bias ).  Grid (ceil(M/128)),
// 512 thr, block tile 128x256. PoolOut: atomicAdd rows into pooled[batch].
// ---------------------------------------------------------------------------
template<bool PoolOut>
__global__ __launch_bounds__(512) void k_gemm2(
    const bf16* __restrict__ A1, int lda1, int K1,
    const bf16* __restrict__ A2, int lda2, int K2,
    const bf16* __restrict__ Bt,
    bf16* __restrict__ Cout,
    int M, const float* __restrict__ bias,
    const float* __restrict__ scl, const float* __restrict__ shf,
    const int* __restrict__ batch, float* __restrict__ pooled)
{
    const int K = K1 + K2;
    const int t = threadIdx.x;
    const int wave = t >> 6, lane = t & 63;
    const int l15 = lane & 15, lq = lane >> 4, koff = lq * 8;
    const int wm = (wave & 1) * 64, wn = (wave >> 1) * 64;
    const int m0 = blockIdx.x * 128;

    const bf16 *A1p[4], *A2p[4], *Bp[4];
#pragma unroll
    for (int i = 0; i < 4; ++i) {
        int gm = m0 + wm + i * 16 + l15;
        if (gm >= M) gm = M - 1;
        A1p[i] = A1 + (long)gm * lda1 + koff;
        A2p[i] = A2 + (long)gm * lda2 + koff;
    }
#pragma unroll
    for (int j = 0; j < 4; ++j)
        Bp[j] = Bt + (long)(wn + j * 16 + l15) * K + koff;

    f32x4 acc[4][4];
#pragma unroll
    for (int i = 0; i < 4; ++i)
#pragma unroll
        for (int j = 0; j < 4; ++j) acc[i][j] = (f32x4){0.f, 0.f, 0.f, 0.f};

    auto ldA = [&](int kt, bf16x8* dst) {
        if (kt < K1) {
#pragma unroll
            for (int i = 0; i < 4; ++i) dst[i] = *(const bf16x8*)(A1p[i] + kt);
        } else {
            int k2 = kt - K1;
            float4 s0 = *(const float4*)(scl + k2 + koff);
            float4 s1 = *(const float4*)(scl + k2 + koff + 4);
            float4 t0 = *(const float4*)(shf + k2 + koff);
            float4 t1 = *(const float4*)(shf + k2 + koff + 4);
            float sa[8] = {s0.x,s0.y,s0.z,s0.w,s1.x,s1.y,s1.z,s1.w};
            float ta[8] = {t0.x,t0.y,t0.z,t0.w,t1.x,t1.y,t1.z,t1.w};
#pragma unroll
            for (int i = 0; i < 4; ++i) {
                bf16x8 v = *(const bf16x8*)(A2p[i] + k2);
                bf16x8 o;
#pragma unroll
                for (int u = 0; u < 8; ++u)
                    o[u] = (bf16)fmaxf(0.f, fmaf((float)v[u], sa[u], ta[u]));
                dst[i] = o;
            }
        }
    };

    bf16x8 a0[4], b0[4], a1[4], b1[4];
    ldA(0, a0);
#pragma unroll
    for (int j = 0; j < 4; ++j) b0[j] = *(const bf16x8*)(Bp[j]);
    for (int kt = 0; kt < K; kt += 64) {
        ldA(kt + 32, a1);
#pragma unroll
        for (int j = 0; j < 4; ++j) b1[j] = *(const bf16x8*)(Bp[j] + kt + 32);
#pragma unroll
        for (int i = 0; i < 4; ++i)
#pragma unroll
            for (int j = 0; j < 4; ++j)
                acc[i][j] = __builtin_amdgcn_mfma_f32_16x16x32_bf16(a0[i], b0[j], acc[i][j], 0, 0, 0);
        int kn = kt + 64; if (kn >= K) kn = 0;
        ldA(kn, a0);
#pragma unroll
        for (int j = 0; j < 4; ++j) b0[j] = *(const bf16x8*)(Bp[j] + kn);
#pragma unroll
        for (int i = 0; i < 4; ++i)
#pragma unroll
            for (int j = 0; j < 4; ++j)
                acc[i][j] = __builtin_amdgcn_mfma_f32_16x16x32_bf16(a1[i], b1[j], acc[i][j], 0, 0, 0);
    }

#pragma unroll
    for (int i = 0; i < 4; ++i) {
        int rowb = m0 + wm + i * 16 + lq * 4;
#pragma unroll
        for (int rr = 0; rr < 4; ++rr) {
            int gm = rowb + rr;
            if (gm < M) {
                int g = PoolOut ? batch[gm] : 0;
#pragma unroll
                for (int j = 0; j < 4; ++j) {
                    int gn = wn + j * 16 + l15;
                    float v = fmaxf(acc[i][j][rr] + bias[gn], 0.f);
                    if (PoolOut) atomicAdd(&pooled[(long)g * 256 + gn], v);
                    else         Cout[(long)gm * 256 + gn] = (bf16)v;
                }
            }
        }
    }
}

// ---------------------------------------------------------------------------
// CSR build
__global__ void k_hist(const int* __restrict__ ei, const int* __restrict__ et,
                       int* __restrict__ hist)
{
    int e = blockIdx.x * 256 + threadIdx.x;
    if (e >= kE) return;
    atomicAdd(&hist[ei[kE + e] * 4 + et[e]], 1);
}

__global__ void k_scan1(const int* __restrict__ hist, int* __restrict__ bsum)
{
    __shared__ int sd[256];
    int i = blockIdx.x * 256 + threadIdx.x;
    sd[threadIdx.x] = (i < kSeg) ? hist[i] : 0;
    __syncthreads();
    for (int o = 128; o > 0; o >>= 1) {
        if (threadIdx.x < o) sd[threadIdx.x] += sd[threadIdx.x + o];
        __syncthreads();
    }
    if (threadIdx.x == 0) bsum[blockIdx.x] = sd[0];
}

__global__ __launch_bounds__(1024) void k_scan2(const int* __restrict__ bsum,
                                                int* __restrict__ boff)
{
    __shared__ int sd[1024];
    int t = threadIdx.x;
    sd[t] = (t < kScanB) ? bsum[t] : 0;
    __syncthreads();
    for (int o = 1; o < 1024; o <<= 1) {
        int v = (t >= o) ? sd[t - o] : 0;
        __syncthreads();
        sd[t] += v;
        __syncthreads();
    }
    if (t < kScanB) boff[t] = (t == 0) ? 0 : sd[t - 1];
}

__global__ void k_scan3(const int* __restrict__ hist, const int* __restrict__ boff,
                        int* __restrict__ row_ptr, int* __restrict__ cursor)
{
    __shared__ int sd[256];
    int i = blockIdx.x * 256 + threadIdx.x;
    int v = (i < kSeg) ? hist[i] : 0;
    sd[threadIdx.x] = v;
    __syncthreads();
    for (int o = 1; o < 256; o <<= 1) {
        int u = (threadIdx.x >= o) ? sd[threadIdx.x - o] : 0;
        __syncthreads();
        sd[threadIdx.x] += u;
        __syncthreads();
    }
    if (i <= kSeg) {
        int excl = boff[blockIdx.x] + sd[threadIdx.x] - v;
        row_ptr[i] = excl;
        if (i < kSeg) cursor[i] = excl;
    }
}

__global__ void k_fill(const int* __restrict__ ei, const int* __restrict__ et,
                       int* __restrict__ cursor, int* __restrict__ srcidx)
{
    int e = blockIdx.x * 256 + threadIdx.x;
    if (e >= kE) return;
    int key = ei[kE + e] * 4 + et[e];
    int pos = atomicAdd(&cursor[key], 1);
    srcidx[pos] = ei[e];
}

// ---------------------------------------------------------------------------
// layer-1 aggregate: a1b[r][d][ch] = bf16( x[d][ch] + sum_src x[src][ch] ), ch<11
__global__ void k_agg11(const float* __restrict__ x, const int* __restrict__ srcidx,
                        const int* __restrict__ row_ptr, bf16* __restrict__ a1b)
{
    long gid = (long)blockIdx.x * 256 + threadIdx.x;
    if (gid >= (long)kSeg * 32) return;
    int ch  = (int)(gid & 31);
    int seg = (int)(gid >> 5);
    int d = seg >> 2, r = seg & 3;
    float acc = 0.f;
    if (ch < 11) {
        acc = x[(long)d * 11 + ch];
        int i0 = row_ptr[seg], i1 = row_ptr[seg + 1];
        for (int i = i0; i < i1; ++i) acc += x[(long)srcidx[i] * 11 + ch];
    }
    a1b[((long)r * kN + d) * 32 + ch] = (bf16)acc;
}

// x [N,11] fp32 -> xb1 [N,64] bf16 zero-padded
__global__ void k_xpad(const float* __restrict__ x, bf16* __restrict__ xb1)
{
    int gid = blockIdx.x * 256 + threadIdx.x;
    if (gid >= kN * 64) return;
    int c = gid & 63, d = gid >> 6;
    xb1[gid] = (c < 11) ? (bf16)x[(long)d * 11 + c] : (bf16)0.f;
}

// weight transpose-pack: in [K,N] fp32 -> out[n*ldout + coff + k] bf16
__global__ void k_wt_s(const float* __restrict__ in, bf16* __restrict__ out,
                       int K, int N, int ldout, int coff)
{
    int i = blockIdx.x * 256 + threadIdx.x;
    if (i >= K * N) return;
    int n = i / K, k = i - n * K;
    out[(long)n * ldout + coff + k] = (bf16)in[(long)k * N + n];
}

// layer-1 w1 pack: [4][11][256] fp32 -> [4][256][32] bf16 zero-padded
__global__ void k_wtL1(const float* __restrict__ w1, bf16* __restrict__ out)
{
    int i = blockIdx.x * 256 + threadIdx.x;
    if (i >= 4 * 256 * 32) return;
    int r = i >> 13, rem = i & 8191, n = rem >> 5, k = rem & 31;
    out[i] = (k < 11) ? (bf16)w1[(long)r * 11 * 256 + (long)k * 256 + n] : (bf16)0.f;
}

__global__ void k_bn_params(const float* __restrict__ stats,
                            const float* __restrict__ g, const float* __restrict__ bt,
                            float* __restrict__ scl, float* __restrict__ shf)
{
    int c = blockIdx.x * 256 + threadIdx.x;  // < 1024
    const float invN = 1.0f / (float)kN;
    float mu  = stats[c] * invN;
    float var = stats[1024 + c] * invN - mu * mu;
    float sc  = g[c] * rsqrtf(var + 1e-5f);
    scl[c] = sc;
    shf[c] = bt[c] - mu * sc;
}

__global__ void k_bias_total(const float* sb0, const float* b20,
                             const float* sb1, const float* b21,
                             const float* sb2, const float* b22,
                             float* __restrict__ btt)
{
    int l = blockIdx.x, j = threadIdx.x;
    const float* sb = (l == 0) ? sb0 : (l == 1) ? sb1 : sb2;
    const float* b2 = (l == 0) ? b20 : (l == 1) ? b21 : b22;
    float v = sb[j];
#pragma unroll
    for (int r = 0; r < 4; ++r) v += b2[r * 256 + j];
    btt[l * 256 + j] = v;
}

__global__ void k_counts(const int* __restrict__ batch, float* __restrict__ counts)
{
    int v = blockIdx.x * 256 + threadIdx.x;
    if (v < kN) atomicAdd(&counts[batch[v]], 1.0f);
}

__global__ __launch_bounds__(64) void k_head(const float* __restrict__ pooled,
                                             const float* __restrict__ counts,
                                             const float* __restrict__ lw,
                                             const float* __restrict__ lb,
                                             float* __restrict__ out)
{
    int g = blockIdx.x;
    int l = threadIdx.x;
    float inv = 1.0f / fmaxf(counts[g], 1.0f);
    float acc[kT];
#pragma unroll
    for (int t = 0; t < kT; ++t) acc[t] = 0.f;
    for (int k = l; k < 256; k += 64) {
        float p = pooled[((long)g << 8) + k] * inv;
#pragma unroll
        for (int t = 0; t < kT; ++t) acc[t] = fmaf(p, lw[k * kT + t], acc[t]);
    }
#pragma unroll
    for (int off = 32; off > 0; off >>= 1)
#pragma unroll
        for (int t = 0; t < kT; ++t) acc[t] += __shfl_down(acc[t], off);
    if (l == 0) {
#pragma unroll
        for (int t = 0; t < kT; ++t) out[(long)g * kT + t] = acc[t] + lb[t];
    }
}

// ---------------------------------------------------------------------------
extern "C" void kernel_launch(void* const* d_in, const int* in_sizes, int n_in,
                              void* d_out, int out_size, void* d_ws, size_t ws_size,
                              hipStream_t stream)
{
    const float* x     = (const float*)d_in[0];
    const int*   ei    = (const int*)d_in[1];
    const int*   et    = (const int*)d_in[2];
    const int*   batch = (const int*)d_in[3];

    const float *sw[3], *sb[3], *w1[3], *gmm[3], *btm[3], *w2[3], *b2[3];
    for (int l = 0; l < 3; ++l) {
        int b = 4 + l * 8;
        sw[l]  = (const float*)d_in[b + 0];
        sb[l]  = (const float*)d_in[b + 1];
        w1[l]  = (const float*)d_in[b + 2];
        // b+3 = b1 (cancels inside BatchNorm)
        gmm[l] = (const float*)d_in[b + 4];
        btm[l] = (const float*)d_in[b + 5];
        w2[l]  = (const float*)d_in[b + 6];
        b2[l]  = (const float*)d_in[b + 7];
    }
    const float* lin_w = (const float*)d_in[28];
    const float* lin_b = (const float*)d_in[29];
    float* out = (float*)d_out;
    (void)in_sizes; (void)n_in; (void)out_size;

    // ---- workspace (~184 MB) ----
    char* wsb = (char*)d_ws;
    size_t off = 0;
    auto alloc = [&](size_t bytes) { void* p = wsb + off; off = (off + bytes + 255) & ~(size_t)255; return p; };
    bf16*  Pb0    = (bf16*) alloc((size_t)kN * 256 * 2);
    bf16*  Pb1    = (bf16*) alloc((size_t)kN * 256 * 2);
    bf16*  h1     = (bf16*) alloc((size_t)kN * 1024 * 2);
    bf16*  a1b    = (bf16*) alloc((size_t)4 * kN * 32 * 2);
    bf16*  xb1    = (bf16*) alloc((size_t)kN * 64 * 2);
    bf16*  w1t    = (bf16*) alloc((size_t)2 * 4 * 65536 * 2);   // layers 2,3
    bf16*  w1tL1  = (bf16*) alloc((size_t)4 * 256 * 32 * 2);
    bf16*  Bc0    = (bf16*) alloc((size_t)256 * 1088 * 2);
    bf16*  Bc1    = (bf16*) alloc((size_t)256 * 1280 * 2);
    bf16*  Bc2    = (bf16*) alloc((size_t)256 * 1280 * 2);
    int*   hist   = (int*)  alloc((size_t)(kSeg + 1) * 4);
    int*   row_ptr= (int*)  alloc((size_t)(kSeg + 1) * 4);
    int*   cursor = (int*)  alloc((size_t)kSeg * 4);
    int*   srcidx = (int*)  alloc((size_t)kE * 4);
    int*   bsum   = (int*)  alloc((size_t)kScanB * 4);
    int*   boff   = (int*)  alloc((size_t)kScanB * 4);
    float* stats  = (float*)alloc(2048 * 4);
    float* scl    = (float*)alloc(1024 * 4);
    float* shf    = (float*)alloc(1024 * 4);
    float* btt    = (float*)alloc(3 * 256 * 4);
    float* pooled = (float*)alloc((size_t)kG * 256 * 4);
    float* counts = (float*)alloc(kG * 4);
    if (ws_size < off) return;  // clean absmax-fail instead of OOB crash

    const dim3 gR((kN + 127) / 128, 4);   // GEMM1 grids (512 thr)
    const dim3 g2((kN + 127) / 128);      // GEMM2 grid  (512 thr)

    // ---- CSR build (parallel scan) + weight prepack ----
    hipMemsetAsync(hist, 0, (size_t)(kSeg + 1) * 4, stream);
    k_hist<<<(kE + 255) / 256, 256, 0, stream>>>(ei, et, hist);
    k_scan1<<<kScanB, 256, 0, stream>>>(hist, bsum);
    k_scan2<<<1, 1024, 0, stream>>>(bsum, boff);
    k_scan3<<<kScanB, 256, 0, stream>>>(hist, boff, row_ptr, cursor);
    k_fill<<<(kE + 255) / 256, 256, 0, stream>>>(ei, et, cursor, srcidx);

    k_bias_total<<<3, 256, 0, stream>>>(sb[0], b2[0], sb[1], b2[1], sb[2], b2[2], btt);
    k_xpad<<<(kN * 64 + 255) / 256, 256, 0, stream>>>(x, xb1);
    k_wtL1<<<(4 * 256 * 32 + 255) / 256, 256, 0, stream>>>(w1[0], w1tL1);
    for (int l = 1; l < 3; ++l)
        for (int r = 0; r < 4; ++r)
            k_wt_s<<<256, 256, 0, stream>>>(w1[l] + (long)r * 65536,
                                            w1t + (long)(l - 1) * 4 * 65536 + (long)r * 65536,
                                            256, 256, 256, 0);
    hipMemsetAsync(Bc0, 0, (size_t)256 * 1088 * 2, stream);
    k_wt_s<<<(11 * 256 + 255) / 256, 256, 0, stream>>>(sw[0], Bc0, 11, 256, 1088, 0);
    k_wt_s<<<1024, 256, 0, stream>>>(w2[0], Bc0, 1024, 256, 1088, 64);
    k_wt_s<<<256, 256, 0, stream>>>(sw[1], Bc1, 256, 256, 1280, 0);
    k_wt_s<<<1024, 256, 0, stream>>>(w2[1], Bc1, 1024, 256, 1280, 256);
    k_wt_s<<<256, 256, 0, stream>>>(sw[2], Bc2, 256, 256, 1280, 0);
    k_wt_s<<<1024, 256, 0, stream>>>(w2[2], Bc2, 1024, 256, 1280, 256);

    k_counts<<<(kN + 255) / 256, 256, 0, stream>>>(batch, counts);  // counts poisoned -> must init
    hipMemsetAsync(pooled, 0, (size_t)kG * 256 * 4, stream);

    // ---------------- layer 1 ----------------
    k_agg11<<<(int)(((long)kSeg * 32 + 255) / 256), 256, 0, stream>>>(x, srcidx, row_ptr, a1b);
    hipMemsetAsync(stats, 0, 2048 * 4, stream);
    k_l1gemm<<<gR, 512, 0, stream>>>(a1b, w1tL1, h1, stats);
    k_bn_params<<<4, 256, 0, stream>>>(stats, gmm[0], btm[0], scl, shf);
    k_gemm2<false><<<g2, 512, 0, stream>>>(xb1, 64, 64, h1, 1024, 1024, Bc0,
                                           Pb0, kN, btt + 0, scl, shf, nullptr, nullptr);

    // ---------------- layer 2 ----------------
    hipMemsetAsync(stats, 0, 2048 * 4, stream);
    k_rgin1<<<gR, 512, 0, stream>>>(Pb0, srcidx, row_ptr, w1t, h1, stats);
    k_bn_params<<<4, 256, 0, stream>>>(stats, gmm[1], btm[1], scl, shf);
    k_gemm2<false><<<g2, 512, 0, stream>>>(Pb0, 256, 256, h1, 1024, 1024, Bc1,
                                           Pb1, kN, btt + 256, scl, shf, nullptr, nullptr);

    // ---------------- layer 3 (pool fused into GEMM2) ----------------
    hipMemsetAsync(stats, 0, 2048 * 4, stream);
    k_rgin1<<<gR, 512, 0, stream>>>(Pb1, srcidx, row_ptr, w1t + (size_t)4 * 65536, h1, stats);
    k_bn_params<<<4, 256, 0, stream>>>(stats, gmm[2], btm[2], scl, shf);
    k_gemm2<true><<<g2, 512, 0, stream>>>(Pb1, 256, 256, h1, 1024, 1024, Bc2,
                                          nullptr, kN, btt + 512, scl, shf, batch, pooled);

    // ---------------- head ----------------
    k_head<<<kG, 64, 0, stream>>>(pooled, counts, lin_w, lin_b, out);
}

// Round 6
// 1354.781 us; speedup vs baseline: 4.7752x; 1.1022x over previous
//
#include <hip/hip_runtime.h>

static const int kN = 50000;   // nodes
static const int kE = 300000;  // edges
static const int kG = 2048;    // graphs
static const int kT = 19;      // targets
static const int kSeg = kN * 4;  // CSR segments: key = dst*4 + rel
static const int kScanB = (kSeg + 256) / 256;  // 784 blocks covers kSeg+1

typedef __bf16 bf16;
typedef __bf16 bf16x8 __attribute__((ext_vector_type(8)));
typedef __bf16 bf16x4 __attribute__((ext_vector_type(4)));
typedef float  f32x4  __attribute__((ext_vector_type(4)));

// ---------------------------------------------------------------------------
// GEMM1 layers 2/3: aggregate (CSR, +self) into LDS, then MFMA vs w1t[r].
// Grid (ceil(N/128), 4=rel), 512 threads (8 waves, 2m x 4n of 64x64).
// Aggregation: ONE WAVE PER ROW, lane = 4 ch (bf16x4): per edge the wave
// reads the full 512 B source row coalesced (fixes 8x line overfetch seen
// in round 5: FETCH 800 MB -> ~210 MB).
// Layouts (m89/m91-verified): A/B idx=lane&15,k=(lane>>4)*8+j;
//                             C/D row=(lane>>4)*4+reg, col=lane&15.
// ---------------------------------------------------------------------------
__global__ __launch_bounds__(512) void k_rgin1(
    const bf16* __restrict__ Pb, const int* __restrict__ srcidx,
    const int* __restrict__ row_ptr, const bf16* __restrict__ w1t,
    bf16* __restrict__ h1, float* __restrict__ stats)
{
    __shared__ bf16 As[128][264];   // row stride 264 bf16 = 132 dwords (pad)
    const int t = threadIdx.x;
    const int r = blockIdx.y;
    const int m0 = blockIdx.x * 128;
    const int wave = t >> 6, lane = t & 63;

    // ---- phase 1: aggregate 128 rows x 256 ch into LDS (wave per row) ----
    for (int row = wave; row < 128; row += 8) {
        int dst = m0 + row;
        int dc  = dst < kN ? dst : kN - 1;   // clamp: safe read, stores guarded
        int seg = dc * 4 + r;
        int i0 = row_ptr[seg], i1 = row_ptr[seg + 1];
        bf16x4 sv = ((const bf16x4*)(Pb + (long)dc * 256))[lane];
        f32x4 a = {(float)sv[0], (float)sv[1], (float)sv[2], (float)sv[3]};
        int i = i0;
        for (; i + 1 < i1; i += 2) {
            int s0 = srcidx[i], s1 = srcidx[i + 1];
            bf16x4 v0 = ((const bf16x4*)(Pb + (long)s0 * 256))[lane];
            bf16x4 v1 = ((const bf16x4*)(Pb + (long)s1 * 256))[lane];
            a[0] += (float)v0[0] + (float)v1[0];
            a[1] += (float)v0[1] + (float)v1[1];
            a[2] += (float)v0[2] + (float)v1[2];
            a[3] += (float)v0[3] + (float)v1[3];
        }
        if (i < i1) {
            bf16x4 v0 = ((const bf16x4*)(Pb + (long)srcidx[i] * 256))[lane];
            a[0] += (float)v0[0]; a[1] += (float)v0[1];
            a[2] += (float)v0[2]; a[3] += (float)v0[3];
        }
        bf16x4 o = {(bf16)a[0], (bf16)a[1], (bf16)a[2], (bf16)a[3]};
        *(bf16x4*)&As[row][lane * 4] = o;
    }
    __syncthreads();

    // ---- phase 2: MFMA from LDS, B direct-load double-buffered ----
    const int l15 = lane & 15, lq = lane >> 4, koff = lq * 8;
    const int wm = (wave & 1) * 64, wn = (wave >> 1) * 64;

    const bf16* Bt = w1t + (long)r * 65536;
    const bf16* Bp[4];
#pragma unroll
    for (int j = 0; j < 4; ++j)
        Bp[j] = Bt + (long)(wn + j * 16 + l15) * 256 + koff;
    const bf16* Ar[4];
#pragma unroll
    for (int i = 0; i < 4; ++i) Ar[i] = &As[wm + i * 16 + l15][koff];

    f32x4 acc[4][4];
#pragma unroll
    for (int i = 0; i < 4; ++i)
#pragma unroll
        for (int j = 0; j < 4; ++j) acc[i][j] = (f32x4){0.f, 0.f, 0.f, 0.f};

    bf16x8 b0[4], b1[4];
#pragma unroll
    for (int j = 0; j < 4; ++j) b0[j] = *(const bf16x8*)(Bp[j]);
#pragma unroll
    for (int kt = 0; kt < 256; kt += 32) {
        int kn = kt + 32; if (kn >= 256) kn = 0;
#pragma unroll
        for (int j = 0; j < 4; ++j) b1[j] = *(const bf16x8*)(Bp[j] + kn);
        bf16x8 a[4];
#pragma unroll
        for (int i = 0; i < 4; ++i) a[i] = *(const bf16x8*)(Ar[i] + kt);
#pragma unroll
        for (int i = 0; i < 4; ++i)
#pragma unroll
            for (int j = 0; j < 4; ++j)
                acc[i][j] = __builtin_amdgcn_mfma_f32_16x16x32_bf16(a[i], b0[j], acc[i][j], 0, 0, 0);
#pragma unroll
        for (int j = 0; j < 4; ++j) b0[j] = b1[j];
    }

    // ---- epilogue: store h1 + fused stats ----
    const int cB = r * 256;
    float sv[4] = {0,0,0,0}, qv[4] = {0,0,0,0};
#pragma unroll
    for (int i = 0; i < 4; ++i) {
        int rowb = m0 + wm + i * 16 + lq * 4;
#pragma unroll
        for (int rr = 0; rr < 4; ++rr) {
            int gm = rowb + rr;
            if (gm < kN) {
#pragma unroll
                for (int j = 0; j < 4; ++j) {
                    int gn = wn + j * 16 + l15;
                    bf16 bv = (bf16)acc[i][j][rr];
                    h1[(long)gm * 1024 + cB + gn] = bv;
                    float f = (float)bv;
                    sv[j] += f; qv[j] += f * f;
                }
            }
        }
    }
#pragma unroll
    for (int j = 0; j < 4; ++j) {
        float s = sv[j], q = qv[j];
        s += __shfl_xor(s, 16); s += __shfl_xor(s, 32);
        q += __shfl_xor(q, 16); q += __shfl_xor(q, 32);
        if (lq == 0) {
            int gn = cB + wn + j * 16 + l15;
            atomicAdd(&stats[gn], s);
            atomicAdd(&stats[1024 + gn], q);
        }
    }
}

// ---------------------------------------------------------------------------
// GEMM1 layer 1: A = a1b[r] [N,32] bf16 (K=32, one MFMA step) + fused stats.
// Grid (ceil(N/128), 4), 512 threads.
// ---------------------------------------------------------------------------
__global__ __launch_bounds__(512) void k_l1gemm(
    const bf16* __restrict__ a1b, const bf16* __restrict__ w1tL1,
    bf16* __restrict__ h1, float* __restrict__ stats)
{
    const int t = threadIdx.x;
    const int r = blockIdx.y;
    const int m0 = blockIdx.x * 128;
    const int wave = t >> 6, lane = t & 63;
    const int l15 = lane & 15, lq = lane >> 4, koff = lq * 8;
    const int wm = (wave & 1) * 64, wn = (wave >> 1) * 64;

    bf16x8 a[4], b[4];
#pragma unroll
    for (int i = 0; i < 4; ++i) {
        int gm = m0 + wm + i * 16 + l15;
        if (gm >= kN) gm = kN - 1;
        a[i] = *(const bf16x8*)(a1b + ((long)r * kN + gm) * 32 + koff);
    }
#pragma unroll
    for (int j = 0; j < 4; ++j)
        b[j] = *(const bf16x8*)(w1tL1 + (long)r * 8192 + (long)(wn + j * 16 + l15) * 32 + koff);

    f32x4 acc[4][4];
#pragma unroll
    for (int i = 0; i < 4; ++i)
#pragma unroll
        for (int j = 0; j < 4; ++j)
            acc[i][j] = __builtin_amdgcn_mfma_f32_16x16x32_bf16(a[i], b[j],
                        (f32x4){0.f, 0.f, 0.f, 0.f}, 0, 0, 0);

    const int cB = r * 256;
    float sv[4] = {0,0,0,0}, qv[4] = {0,0,0,0};
#pragma unroll
    for (int i = 0; i < 4; ++i) {
        int rowb = m0 + wm + i * 16 + lq * 4;
#pragma unroll
        for (int rr = 0; rr < 4; ++rr) {
            int gm = rowb + rr;
            if (gm < kN) {
#pragma unroll
                for (int j = 0; j < 4; ++j) {
                    int gn = wn + j * 16 + l15;
                    bf16 bv = (bf16)acc[i][j][rr];
                    h1[(long)gm * 1024 + cB + gn] = bv;
                    float f = (float)bv;
                    sv[j] += f; qv[j] += f * f;
                }
            }
        }
    }
#pragma unroll
    for (int j = 0; j < 4; ++j) {
        float s = sv[j], q = qv[j];
        s += __shfl_xor(s, 16); s += __shfl_xor(s, 32);
        q += __shfl_xor(q, 16); q += __shfl_xor(q, 32);
        if (lq == 0) {
            int gn = cB + wn + j * 16 + l15;
            atomicAdd(&stats[gn], s);
            atomicAdd(&stats[1024 + gn], q);
        }
    }
}

// ---------------------------------------------------------------------------
// GEMM2: C = relu( [A1 | relu(BN(A2))] @ Bt^T + bias ).  Grid (ceil(M/128)),
// 512 thr, block tile 128x256. PoolOut: atomicAdd rows into pooled[batch].
// ---------------------------------------------------------------------------
template<bool PoolOut>
__global__ __launch_bounds__(512) void k_gemm2(
    const bf16* __restrict__ A1, int lda1, int K1,
    const bf16* __restrict__ A2, int lda2, int K2,
    const bf16* __restrict__ Bt,
    bf16* __restrict__ Cout,
    int M, const float* __restrict__ bias,
    const float* __restrict__ scl, const float* __restrict__ shf,
    const int* __restrict__ batch, float* __restrict__ pooled)
{
    const int K = K1 + K2;
    const int t = threadIdx.x;
    const int wave = t >> 6, lane = t & 63;
    const int l15 = lane & 15, lq = lane >> 4, koff = lq * 8;
    const int wm = (wave & 1) * 64, wn = (wave >> 1) * 64;
    const int m0 = blockIdx.x * 128;

    const bf16 *A1p[4], *A2p[4], *Bp[4];
#pragma unroll
    for (int i = 0; i < 4; ++i) {
        int gm = m0 + wm + i * 16 + l15;
        if (gm >= M) gm = M - 1;
        A1p[i] = A1 + (long)gm * lda1 + koff;
        A2p[i] = A2 + (long)gm * lda2 + koff;
    }
#pragma unroll
    for (int j = 0; j < 4; ++j)
        Bp[j] = Bt + (long)(wn + j * 16 + l15) * K + koff;

    f32x4 acc[4][4];
#pragma unroll
    for (int i = 0; i < 4; ++i)
#pragma unroll
        for (int j = 0; j < 4; ++j) acc[i][j] = (f32x4){0.f, 0.f, 0.f, 0.f};

    auto ldA = [&](int kt, bf16x8* dst) {
        if (kt < K1) {
#pragma unroll
            for (int i = 0; i < 4; ++i) dst[i] = *(const bf16x8*)(A1p[i] + kt);
        } else {
            int k2 = kt - K1;
            float4 s0 = *(const float4*)(scl + k2 + koff);
            float4 s1 = *(const float4*)(scl + k2 + koff + 4);
            float4 t0 = *(const float4*)(shf + k2 + koff);
            float4 t1 = *(const float4*)(shf + k2 + koff + 4);
            float sa[8] = {s0.x,s0.y,s0.z,s0.w,s1.x,s1.y,s1.z,s1.w};
            float ta[8] = {t0.x,t0.y,t0.z,t0.w,t1.x,t1.y,t1.z,t1.w};
#pragma unroll
            for (int i = 0; i < 4; ++i) {
                bf16x8 v = *(const bf16x8*)(A2p[i] + k2);
                bf16x8 o;
#pragma unroll
                for (int u = 0; u < 8; ++u)
                    o[u] = (bf16)fmaxf(0.f, fmaf((float)v[u], sa[u], ta[u]));
                dst[i] = o;
            }
        }
    };

    bf16x8 a0[4], b0[4], a1[4], b1[4];
    ldA(0, a0);
#pragma unroll
    for (int j = 0; j < 4; ++j) b0[j] = *(const bf16x8*)(Bp[j]);
    for (int kt = 0; kt < K; kt += 64) {
        ldA(kt + 32, a1);
#pragma unroll
        for (int j = 0; j < 4; ++j) b1[j] = *(const bf16x8*)(Bp[j] + kt + 32);
#pragma unroll
        for (int i = 0; i < 4; ++i)
#pragma unroll
            for (int j = 0; j < 4; ++j)
                acc[i][j] = __builtin_amdgcn_mfma_f32_16x16x32_bf16(a0[i], b0[j], acc[i][j], 0, 0, 0);
        int kn = kt + 64; if (kn >= K) kn = 0;
        ldA(kn, a0);
#pragma unroll
        for (int j = 0; j < 4; ++j) b0[j] = *(const bf16x8*)(Bp[j] + kn);
#pragma unroll
        for (int i = 0; i < 4; ++i)
#pragma unroll
            for (int j = 0; j < 4; ++j)
                acc[i][j] = __builtin_amdgcn_mfma_f32_16x16x32_bf16(a1[i], b1[j], acc[i][j], 0, 0, 0);
    }

#pragma unroll
    for (int i = 0; i < 4; ++i) {
        int rowb = m0 + wm + i * 16 + lq * 4;
#pragma unroll
        for (int rr = 0; rr < 4; ++rr) {
            int gm = rowb + rr;
            if (gm < M) {
                int g = PoolOut ? batch[gm] : 0;
#pragma unroll
                for (int j = 0; j < 4; ++j) {
                    int gn = wn + j * 16 + l15;
                    float v = fmaxf(acc[i][j][rr] + bias[gn], 0.f);
                    if (PoolOut) atomicAdd(&pooled[(long)g * 256 + gn], v);
                    else         Cout[(long)gm * 256 + gn] = (bf16)v;
                }
            }
        }
    }
}

// ---------------------------------------------------------------------------
// CSR build
__global__ void k_hist(const int* __restrict__ ei, const int* __restrict__ et,
                       int* __restrict__ hist)
{
    int e = blockIdx.x * 256 + threadIdx.x;
    if (e >= kE) return;
    atomicAdd(&hist[ei[kE + e] * 4 + et[e]], 1);
}

__global__ void k_scan1(const int* __restrict__ hist, int* __restrict__ bsum)
{
    __shared__ int sd[256];
    int i = blockIdx.x * 256 + threadIdx.x;
    sd[threadIdx.x] = (i < kSeg) ? hist[i] : 0;
    __syncthreads();
    for (int o = 128; o > 0; o >>= 1) {
        if (threadIdx.x < o) sd[threadIdx.x] += sd[threadIdx.x + o];
        __syncthreads();
    }
    if (threadIdx.x == 0) bsum[blockIdx.x] = sd[0];
}

__global__ __launch_bounds__(1024) void k_scan2(const int* __restrict__ bsum,
                                                int* __restrict__ boff)
{
    __shared__ int sd[1024];
    int t = threadIdx.x;
    sd[t] = (t < kScanB) ? bsum[t] : 0;
    __syncthreads();
    for (int o = 1; o < 1024; o <<= 1) {
        int v = (t >= o) ? sd[t - o] : 0;
        __syncthreads();
        sd[t] += v;
        __syncthreads();
    }
    if (t < kScanB) boff[t] = (t == 0) ? 0 : sd[t - 1];
}

__global__ void k_scan3(const int* __restrict__ hist, const int* __restrict__ boff,
                        int* __restrict__ row_ptr, int* __restrict__ cursor)
{
    __shared__ int sd[256];
    int i = blockIdx.x * 256 + threadIdx.x;
    int v = (i < kSeg) ? hist[i] : 0;
    sd[threadIdx.x] = v;
    __syncthreads();
    for (int o = 1; o < 256; o <<= 1) {
        int u = (threadIdx.x >= o) ? sd[threadIdx.x - o] : 0;
        __syncthreads();
        sd[threadIdx.x] += u;
        __syncthreads();
    }
    if (i <= kSeg) {
        int excl = boff[blockIdx.x] + sd[threadIdx.x] - v;
        row_ptr[i] = excl;
        if (i < kSeg) cursor[i] = excl;
    }
}

__global__ void k_fill(const int* __restrict__ ei, const int* __restrict__ et,
                       int* __restrict__ cursor, int* __restrict__ srcidx)
{
    int e = blockIdx.x * 256 + threadIdx.x;
    if (e >= kE) return;
    int key = ei[kE + e] * 4 + et[e];
    int pos = atomicAdd(&cursor[key], 1);
    srcidx[pos] = ei[e];
}

// ---------------------------------------------------------------------------
// layer-1 aggregate: a1b[r][d][ch] = bf16( x[d][ch] + sum_src x[src][ch] ), ch<11
__global__ void k_agg11(const float* __restrict__ x, const int* __restrict__ srcidx,
                        const int* __restrict__ row_ptr, bf16* __restrict__ a1b)
{
    long gid = (long)blockIdx.x * 256 + threadIdx.x;
    if (gid >= (long)kSeg * 32) return;
    int ch  = (int)(gid & 31);
    int seg = (int)(gid >> 5);
    int d = seg >> 2, r = seg & 3;
    float acc = 0.f;
    if (ch < 11) {
        acc = x[(long)d * 11 + ch];
        int i0 = row_ptr[seg], i1 = row_ptr[seg + 1];
        for (int i = i0; i < i1; ++i) acc += x[(long)srcidx[i] * 11 + ch];
    }
    a1b[((long)r * kN + d) * 32 + ch] = (bf16)acc;
}

// x [N,11] fp32 -> xb1 [N,64] bf16 zero-padded
__global__ void k_xpad(const float* __restrict__ x, bf16* __restrict__ xb1)
{
    int gid = blockIdx.x * 256 + threadIdx.x;
    if (gid >= kN * 64) return;
    int c = gid & 63, d = gid >> 6;
    xb1[gid] = (c < 11) ? (bf16)x[(long)d * 11 + c] : (bf16)0.f;
}

// weight transpose-pack: in [K,N] fp32 -> out[n*ldout + coff + k] bf16
__global__ void k_wt_s(const float* __restrict__ in, bf16* __restrict__ out,
                       int K, int N, int ldout, int coff)
{
    int i = blockIdx.x * 256 + threadIdx.x;
    if (i >= K * N) return;
    int n = i / K, k = i - n * K;
    out[(long)n * ldout + coff + k] = (bf16)in[(long)k * N + n];
}

// layer-1 w1 pack: [4][11][256] fp32 -> [4][256][32] bf16 zero-padded
__global__ void k_wtL1(const float* __restrict__ w1, bf16* __restrict__ out)
{
    int i = blockIdx.x * 256 + threadIdx.x;
    if (i >= 4 * 256 * 32) return;
    int r = i >> 13, rem = i & 8191, n = rem >> 5, k = rem & 31;
    out[i] = (k < 11) ? (bf16)w1[(long)r * 11 * 256 + (long)k * 256 + n] : (bf16)0.f;
}

__global__ void k_bn_params(const float* __restrict__ stats,
                            const float* __restrict__ g, const float* __restrict__ bt,
                            float* __restrict__ scl, float* __restrict__ shf)
{
    int c = blockIdx.x * 256 + threadIdx.x;  // < 1024
    const float invN = 1.0f / (float)kN;
    float mu  = stats[c] * invN;
    float var = stats[1024 + c] * invN - mu * mu;
    float sc  = g[c] * rsqrtf(var + 1e-5f);
    scl[c] = sc;
    shf[c] = bt[c] - mu * sc;
}

__global__ void k_bias_total(const float* sb0, const float* b20,
                             const float* sb1, const float* b21,
                             const float* sb2, const float* b22,
                             float* __restrict__ btt)
{
    int l = blockIdx.x, j = threadIdx.x;
    const float* sb = (l == 0) ? sb0 : (l == 1) ? sb1 : sb2;
    const float* b2 = (l == 0) ? b20 : (l == 1) ? b21 : b22;
    float v = sb[j];
#pragma unroll
    for (int r = 0; r < 4; ++r) v += b2[r * 256 + j];
    btt[l * 256 + j] = v;
}

__global__ void k_counts(const int* __restrict__ batch, float* __restrict__ counts)
{
    int v = blockIdx.x * 256 + threadIdx.x;
    if (v < kN) atomicAdd(&counts[batch[v]], 1.0f);
}

__global__ __launch_bounds__(64) void k_head(const float* __restrict__ pooled,
                                             const float* __restrict__ counts,
                                             const float* __restrict__ lw,
                                             const float* __restrict__ lb,
                                             float* __restrict__ out)
{
    int g = blockIdx.x;
    int l = threadIdx.x;
    float inv = 1.0f / fmaxf(counts[g], 1.0f);
    float acc[kT];
#pragma unroll
    for (int t = 0; t < kT; ++t) acc[t] = 0.f;
    for (int k = l; k < 256; k += 64) {
        float p = pooled[((long)g << 8) + k] * inv;
#pragma unroll
        for (int t = 0; t < kT; ++t) acc[t] = fmaf(p, lw[k * kT + t], acc[t]);
    }
#pragma unroll
    for (int off = 32; off > 0; off >>= 1)
#pragma unroll
        for (int t = 0; t < kT; ++t) acc[t] += __shfl_down(acc[t], off);
    if (l == 0) {
#pragma unroll
        for (int t = 0; t < kT; ++t) out[(long)g * kT + t] = acc[t] + lb[t];
    }
}

// ---------------------------------------------------------------------------
extern "C" void kernel_launch(void* const* d_in, const int* in_sizes, int n_in,
                              void* d_out, int out_size, void* d_ws, size_t ws_size,
                              hipStream_t stream)
{
    const float* x     = (const float*)d_in[0];
    const int*   ei    = (const int*)d_in[1];
    const int*   et    = (const int*)d_in[2];
    const int*   batch = (const int*)d_in[3];

    const float *sw[3], *sb[3], *w1[3], *gmm[3], *btm[3], *w2[3], *b2[3];
    for (int l = 0; l < 3; ++l) {
        int b = 4 + l * 8;
        sw[l]  = (const float*)d_in[b + 0];
        sb[l]  = (const float*)d_in[b + 1];
        w1[l]  = (const float*)d_in[b + 2];
        // b+3 = b1 (cancels inside BatchNorm)
        gmm[l] = (const float*)d_in[b + 4];
        btm[l] = (const float*)d_in[b + 5];
        w2[l]  = (const float*)d_in[b + 6];
        b2[l]  = (const float*)d_in[b + 7];
    }
    const float* lin_w = (const float*)d_in[28];
    const float* lin_b = (const float*)d_in[29];
    float* out = (float*)d_out;
    (void)in_sizes; (void)n_in; (void)out_size;

    // ---- workspace (~184 MB) ----
    char* wsb = (char*)d_ws;
    size_t off = 0;
    auto alloc = [&](size_t bytes) { void* p = wsb + off; off = (off + bytes + 255) & ~(size_t)255; return p; };
    bf16*  Pb0    = (bf16*) alloc((size_t)kN * 256 * 2);
    bf16*  Pb1    = (bf16*) alloc((size_t)kN * 256 * 2);
    bf16*  h1     = (bf16*) alloc((size_t)kN * 1024 * 2);
    bf16*  a1b    = (bf16*) alloc((size_t)4 * kN * 32 * 2);
    bf16*  xb1    = (bf16*) alloc((size_t)kN * 64 * 2);
    bf16*  w1t    = (bf16*) alloc((size_t)2 * 4 * 65536 * 2);   // layers 2,3
    bf16*  w1tL1  = (bf16*) alloc((size_t)4 * 256 * 32 * 2);
    bf16*  Bc0    = (bf16*) alloc((size_t)256 * 1088 * 2);
    bf16*  Bc1    = (bf16*) alloc((size_t)256 * 1280 * 2);
    bf16*  Bc2    = (bf16*) alloc((size_t)256 * 1280 * 2);
    int*   hist   = (int*)  alloc((size_t)(kSeg + 1) * 4);
    int*   row_ptr= (int*)  alloc((size_t)(kSeg + 1) * 4);
    int*   cursor = (int*)  alloc((size_t)kSeg * 4);
    int*   srcidx = (int*)  alloc((size_t)kE * 4);
    int*   bsum   = (int*)  alloc((size_t)kScanB * 4);
    int*   boff   = (int*)  alloc((size_t)kScanB * 4);
    float* stats  = (float*)alloc(2048 * 4);
    float* scl    = (float*)alloc(1024 * 4);
    float* shf    = (float*)alloc(1024 * 4);
    float* btt    = (float*)alloc(3 * 256 * 4);
    float* pooled = (float*)alloc((size_t)kG * 256 * 4);
    float* counts = (float*)alloc(kG * 4);
    if (ws_size < off) return;  // clean absmax-fail instead of OOB crash

    const dim3 gR((kN + 127) / 128, 4);   // GEMM1 grids (512 thr)
    const dim3 g2((kN + 127) / 128);      // GEMM2 grid  (512 thr)

    // ---- CSR build (parallel scan) + weight prepack ----
    hipMemsetAsync(hist, 0, (size_t)(kSeg + 1) * 4, stream);
    k_hist<<<(kE + 255) / 256, 256, 0, stream>>>(ei, et, hist);
    k_scan1<<<kScanB, 256, 0, stream>>>(hist, bsum);
    k_scan2<<<1, 1024, 0, stream>>>(bsum, boff);
    k_scan3<<<kScanB, 256, 0, stream>>>(hist, boff, row_ptr, cursor);
    k_fill<<<(kE + 255) / 256, 256, 0, stream>>>(ei, et, cursor, srcidx);

    k_bias_total<<<3, 256, 0, stream>>>(sb[0], b2[0], sb[1], b2[1], sb[2], b2[2], btt);
    k_xpad<<<(kN * 64 + 255) / 256, 256, 0, stream>>>(x, xb1);
    k_wtL1<<<(4 * 256 * 32 + 255) / 256, 256, 0, stream>>>(w1[0], w1tL1);
    for (int l = 1; l < 3; ++l)
        for (int r = 0; r < 4; ++r)
            k_wt_s<<<256, 256, 0, stream>>>(w1[l] + (long)r * 65536,
                                            w1t + (long)(l - 1) * 4 * 65536 + (long)r * 65536,
                                            256, 256, 256, 0);
    hipMemsetAsync(Bc0, 0, (size_t)256 * 1088 * 2, stream);
    k_wt_s<<<(11 * 256 + 255) / 256, 256, 0, stream>>>(sw[0], Bc0, 11, 256, 1088, 0);
    k_wt_s<<<1024, 256, 0, stream>>>(w2[0], Bc0, 1024, 256, 1088, 64);
    k_wt_s<<<256, 256, 0, stream>>>(sw[1], Bc1, 256, 256, 1280, 0);
    k_wt_s<<<1024, 256, 0, stream>>>(w2[1], Bc1, 1024, 256, 1280, 256);
    k_wt_s<<<256, 256, 0, stream>>>(sw[2], Bc2, 256, 256, 1280, 0);
    k_wt_s<<<1024, 256, 0, stream>>>(w2[2], Bc2, 1024, 256, 1280, 256);

    k_counts<<<(kN + 255) / 256, 256, 0, stream>>>(batch, counts);  // counts poisoned -> must init
    hipMemsetAsync(pooled, 0, (size_t)kG * 256 * 4, stream);

    // ---------------- layer 1 ----------------
    k_agg11<<<(int)(((long)kSeg * 32 + 255) / 256), 256, 0, stream>>>(x, srcidx, row_ptr, a1b);
    hipMemsetAsync(stats, 0, 2048 * 4, stream);
    k_l1gemm<<<gR, 512, 0, stream>>>(a1b, w1tL1, h1, stats);
    k_bn_params<<<4, 256, 0, stream>>>(stats, gmm[0], btm[0], scl, shf);
    k_gemm2<false><<<g2, 512, 0, stream>>>(xb1, 64, 64, h1, 1024, 1024, Bc0,
                                           Pb0, kN, btt + 0, scl, shf, nullptr, nullptr);

    // ---------------- layer 2 ----------------
    hipMemsetAsync(stats, 0, 2048 * 4, stream);
    k_rgin1<<<gR, 512, 0, stream>>>(Pb0, srcidx, row_ptr, w1t, h1, stats);
    k_bn_params<<<4, 256, 0, stream>>>(stats, gmm[1], btm[1], scl, shf);
    k_gemm2<false><<<g2, 512, 0, stream>>>(Pb0, 256, 256, h1, 1024, 1024, Bc1,
                                           Pb1, kN, btt + 256, scl, shf, nullptr, nullptr);

    // ---------------- layer 3 (pool fused into GEMM2) ----------------
    hipMemsetAsync(stats, 0, 2048 * 4, stream);
    k_rgin1<<<gR, 512, 0, stream>>>(Pb1, srcidx, row_ptr, w1t + (size_t)4 * 65536, h1, stats);
    k_bn_params<<<4, 256, 0, stream>>>(stats, gmm[2], btm[2], scl, shf);
    k_gemm2<true><<<g2, 512, 0, stream>>>(Pb1, 256, 256, h1, 1024, 1024, Bc2,
                                          nullptr, kN, btt + 512, scl, shf, batch, pooled);

    // ---------------- head ----------------
    k_head<<<kG, 64, 0, stream>>>(pooled, counts, lin_w, lin_b, out);
}

// Round 7
// 1244.443 us; speedup vs baseline: 5.1986x; 1.0887x over previous
//
#include <hip/hip_runtime.h>

static const int kN = 50000;   // nodes
static const int kE = 300000;  // edges
static const int kG = 2048;    // graphs
static const int kT = 19;      // targets
static const int kSeg = kN * 4;  // CSR segments: key = dst*4 + rel
static const int kScanB = (kSeg + 256) / 256;  // 784 blocks covers kSeg+1

typedef __bf16 bf16;
typedef __bf16 bf16x8 __attribute__((ext_vector_type(8)));
typedef __bf16 bf16x4 __attribute__((ext_vector_type(4)));
typedef float  f32x4  __attribute__((ext_vector_type(4)));

// ---------------------------------------------------------------------------
// GEMM1 layers 2/3: aggregate (CSR, +self) into LDS, then MFMA vs w1t[r].
// Grid (ceil(N/128), 4=rel), 512 threads (8 waves, 2m x 4n of 64x64).
// Aggregation: one wave per row, lane = 4 ch (coalesced full-row gathers).
// Layouts (m89/m91-verified): A/B idx=lane&15,k=(lane>>4)*8+j;
//                             C/D row=(lane>>4)*4+reg, col=lane&15.
// ---------------------------------------------------------------------------
__global__ __launch_bounds__(512) void k_rgin1(
    const bf16* __restrict__ Pb, const int* __restrict__ srcidx,
    const int* __restrict__ row_ptr, const bf16* __restrict__ w1t,
    bf16* __restrict__ h1, float* __restrict__ stats)
{
    __shared__ bf16 As[128][264];   // row stride 264 bf16 = 132 dwords (pad)
    const int t = threadIdx.x;
    const int r = blockIdx.y;
    const int m0 = blockIdx.x * 128;
    const int wave = t >> 6, lane = t & 63;

    // ---- phase 1: aggregate 128 rows x 256 ch into LDS (wave per row) ----
    for (int row = wave; row < 128; row += 8) {
        int dst = m0 + row;
        int dc  = dst < kN ? dst : kN - 1;   // clamp: safe read, stores guarded
        int seg = dc * 4 + r;
        int i0 = row_ptr[seg], i1 = row_ptr[seg + 1];
        bf16x4 sv = ((const bf16x4*)(Pb + (long)dc * 256))[lane];
        f32x4 a = {(float)sv[0], (float)sv[1], (float)sv[2], (float)sv[3]};
        int i = i0;
        for (; i + 1 < i1; i += 2) {
            int s0 = srcidx[i], s1 = srcidx[i + 1];
            bf16x4 v0 = ((const bf16x4*)(Pb + (long)s0 * 256))[lane];
            bf16x4 v1 = ((const bf16x4*)(Pb + (long)s1 * 256))[lane];
            a[0] += (float)v0[0] + (float)v1[0];
            a[1] += (float)v0[1] + (float)v1[1];
            a[2] += (float)v0[2] + (float)v1[2];
            a[3] += (float)v0[3] + (float)v1[3];
        }
        if (i < i1) {
            bf16x4 v0 = ((const bf16x4*)(Pb + (long)srcidx[i] * 256))[lane];
            a[0] += (float)v0[0]; a[1] += (float)v0[1];
            a[2] += (float)v0[2]; a[3] += (float)v0[3];
        }
        bf16x4 o = {(bf16)a[0], (bf16)a[1], (bf16)a[2], (bf16)a[3]};
        *(bf16x4*)&As[row][lane * 4] = o;
    }
    __syncthreads();

    // ---- phase 2: MFMA from LDS, B direct-load double-buffered ----
    const int l15 = lane & 15, lq = lane >> 4, koff = lq * 8;
    const int wm = (wave & 1) * 64, wn = (wave >> 1) * 64;

    const bf16* Bt = w1t + (long)r * 65536;
    const bf16* Bp[4];
#pragma unroll
    for (int j = 0; j < 4; ++j)
        Bp[j] = Bt + (long)(wn + j * 16 + l15) * 256 + koff;
    const bf16* Ar[4];
#pragma unroll
    for (int i = 0; i < 4; ++i) Ar[i] = &As[wm + i * 16 + l15][koff];

    f32x4 acc[4][4];
#pragma unroll
    for (int i = 0; i < 4; ++i)
#pragma unroll
        for (int j = 0; j < 4; ++j) acc[i][j] = (f32x4){0.f, 0.f, 0.f, 0.f};

    bf16x8 b0[4], b1[4];
#pragma unroll
    for (int j = 0; j < 4; ++j) b0[j] = *(const bf16x8*)(Bp[j]);
#pragma unroll
    for (int kt = 0; kt < 256; kt += 32) {
        int kn = kt + 32; if (kn >= 256) kn = 0;
#pragma unroll
        for (int j = 0; j < 4; ++j) b1[j] = *(const bf16x8*)(Bp[j] + kn);
        bf16x8 a[4];
#pragma unroll
        for (int i = 0; i < 4; ++i) a[i] = *(const bf16x8*)(Ar[i] + kt);
#pragma unroll
        for (int i = 0; i < 4; ++i)
#pragma unroll
            for (int j = 0; j < 4; ++j)
                acc[i][j] = __builtin_amdgcn_mfma_f32_16x16x32_bf16(a[i], b0[j], acc[i][j], 0, 0, 0);
#pragma unroll
        for (int j = 0; j < 4; ++j) b0[j] = b1[j];
    }

    // ---- epilogue: store h1 + fused stats ----
    const int cB = r * 256;
    float sv[4] = {0,0,0,0}, qv[4] = {0,0,0,0};
#pragma unroll
    for (int i = 0; i < 4; ++i) {
        int rowb = m0 + wm + i * 16 + lq * 4;
#pragma unroll
        for (int rr = 0; rr < 4; ++rr) {
            int gm = rowb + rr;
            if (gm < kN) {
#pragma unroll
                for (int j = 0; j < 4; ++j) {
                    int gn = wn + j * 16 + l15;
                    bf16 bv = (bf16)acc[i][j][rr];
                    h1[(long)gm * 1024 + cB + gn] = bv;
                    float f = (float)bv;
                    sv[j] += f; qv[j] += f * f;
                }
            }
        }
    }
#pragma unroll
    for (int j = 0; j < 4; ++j) {
        float s = sv[j], q = qv[j];
        s += __shfl_xor(s, 16); s += __shfl_xor(s, 32);
        q += __shfl_xor(q, 16); q += __shfl_xor(q, 32);
        if (lq == 0) {
            int gn = cB + wn + j * 16 + l15;
            atomicAdd(&stats[gn], s);
            atomicAdd(&stats[1024 + gn], q);
        }
    }
}

// ---------------------------------------------------------------------------
// GEMM1 layer 1: A = a1b[r] [N,32] bf16 (K=32, one MFMA step) + fused stats.
// Grid (ceil(N/128), 4), 512 threads.
// ---------------------------------------------------------------------------
__global__ __launch_bounds__(512) void k_l1gemm(
    const bf16* __restrict__ a1b, const bf16* __restrict__ w1tL1,
    bf16* __restrict__ h1, float* __restrict__ stats)
{
    const int t = threadIdx.x;
    const int r = blockIdx.y;
    const int m0 = blockIdx.x * 128;
    const int wave = t >> 6, lane = t & 63;
    const int l15 = lane & 15, lq = lane >> 4, koff = lq * 8;
    const int wm = (wave & 1) * 64, wn = (wave >> 1) * 64;

    bf16x8 a[4], b[4];
#pragma unroll
    for (int i = 0; i < 4; ++i) {
        int gm = m0 + wm + i * 16 + l15;
        if (gm >= kN) gm = kN - 1;
        a[i] = *(const bf16x8*)(a1b + ((long)r * kN + gm) * 32 + koff);
    }
#pragma unroll
    for (int j = 0; j < 4; ++j)
        b[j] = *(const bf16x8*)(w1tL1 + (long)r * 8192 + (long)(wn + j * 16 + l15) * 32 + koff);

    f32x4 acc[4][4];
#pragma unroll
    for (int i = 0; i < 4; ++i)
#pragma unroll
        for (int j = 0; j < 4; ++j)
            acc[i][j] = __builtin_amdgcn_mfma_f32_16x16x32_bf16(a[i], b[j],
                        (f32x4){0.f, 0.f, 0.f, 0.f}, 0, 0, 0);

    const int cB = r * 256;
    float sv[4] = {0,0,0,0}, qv[4] = {0,0,0,0};
#pragma unroll
    for (int i = 0; i < 4; ++i) {
        int rowb = m0 + wm + i * 16 + lq * 4;
#pragma unroll
        for (int rr = 0; rr < 4; ++rr) {
            int gm = rowb + rr;
            if (gm < kN) {
#pragma unroll
                for (int j = 0; j < 4; ++j) {
                    int gn = wn + j * 16 + l15;
                    bf16 bv = (bf16)acc[i][j][rr];
                    h1[(long)gm * 1024 + cB + gn] = bv;
                    float f = (float)bv;
                    sv[j] += f; qv[j] += f * f;
                }
            }
        }
    }
#pragma unroll
    for (int j = 0; j < 4; ++j) {
        float s = sv[j], q = qv[j];
        s += __shfl_xor(s, 16); s += __shfl_xor(s, 32);
        q += __shfl_xor(q, 16); q += __shfl_xor(q, 32);
        if (lq == 0) {
            int gn = cB + wn + j * 16 + l15;
            atomicAdd(&stats[gn], s);
            atomicAdd(&stats[1024 + gn], q);
        }
    }
}

// ---------------------------------------------------------------------------
// GEMM2 (LDS-staged): C = relu( [A1 | relu(BN(A2))] @ Bt^T + bias ).
// Grid ceil(M/64), 256 thr (4 waves, each n-slice 64 of the 256 cols).
// K chunked by 128 into padded LDS As[64][136] (stride%32==4 dwords ->
// 2-way bank aliasing, free). BN applied ONCE at staging (off MFMA path).
// PoolOut: atomicAdd rows into pooled[batch].
// ---------------------------------------------------------------------------
template<bool PoolOut>
__global__ __launch_bounds__(256) void k_gemm2(
    const bf16* __restrict__ A1, int lda1, int K1,
    const bf16* __restrict__ A2, int lda2, int K2,
    const bf16* __restrict__ Bt,
    bf16* __restrict__ Cout,
    int M, const float* __restrict__ bias,
    const float* __restrict__ scl, const float* __restrict__ shf,
    const int* __restrict__ batch, float* __restrict__ pooled)
{
    const int K = K1 + K2;
    __shared__ bf16 As[64][136];
    const int t = threadIdx.x;
    const int wave = t >> 6, lane = t & 63;
    const int l15 = lane & 15, lq = lane >> 4, koff = lq * 8;
    const int wn = wave * 64;
    const int m0 = blockIdx.x * 64;

    const bf16* Bp[4];
#pragma unroll
    for (int j = 0; j < 4; ++j)
        Bp[j] = Bt + (long)(wn + j * 16 + l15) * K + koff;

    f32x4 acc[4][4];
#pragma unroll
    for (int i = 0; i < 4; ++i)
#pragma unroll
        for (int j = 0; j < 4; ++j) acc[i][j] = (f32x4){0.f, 0.f, 0.f, 0.f};

    for (int kc = 0; kc < K; kc += 128) {
        const int kw = (K - kc < 128) ? (K - kc) : 128;   // 128 or 64 tail
        __syncthreads();   // previous chunk's LDS reads done
        // ---- stage 64 rows x kw cols (16B groups) ----
        const int wide = (kw == 128);
        const int groups = wide ? 1024 : 512;
        for (int g = t; g < groups; g += 256) {
            int row = wide ? (g >> 4) : (g >> 3);
            int kg  = (wide ? (g & 15) : (g & 7)) * 8;
            int gm = m0 + row; if (gm >= M) gm = M - 1;
            int gk = kc + kg;
            bf16x8 v;
            if (gk < K1) {
                v = *(const bf16x8*)(A1 + (long)gm * lda1 + gk);
            } else {
                int k2 = gk - K1;
                bf16x8 h = *(const bf16x8*)(A2 + (long)gm * lda2 + k2);
                float4 s0 = *(const float4*)(scl + k2);
                float4 s1 = *(const float4*)(scl + k2 + 4);
                float4 t0 = *(const float4*)(shf + k2);
                float4 t1 = *(const float4*)(shf + k2 + 4);
                float sa[8] = {s0.x,s0.y,s0.z,s0.w,s1.x,s1.y,s1.z,s1.w};
                float ta[8] = {t0.x,t0.y,t0.z,t0.w,t1.x,t1.y,t1.z,t1.w};
#pragma unroll
                for (int u = 0; u < 8; ++u)
                    v[u] = (bf16)fmaxf(0.f, fmaf((float)h[u], sa[u], ta[u]));
            }
            *(bf16x8*)&As[row][kg] = v;
        }
        __syncthreads();
        // ---- MFMA over this chunk ----
        for (int ks = 0; ks < kw; ks += 32) {
            bf16x8 b[4], a[4];
#pragma unroll
            for (int j = 0; j < 4; ++j) b[j] = *(const bf16x8*)(Bp[j] + kc + ks);
#pragma unroll
            for (int i = 0; i < 4; ++i) a[i] = *(const bf16x8*)&As[i * 16 + l15][ks + koff];
#pragma unroll
            for (int i = 0; i < 4; ++i)
#pragma unroll
                for (int j = 0; j < 4; ++j)
                    acc[i][j] = __builtin_amdgcn_mfma_f32_16x16x32_bf16(a[i], b[j], acc[i][j], 0, 0, 0);
        }
    }

#pragma unroll
    for (int i = 0; i < 4; ++i) {
        int rowb = m0 + i * 16 + lq * 4;
#pragma unroll
        for (int rr = 0; rr < 4; ++rr) {
            int gm = rowb + rr;
            if (gm < M) {
                int g = PoolOut ? batch[gm] : 0;
#pragma unroll
                for (int j = 0; j < 4; ++j) {
                    int gn = wn + j * 16 + l15;
                    float v = fmaxf(acc[i][j][rr] + bias[gn], 0.f);
                    if (PoolOut) atomicAdd(&pooled[(long)g * 256 + gn], v);
                    else         Cout[(long)gm * 256 + gn] = (bf16)v;
                }
            }
        }
    }
}

// ---------------------------------------------------------------------------
// CSR build
__global__ void k_hist(const int* __restrict__ ei, const int* __restrict__ et,
                       int* __restrict__ hist)
{
    int e = blockIdx.x * 256 + threadIdx.x;
    if (e >= kE) return;
    atomicAdd(&hist[ei[kE + e] * 4 + et[e]], 1);
}

__global__ void k_scan1(const int* __restrict__ hist, int* __restrict__ bsum)
{
    __shared__ int sd[256];
    int i = blockIdx.x * 256 + threadIdx.x;
    sd[threadIdx.x] = (i < kSeg) ? hist[i] : 0;
    __syncthreads();
    for (int o = 128; o > 0; o >>= 1) {
        if (threadIdx.x < o) sd[threadIdx.x] += sd[threadIdx.x + o];
        __syncthreads();
    }
    if (threadIdx.x == 0) bsum[blockIdx.x] = sd[0];
}

__global__ __launch_bounds__(1024) void k_scan2(const int* __restrict__ bsum,
                                                int* __restrict__ boff)
{
    __shared__ int sd[1024];
    int t = threadIdx.x;
    sd[t] = (t < kScanB) ? bsum[t] : 0;
    __syncthreads();
    for (int o = 1; o < 1024; o <<= 1) {
        int v = (t >= o) ? sd[t - o] : 0;
        __syncthreads();
        sd[t] += v;
        __syncthreads();
    }
    if (t < kScanB) boff[t] = (t == 0) ? 0 : sd[t - 1];
}

__global__ void k_scan3(const int* __restrict__ hist, const int* __restrict__ boff,
                        int* __restrict__ row_ptr, int* __restrict__ cursor)
{
    __shared__ int sd[256];
    int i = blockIdx.x * 256 + threadIdx.x;
    int v = (i < kSeg) ? hist[i] : 0;
    sd[threadIdx.x] = v;
    __syncthreads();
    for (int o = 1; o < 256; o <<= 1) {
        int u = (threadIdx.x >= o) ? sd[threadIdx.x - o] : 0;
        __syncthreads();
        sd[threadIdx.x] += u;
        __syncthreads();
    }
    if (i <= kSeg) {
        int excl = boff[blockIdx.x] + sd[threadIdx.x] - v;
        row_ptr[i] = excl;
        if (i < kSeg) cursor[i] = excl;
    }
}

__global__ void k_fill(const int* __restrict__ ei, const int* __restrict__ et,
                       int* __restrict__ cursor, int* __restrict__ srcidx)
{
    int e = blockIdx.x * 256 + threadIdx.x;
    if (e >= kE) return;
    int key = ei[kE + e] * 4 + et[e];
    int pos = atomicAdd(&cursor[key], 1);
    srcidx[pos] = ei[e];
}

// ---------------------------------------------------------------------------
// layer-1 aggregate: a1b[r][d][ch] = bf16( x[d][ch] + sum_src x[src][ch] ), ch<11
__global__ void k_agg11(const float* __restrict__ x, const int* __restrict__ srcidx,
                        const int* __restrict__ row_ptr, bf16* __restrict__ a1b)
{
    long gid = (long)blockIdx.x * 256 + threadIdx.x;
    if (gid >= (long)kSeg * 32) return;
    int ch  = (int)(gid & 31);
    int seg = (int)(gid >> 5);
    int d = seg >> 2, r = seg & 3;
    float acc = 0.f;
    if (ch < 11) {
        acc = x[(long)d * 11 + ch];
        int i0 = row_ptr[seg], i1 = row_ptr[seg + 1];
        for (int i = i0; i < i1; ++i) acc += x[(long)srcidx[i] * 11 + ch];
    }
    a1b[((long)r * kN + d) * 32 + ch] = (bf16)acc;
}

// x [N,11] fp32 -> xb1 [N,64] bf16 zero-padded
__global__ void k_xpad(const float* __restrict__ x, bf16* __restrict__ xb1)
{
    int gid = blockIdx.x * 256 + threadIdx.x;
    if (gid >= kN * 64) return;
    int c = gid & 63, d = gid >> 6;
    xb1[gid] = (c < 11) ? (bf16)x[(long)d * 11 + c] : (bf16)0.f;
}

// weight transpose-pack: in [K,N] fp32 -> out[n*ldout + coff + k] bf16
__global__ void k_wt_s(const float* __restrict__ in, bf16* __restrict__ out,
                       int K, int N, int ldout, int coff)
{
    int i = blockIdx.x * 256 + threadIdx.x;
    if (i >= K * N) return;
    int n = i / K, k = i - n * K;
    out[(long)n * ldout + coff + k] = (bf16)in[(long)k * N + n];
}

// layer-1 w1 pack: [4][11][256] fp32 -> [4][256][32] bf16 zero-padded
__global__ void k_wtL1(const float* __restrict__ w1, bf16* __restrict__ out)
{
    int i = blockIdx.x * 256 + threadIdx.x;
    if (i >= 4 * 256 * 32) return;
    int r = i >> 13, rem = i & 8191, n = rem >> 5, k = rem & 31;
    out[i] = (k < 11) ? (bf16)w1[(long)r * 11 * 256 + (long)k * 256 + n] : (bf16)0.f;
}

__global__ void k_bn_params(const float* __restrict__ stats,
                            const float* __restrict__ g, const float* __restrict__ bt,
                            float* __restrict__ scl, float* __restrict__ shf)
{
    int c = blockIdx.x * 256 + threadIdx.x;  // < 1024
    const float invN = 1.0f / (float)kN;
    float mu  = stats[c] * invN;
    float var = stats[1024 + c] * invN - mu * mu;
    float sc  = g[c] * rsqrtf(var + 1e-5f);
    scl[c] = sc;
    shf[c] = bt[c] - mu * sc;
}

__global__ void k_bias_total(const float* sb0, const float* b20,
                             const float* sb1, const float* b21,
                             const float* sb2, const float* b22,
                             float* __restrict__ btt)
{
    int l = blockIdx.x, j = threadIdx.x;
    const float* sb = (l == 0) ? sb0 : (l == 1) ? sb1 : sb2;
    const float* b2 = (l == 0) ? b20 : (l == 1) ? b21 : b22;
    float v = sb[j];
#pragma unroll
    for (int r = 0; r < 4; ++r) v += b2[r * 256 + j];
    btt[l * 256 + j] = v;
}

__global__ void k_counts(const int* __restrict__ batch, float* __restrict__ counts)
{
    int v = blockIdx.x * 256 + threadIdx.x;
    if (v < kN) atomicAdd(&counts[batch[v]], 1.0f);
}

__global__ __launch_bounds__(64) void k_head(const float* __restrict__ pooled,
                                             const float* __restrict__ counts,
                                             const float* __restrict__ lw,
                                             const float* __restrict__ lb,
                                             float* __restrict__ out)
{
    int g = blockIdx.x;
    int l = threadIdx.x;
    float inv = 1.0f / fmaxf(counts[g], 1.0f);
    float acc[kT];
#pragma unroll
    for (int t = 0; t < kT; ++t) acc[t] = 0.f;
    for (int k = l; k < 256; k += 64) {
        float p = pooled[((long)g << 8) + k] * inv;
#pragma unroll
        for (int t = 0; t < kT; ++t) acc[t] = fmaf(p, lw[k * kT + t], acc[t]);
    }
#pragma unroll
    for (int off = 32; off > 0; off >>= 1)
#pragma unroll
        for (int t = 0; t < kT; ++t) acc[t] += __shfl_down(acc[t], off);
    if (l == 0) {
#pragma unroll
        for (int t = 0; t < kT; ++t) out[(long)g * kT + t] = acc[t] + lb[t];
    }
}

// ---------------------------------------------------------------------------
extern "C" void kernel_launch(void* const* d_in, const int* in_sizes, int n_in,
                              void* d_out, int out_size, void* d_ws, size_t ws_size,
                              hipStream_t stream)
{
    const float* x     = (const float*)d_in[0];
    const int*   ei    = (const int*)d_in[1];
    const int*   et    = (const int*)d_in[2];
    const int*   batch = (const int*)d_in[3];

    const float *sw[3], *sb[3], *w1[3], *gmm[3], *btm[3], *w2[3], *b2[3];
    for (int l = 0; l < 3; ++l) {
        int b = 4 + l * 8;
        sw[l]  = (const float*)d_in[b + 0];
        sb[l]  = (const float*)d_in[b + 1];
        w1[l]  = (const float*)d_in[b + 2];
        // b+3 = b1 (cancels inside BatchNorm)
        gmm[l] = (const float*)d_in[b + 4];
        btm[l] = (const float*)d_in[b + 5];
        w2[l]  = (const float*)d_in[b + 6];
        b2[l]  = (const float*)d_in[b + 7];
    }
    const float* lin_w = (const float*)d_in[28];
    const float* lin_b = (const float*)d_in[29];
    float* out = (float*)d_out;
    (void)in_sizes; (void)n_in; (void)out_size;

    // ---- workspace (~184 MB) ----
    char* wsb = (char*)d_ws;
    size_t off = 0;
    auto alloc = [&](size_t bytes) { void* p = wsb + off; off = (off + bytes + 255) & ~(size_t)255; return p; };
    bf16*  Pb0    = (bf16*) alloc((size_t)kN * 256 * 2);
    bf16*  Pb1    = (bf16*) alloc((size_t)kN * 256 * 2);
    bf16*  h1     = (bf16*) alloc((size_t)kN * 1024 * 2);
    bf16*  a1b    = (bf16*) alloc((size_t)4 * kN * 32 * 2);
    bf16*  xb1    = (bf16*) alloc((size_t)kN * 64 * 2);
    bf16*  w1t    = (bf16*) alloc((size_t)2 * 4 * 65536 * 2);   // layers 2,3
    bf16*  w1tL1  = (bf16*) alloc((size_t)4 * 256 * 32 * 2);
    bf16*  Bc0    = (bf16*) alloc((size_t)256 * 1088 * 2);
    bf16*  Bc1    = (bf16*) alloc((size_t)256 * 1280 * 2);
    bf16*  Bc2    = (bf16*) alloc((size_t)256 * 1280 * 2);
    int*   hist   = (int*)  alloc((size_t)(kSeg + 1) * 4);
    int*   row_ptr= (int*)  alloc((size_t)(kSeg + 1) * 4);
    int*   cursor = (int*)  alloc((size_t)kSeg * 4);
    int*   srcidx = (int*)  alloc((size_t)kE * 4);
    int*   bsum   = (int*)  alloc((size_t)kScanB * 4);
    int*   boff   = (int*)  alloc((size_t)kScanB * 4);
    float* stats  = (float*)alloc(2048 * 4);
    float* scl    = (float*)alloc(1024 * 4);
    float* shf    = (float*)alloc(1024 * 4);
    float* btt    = (float*)alloc(3 * 256 * 4);
    float* pooled = (float*)alloc((size_t)kG * 256 * 4);
    float* counts = (float*)alloc(kG * 4);
    if (ws_size < off) return;  // clean absmax-fail instead of OOB crash

    const dim3 gR((kN + 127) / 128, 4);   // GEMM1 grids (512 thr)
    const dim3 g2((kN + 63) / 64);        // GEMM2 grid  (256 thr, 782 blocks)

    // ---- CSR build (parallel scan) + weight prepack ----
    hipMemsetAsync(hist, 0, (size_t)(kSeg + 1) * 4, stream);
    k_hist<<<(kE + 255) / 256, 256, 0, stream>>>(ei, et, hist);
    k_scan1<<<kScanB, 256, 0, stream>>>(hist, bsum);
    k_scan2<<<1, 1024, 0, stream>>>(bsum, boff);
    k_scan3<<<kScanB, 256, 0, stream>>>(hist, boff, row_ptr, cursor);
    k_fill<<<(kE + 255) / 256, 256, 0, stream>>>(ei, et, cursor, srcidx);

    k_bias_total<<<3, 256, 0, stream>>>(sb[0], b2[0], sb[1], b2[1], sb[2], b2[2], btt);
    k_xpad<<<(kN * 64 + 255) / 256, 256, 0, stream>>>(x, xb1);
    k_wtL1<<<(4 * 256 * 32 + 255) / 256, 256, 0, stream>>>(w1[0], w1tL1);
    for (int l = 1; l < 3; ++l)
        for (int r = 0; r < 4; ++r)
            k_wt_s<<<256, 256, 0, stream>>>(w1[l] + (long)r * 65536,
                                            w1t + (long)(l - 1) * 4 * 65536 + (long)r * 65536,
                                            256, 256, 256, 0);
    hipMemsetAsync(Bc0, 0, (size_t)256 * 1088 * 2, stream);
    k_wt_s<<<(11 * 256 + 255) / 256, 256, 0, stream>>>(sw[0], Bc0, 11, 256, 1088, 0);
    k_wt_s<<<1024, 256, 0, stream>>>(w2[0], Bc0, 1024, 256, 1088, 64);
    k_wt_s<<<256, 256, 0, stream>>>(sw[1], Bc1, 256, 256, 1280, 0);
    k_wt_s<<<1024, 256, 0, stream>>>(w2[1], Bc1, 1024, 256, 1280, 256);
    k_wt_s<<<256, 256, 0, stream>>>(sw[2], Bc2, 256, 256, 1280, 0);
    k_wt_s<<<1024, 256, 0, stream>>>(w2[2], Bc2, 1024, 256, 1280, 256);

    k_counts<<<(kN + 255) / 256, 256, 0, stream>>>(batch, counts);  // counts poisoned -> must init
    hipMemsetAsync(pooled, 0, (size_t)kG * 256 * 4, stream);

    // ---------------- layer 1 ----------------
    k_agg11<<<(int)(((long)kSeg * 32 + 255) / 256), 256, 0, stream>>>(x, srcidx, row_ptr, a1b);
    hipMemsetAsync(stats, 0, 2048 * 4, stream);
    k_l1gemm<<<gR, 512, 0, stream>>>(a1b, w1tL1, h1, stats);
    k_bn_params<<<4, 256, 0, stream>>>(stats, gmm[0], btm[0], scl, shf);
    k_gemm2<false><<<g2, 256, 0, stream>>>(xb1, 64, 64, h1, 1024, 1024, Bc0,
                                           Pb0, kN, btt + 0, scl, shf, nullptr, nullptr);

    // ---------------- layer 2 ----------------
    hipMemsetAsync(stats, 0, 2048 * 4, stream);
    k_rgin1<<<gR, 512, 0, stream>>>(Pb0, srcidx, row_ptr, w1t, h1, stats);
    k_bn_params<<<4, 256, 0, stream>>>(stats, gmm[1], btm[1], scl, shf);
    k_gemm2<false><<<g2, 256, 0, stream>>>(Pb0, 256, 256, h1, 1024, 1024, Bc1,
                                           Pb1, kN, btt + 256, scl, shf, nullptr, nullptr);

    // ---------------- layer 3 (pool fused into GEMM2) ----------------
    hipMemsetAsync(stats, 0, 2048 * 4, stream);
    k_rgin1<<<gR, 512, 0, stream>>>(Pb1, srcidx, row_ptr, w1t + (size_t)4 * 65536, h1, stats);
    k_bn_params<<<4, 256, 0, stream>>>(stats, gmm[2], btm[2], scl, shf);
    k_gemm2<true><<<g2, 256, 0, stream>>>(Pb1, 256, 256, h1, 1024, 1024, Bc2,
                                          nullptr, kN, btt + 512, scl, shf, batch, pooled);

    // ---------------- head ----------------
    k_head<<<kG, 64, 0, stream>>>(pooled, counts, lin_w, lin_b, out);
}

// Round 8
// 1154.328 us; speedup vs baseline: 5.6045x; 1.0781x over previous
//
#include <hip/hip_runtime.h>

static const int kN = 50000;   // nodes
static const int kE = 300000;  // edges
static const int kG = 2048;    // graphs
static const int kT = 19;      // targets
static const int kSeg = kN * 4;  // CSR segments: key = dst*4 + rel
static const int kScanB = (kSeg + 256) / 256;  // 784 blocks covers kSeg+1

typedef __bf16 bf16;
typedef __bf16 bf16x8 __attribute__((ext_vector_type(8)));
typedef __bf16 bf16x4 __attribute__((ext_vector_type(4)));
typedef float  f32x4  __attribute__((ext_vector_type(4)));

// ---------------------------------------------------------------------------
// GEMM1 layers 2/3: aggregate (CSR, +self) into LDS, then MFMA vs w1t[r].
// Grid (ceil(N/128), 4=rel), 512 threads (8 waves, 2m x 4n of 64x64).
// Aggregation: one wave per row, lane = 4 ch (coalesced full-row gathers).
// Layouts (m89/m91-verified): A/B idx=lane&15,k=(lane>>4)*8+j;
//                             C/D row=(lane>>4)*4+reg, col=lane&15.
// ---------------------------------------------------------------------------
__global__ __launch_bounds__(512) void k_rgin1(
    const bf16* __restrict__ Pb, const int* __restrict__ srcidx,
    const int* __restrict__ row_ptr, const bf16* __restrict__ w1t,
    bf16* __restrict__ h1, float* __restrict__ stats)
{
    __shared__ bf16 As[128][264];   // row stride 264 bf16 = 132 dwords (pad)
    const int t = threadIdx.x;
    const int r = blockIdx.y;
    const int m0 = blockIdx.x * 128;
    const int wave = t >> 6, lane = t & 63;

    // ---- phase 1: aggregate 128 rows x 256 ch into LDS (wave per row) ----
    for (int row = wave; row < 128; row += 8) {
        int dst = m0 + row;
        int dc  = dst < kN ? dst : kN - 1;   // clamp: safe read, stores guarded
        int seg = dc * 4 + r;
        int i0 = row_ptr[seg], i1 = row_ptr[seg + 1];
        bf16x4 sv = ((const bf16x4*)(Pb + (long)dc * 256))[lane];
        f32x4 a = {(float)sv[0], (float)sv[1], (float)sv[2], (float)sv[3]};
        int i = i0;
        for (; i + 1 < i1; i += 2) {
            int s0 = srcidx[i], s1 = srcidx[i + 1];
            bf16x4 v0 = ((const bf16x4*)(Pb + (long)s0 * 256))[lane];
            bf16x4 v1 = ((const bf16x4*)(Pb + (long)s1 * 256))[lane];
            a[0] += (float)v0[0] + (float)v1[0];
            a[1] += (float)v0[1] + (float)v1[1];
            a[2] += (float)v0[2] + (float)v1[2];
            a[3] += (float)v0[3] + (float)v1[3];
        }
        if (i < i1) {
            bf16x4 v0 = ((const bf16x4*)(Pb + (long)srcidx[i] * 256))[lane];
            a[0] += (float)v0[0]; a[1] += (float)v0[1];
            a[2] += (float)v0[2]; a[3] += (float)v0[3];
        }
        bf16x4 o = {(bf16)a[0], (bf16)a[1], (bf16)a[2], (bf16)a[3]};
        *(bf16x4*)&As[row][lane * 4] = o;
    }
    __syncthreads();

    // ---- phase 2: MFMA from LDS, B direct-load double-buffered ----
    const int l15 = lane & 15, lq = lane >> 4, koff = lq * 8;
    const int wm = (wave & 1) * 64, wn = (wave >> 1) * 64;

    const bf16* Bt = w1t + (long)r * 65536;
    const bf16* Bp[4];
#pragma unroll
    for (int j = 0; j < 4; ++j)
        Bp[j] = Bt + (long)(wn + j * 16 + l15) * 256 + koff;
    const bf16* Ar[4];
#pragma unroll
    for (int i = 0; i < 4; ++i) Ar[i] = &As[wm + i * 16 + l15][koff];

    f32x4 acc[4][4];
#pragma unroll
    for (int i = 0; i < 4; ++i)
#pragma unroll
        for (int j = 0; j < 4; ++j) acc[i][j] = (f32x4){0.f, 0.f, 0.f, 0.f};

    bf16x8 b0[4], b1[4];
#pragma unroll
    for (int j = 0; j < 4; ++j) b0[j] = *(const bf16x8*)(Bp[j]);
#pragma unroll
    for (int kt = 0; kt < 256; kt += 32) {
        int kn = kt + 32; if (kn >= 256) kn = 0;
#pragma unroll
        for (int j = 0; j < 4; ++j) b1[j] = *(const bf16x8*)(Bp[j] + kn);
        bf16x8 a[4];
#pragma unroll
        for (int i = 0; i < 4; ++i) a[i] = *(const bf16x8*)(Ar[i] + kt);
#pragma unroll
        for (int i = 0; i < 4; ++i)
#pragma unroll
            for (int j = 0; j < 4; ++j)
                acc[i][j] = __builtin_amdgcn_mfma_f32_16x16x32_bf16(a[i], b0[j], acc[i][j], 0, 0, 0);
#pragma unroll
        for (int j = 0; j < 4; ++j) b0[j] = b1[j];
    }

    // ---- epilogue: store h1 + fused stats ----
    const int cB = r * 256;
    float sv[4] = {0,0,0,0}, qv[4] = {0,0,0,0};
#pragma unroll
    for (int i = 0; i < 4; ++i) {
        int rowb = m0 + wm + i * 16 + lq * 4;
#pragma unroll
        for (int rr = 0; rr < 4; ++rr) {
            int gm = rowb + rr;
            if (gm < kN) {
#pragma unroll
                for (int j = 0; j < 4; ++j) {
                    int gn = wn + j * 16 + l15;
                    bf16 bv = (bf16)acc[i][j][rr];
                    h1[(long)gm * 1024 + cB + gn] = bv;
                    float f = (float)bv;
                    sv[j] += f; qv[j] += f * f;
                }
            }
        }
    }
#pragma unroll
    for (int j = 0; j < 4; ++j) {
        float s = sv[j], q = qv[j];
        s += __shfl_xor(s, 16); s += __shfl_xor(s, 32);
        q += __shfl_xor(q, 16); q += __shfl_xor(q, 32);
        if (lq == 0) {
            int gn = cB + wn + j * 16 + l15;
            atomicAdd(&stats[gn], s);
            atomicAdd(&stats[1024 + gn], q);
        }
    }
}

// ---------------------------------------------------------------------------
// GEMM1 layer 1: A = a1b[r] [N,32] bf16 (K=32, one MFMA step) + fused stats.
// ---------------------------------------------------------------------------
__global__ __launch_bounds__(512) void k_l1gemm(
    const bf16* __restrict__ a1b, const bf16* __restrict__ w1tL1,
    bf16* __restrict__ h1, float* __restrict__ stats)
{
    const int t = threadIdx.x;
    const int r = blockIdx.y;
    const int m0 = blockIdx.x * 128;
    const int wave = t >> 6, lane = t & 63;
    const int l15 = lane & 15, lq = lane >> 4, koff = lq * 8;
    const int wm = (wave & 1) * 64, wn = (wave >> 1) * 64;

    bf16x8 a[4], b[4];
#pragma unroll
    for (int i = 0; i < 4; ++i) {
        int gm = m0 + wm + i * 16 + l15;
        if (gm >= kN) gm = kN - 1;
        a[i] = *(const bf16x8*)(a1b + ((long)r * kN + gm) * 32 + koff);
    }
#pragma unroll
    for (int j = 0; j < 4; ++j)
        b[j] = *(const bf16x8*)(w1tL1 + (long)r * 8192 + (long)(wn + j * 16 + l15) * 32 + koff);

    f32x4 acc[4][4];
#pragma unroll
    for (int i = 0; i < 4; ++i)
#pragma unroll
        for (int j = 0; j < 4; ++j)
            acc[i][j] = __builtin_amdgcn_mfma_f32_16x16x32_bf16(a[i], b[j],
                        (f32x4){0.f, 0.f, 0.f, 0.f}, 0, 0, 0);

    const int cB = r * 256;
    float sv[4] = {0,0,0,0}, qv[4] = {0,0,0,0};
#pragma unroll
    for (int i = 0; i < 4; ++i) {
        int rowb = m0 + wm + i * 16 + lq * 4;
#pragma unroll
        for (int rr = 0; rr < 4; ++rr) {
            int gm = rowb + rr;
            if (gm < kN) {
#pragma unroll
                for (int j = 0; j < 4; ++j) {
                    int gn = wn + j * 16 + l15;
                    bf16 bv = (bf16)acc[i][j][rr];
                    h1[(long)gm * 1024 + cB + gn] = bv;
                    float f = (float)bv;
                    sv[j] += f; qv[j] += f * f;
                }
            }
        }
    }
#pragma unroll
    for (int j = 0; j < 4; ++j) {
        float s = sv[j], q = qv[j];
        s += __shfl_xor(s, 16); s += __shfl_xor(s, 32);
        q += __shfl_xor(q, 16); q += __shfl_xor(q, 32);
        if (lq == 0) {
            int gn = cB + wn + j * 16 + l15;
            atomicAdd(&stats[gn], s);
            atomicAdd(&stats[1024 + gn], q);
        }
    }
}

// ---------------------------------------------------------------------------
// GEMM2 v3 (pipelined): C = relu( [A1 | relu(BN(A2))] @ Bt^T + bias ).
// K = CHUNKS*128 compile-time; A1 spans first C1 chunks (lda1 = C1*128 for
// l1 / 256 for l2,l3 — passed in), A2 = h1 [*,1024] BN'd region.
// 256 thr, M-tile 64, LDS double-buffered As[2][64][136], ONE barrier/chunk;
// next-chunk A prefetched to regs before MFMA burst; B depth-2 reg prefetch;
// static full unroll of kstep loop. PoolOut: atomicAdd into pooled[batch].
// ---------------------------------------------------------------------------
template<int CHUNKS, int C1, bool PoolOut>
__global__ __launch_bounds__(256) void k_gemm2(
    const bf16* __restrict__ A1, int lda1,
    const bf16* __restrict__ A2,
    const bf16* __restrict__ Bt,
    bf16* __restrict__ Cout,
    int M, const float* __restrict__ bias,
    const float* __restrict__ scl, const float* __restrict__ shf,
    const int* __restrict__ batch, float* __restrict__ pooled)
{
    constexpr int K = CHUNKS * 128;
    __shared__ bf16 As[2][64][136];
    const int t = threadIdx.x;
    const int wave = t >> 6, lane = t & 63;
    const int l15 = lane & 15, lq = lane >> 4, koff = lq * 8;
    const int wn = wave * 64;
    const int m0 = blockIdx.x * 64;

    const int srow = t >> 4;        // staging base row 0..15 (+i*16)
    const int kg   = (t & 15) * 8;  // staging col group within chunk

    const bf16* Bp[4];
#pragma unroll
    for (int j = 0; j < 4; ++j)
        Bp[j] = Bt + (long)(wn + j * 16 + l15) * K + koff;

    f32x4 acc[4][4];
#pragma unroll
    for (int i = 0; i < 4; ++i)
#pragma unroll
        for (int j = 0; j < 4; ++j) acc[i][j] = (f32x4){0.f, 0.f, 0.f, 0.f};

    // raw A loads (+BN params) for chunk c -> regs
    auto ld_raw = [&](int c, bf16x8* rv, float4* sf) {
#pragma unroll
        for (int i = 0; i < 4; ++i) {
            int gm = m0 + srow + i * 16; if (gm >= M) gm = M - 1;
            if (c < C1) rv[i] = *(const bf16x8*)(A1 + (long)gm * lda1 + c * 128 + kg);
            else        rv[i] = *(const bf16x8*)(A2 + (long)gm * 1024 + (c - C1) * 128 + kg);
        }
        if (c >= C1) {
            int k2 = (c - C1) * 128 + kg;
            sf[0] = *(const float4*)(scl + k2);
            sf[1] = *(const float4*)(scl + k2 + 4);
            sf[2] = *(const float4*)(shf + k2);
            sf[3] = *(const float4*)(shf + k2 + 4);
        }
    };
    // convert (+BN+relu) and write chunk c into LDS buffer sel
    auto st_lds = [&](int c, const bf16x8* rv, const float4* sf, int sel) {
        float sa[8], ta[8];
        if (c >= C1) {
            sa[0]=sf[0].x; sa[1]=sf[0].y; sa[2]=sf[0].z; sa[3]=sf[0].w;
            sa[4]=sf[1].x; sa[5]=sf[1].y; sa[6]=sf[1].z; sa[7]=sf[1].w;
            ta[0]=sf[2].x; ta[1]=sf[2].y; ta[2]=sf[2].z; ta[3]=sf[2].w;
            ta[4]=sf[3].x; ta[5]=sf[3].y; ta[6]=sf[3].z; ta[7]=sf[3].w;
        }
#pragma unroll
        for (int i = 0; i < 4; ++i) {
            bf16x8 v = rv[i];
            if (c >= C1) {
                bf16x8 o;
#pragma unroll
                for (int u = 0; u < 8; ++u)
                    o[u] = (bf16)fmaxf(0.f, fmaf((float)v[u], sa[u], ta[u]));
                v = o;
            }
            *(bf16x8*)&As[sel][srow + i * 16][kg] = v;
        }
    };

    // prologue: stage chunk 0, prime B regs
    bf16x8 rv[4]; float4 sf[4];
    ld_raw(0, rv, sf);
    bf16x8 breg[2][4];
#pragma unroll
    for (int j = 0; j < 4; ++j) breg[0][j] = *(const bf16x8*)(Bp[j]);
#pragma unroll
    for (int j = 0; j < 4; ++j) breg[1][j] = *(const bf16x8*)(Bp[j] + 32);
    st_lds(0, rv, sf, 0);
    __syncthreads();

    for (int c = 0; c < CHUNKS; ++c) {
        const int sel = c & 1;
        if (c + 1 < CHUNKS) ld_raw(c + 1, rv, sf);   // global loads in flight over MFMA
#pragma unroll
        for (int ks = 0; ks < 4; ++ks) {
            bf16x8 a[4], bu[4];
#pragma unroll
            for (int i = 0; i < 4; ++i)
                a[i] = *(const bf16x8*)&As[sel][i * 16 + l15][ks * 32 + koff];
#pragma unroll
            for (int j = 0; j < 4; ++j) bu[j] = breg[ks & 1][j];
            int knext = (c * 4 + ks + 2) * 32; if (knext >= K) knext = 0;
#pragma unroll
            for (int j = 0; j < 4; ++j) breg[ks & 1][j] = *(const bf16x8*)(Bp[j] + knext);
#pragma unroll
            for (int i = 0; i < 4; ++i)
#pragma unroll
                for (int j = 0; j < 4; ++j)
                    acc[i][j] = __builtin_amdgcn_mfma_f32_16x16x32_bf16(a[i], bu[j], acc[i][j], 0, 0, 0);
        }
        if (c + 1 < CHUNKS) {
            st_lds(c + 1, rv, sf, sel ^ 1);
            __syncthreads();
        }
    }

#pragma unroll
    for (int i = 0; i < 4; ++i) {
        int rowb = m0 + i * 16 + lq * 4;
#pragma unroll
        for (int rr = 0; rr < 4; ++rr) {
            int gm = rowb + rr;
            if (gm < M) {
                int g = PoolOut ? batch[gm] : 0;
#pragma unroll
                for (int j = 0; j < 4; ++j) {
                    int gn = wn + j * 16 + l15;
                    float v = fmaxf(acc[i][j][rr] + bias[gn], 0.f);
                    if (PoolOut) atomicAdd(&pooled[(long)g * 256 + gn], v);
                    else         Cout[(long)gm * 256 + gn] = (bf16)v;
                }
            }
        }
    }
}

// ---------------------------------------------------------------------------
// CSR build
__global__ void k_hist(const int* __restrict__ ei, const int* __restrict__ et,
                       int* __restrict__ hist)
{
    int e = blockIdx.x * 256 + threadIdx.x;
    if (e >= kE) return;
    atomicAdd(&hist[ei[kE + e] * 4 + et[e]], 1);
}

__global__ void k_scan1(const int* __restrict__ hist, int* __restrict__ bsum)
{
    __shared__ int sd[256];
    int i = blockIdx.x * 256 + threadIdx.x;
    sd[threadIdx.x] = (i < kSeg) ? hist[i] : 0;
    __syncthreads();
    for (int o = 128; o > 0; o >>= 1) {
        if (threadIdx.x < o) sd[threadIdx.x] += sd[threadIdx.x + o];
        __syncthreads();
    }
    if (threadIdx.x == 0) bsum[blockIdx.x] = sd[0];
}

__global__ __launch_bounds__(1024) void k_scan2(const int* __restrict__ bsum,
                                                int* __restrict__ boff)
{
    __shared__ int sd[1024];
    int t = threadIdx.x;
    sd[t] = (t < kScanB) ? bsum[t] : 0;
    __syncthreads();
    for (int o = 1; o < 1024; o <<= 1) {
        int v = (t >= o) ? sd[t - o] : 0;
        __syncthreads();
        sd[t] += v;
        __syncthreads();
    }
    if (t < kScanB) boff[t] = (t == 0) ? 0 : sd[t - 1];
}

__global__ void k_scan3(const int* __restrict__ hist, const int* __restrict__ boff,
                        int* __restrict__ row_ptr, int* __restrict__ cursor)
{
    __shared__ int sd[256];
    int i = blockIdx.x * 256 + threadIdx.x;
    int v = (i < kSeg) ? hist[i] : 0;
    sd[threadIdx.x] = v;
    __syncthreads();
    for (int o = 1; o < 256; o <<= 1) {
        int u = (threadIdx.x >= o) ? sd[threadIdx.x - o] : 0;
        __syncthreads();
        sd[threadIdx.x] += u;
        __syncthreads();
    }
    if (i <= kSeg) {
        int excl = boff[blockIdx.x] + sd[threadIdx.x] - v;
        row_ptr[i] = excl;
        if (i < kSeg) cursor[i] = excl;
    }
}

__global__ void k_fill(const int* __restrict__ ei, const int* __restrict__ et,
                       int* __restrict__ cursor, int* __restrict__ srcidx)
{
    int e = blockIdx.x * 256 + threadIdx.x;
    if (e >= kE) return;
    int key = ei[kE + e] * 4 + et[e];
    int pos = atomicAdd(&cursor[key], 1);
    srcidx[pos] = ei[e];
}

// ---------------------------------------------------------------------------
// layer-1 aggregate: a1b[r][d][ch] = bf16( x[d][ch] + sum_src x[src][ch] ), ch<11
__global__ void k_agg11(const float* __restrict__ x, const int* __restrict__ srcidx,
                        const int* __restrict__ row_ptr, bf16* __restrict__ a1b)
{
    long gid = (long)blockIdx.x * 256 + threadIdx.x;
    if (gid >= (long)kSeg * 32) return;
    int ch  = (int)(gid & 31);
    int seg = (int)(gid >> 5);
    int d = seg >> 2, r = seg & 3;
    float acc = 0.f;
    if (ch < 11) {
        acc = x[(long)d * 11 + ch];
        int i0 = row_ptr[seg], i1 = row_ptr[seg + 1];
        for (int i = i0; i < i1; ++i) acc += x[(long)srcidx[i] * 11 + ch];
    }
    a1b[((long)r * kN + d) * 32 + ch] = (bf16)acc;
}

// x [N,11] fp32 -> xb1 [N,128] bf16 zero-padded (chunk-aligned for k_gemm2)
__global__ void k_xpad(const float* __restrict__ x, bf16* __restrict__ xb1)
{
    long gid = (long)blockIdx.x * 256 + threadIdx.x;
    if (gid >= (long)kN * 128) return;
    int c = (int)(gid & 127); long d = gid >> 7;
    xb1[gid] = (c < 11) ? (bf16)x[d * 11 + c] : (bf16)0.f;
}

// weight transpose-pack: in [K,N] fp32 -> out[n*ldout + coff + k] bf16
__global__ void k_wt_s(const float* __restrict__ in, bf16* __restrict__ out,
                       int K, int N, int ldout, int coff)
{
    int i = blockIdx.x * 256 + threadIdx.x;
    if (i >= K * N) return;
    int n = i / K, k = i - n * K;
    out[(long)n * ldout + coff + k] = (bf16)in[(long)k * N + n];
}

// layer-1 w1 pack: [4][11][256] fp32 -> [4][256][32] bf16 zero-padded
__global__ void k_wtL1(const float* __restrict__ w1, bf16* __restrict__ out)
{
    int i = blockIdx.x * 256 + threadIdx.x;
    if (i >= 4 * 256 * 32) return;
    int r = i >> 13, rem = i & 8191, n = rem >> 5, k = rem & 31;
    out[i] = (k < 11) ? (bf16)w1[(long)r * 11 * 256 + (long)k * 256 + n] : (bf16)0.f;
}

__global__ void k_bn_params(const float* __restrict__ stats,
                            const float* __restrict__ g, const float* __restrict__ bt,
                            float* __restrict__ scl, float* __restrict__ shf)
{
    int c = blockIdx.x * 256 + threadIdx.x;  // < 1024
    const float invN = 1.0f / (float)kN;
    float mu  = stats[c] * invN;
    float var = stats[1024 + c] * invN - mu * mu;
    float sc  = g[c] * rsqrtf(var + 1e-5f);
    scl[c] = sc;
    shf[c] = bt[c] - mu * sc;
}

__global__ void k_bias_total(const float* sb0, const float* b20,
                             const float* sb1, const float* b21,
                             const float* sb2, const float* b22,
                             float* __restrict__ btt)
{
    int l = blockIdx.x, j = threadIdx.x;
    const float* sb = (l == 0) ? sb0 : (l == 1) ? sb1 : sb2;
    const float* b2 = (l == 0) ? b20 : (l == 1) ? b21 : b22;
    float v = sb[j];
#pragma unroll
    for (int r = 0; r < 4; ++r) v += b2[r * 256 + j];
    btt[l * 256 + j] = v;
}

__global__ void k_counts(const int* __restrict__ batch, float* __restrict__ counts)
{
    int v = blockIdx.x * 256 + threadIdx.x;
    if (v < kN) atomicAdd(&counts[batch[v]], 1.0f);
}

__global__ __launch_bounds__(64) void k_head(const float* __restrict__ pooled,
                                             const float* __restrict__ counts,
                                             const float* __restrict__ lw,
                                             const float* __restrict__ lb,
                                             float* __restrict__ out)
{
    int g = blockIdx.x;
    int l = threadIdx.x;
    float inv = 1.0f / fmaxf(counts[g], 1.0f);
    float acc[kT];
#pragma unroll
    for (int t = 0; t < kT; ++t) acc[t] = 0.f;
    for (int k = l; k < 256; k += 64) {
        float p = pooled[((long)g << 8) + k] * inv;
#pragma unroll
        for (int t = 0; t < kT; ++t) acc[t] = fmaf(p, lw[k * kT + t], acc[t]);
    }
#pragma unroll
    for (int off = 32; off > 0; off >>= 1)
#pragma unroll
        for (int t = 0; t < kT; ++t) acc[t] += __shfl_down(acc[t], off);
    if (l == 0) {
#pragma unroll
        for (int t = 0; t < kT; ++t) out[(long)g * kT + t] = acc[t] + lb[t];
    }
}

// ---------------------------------------------------------------------------
extern "C" void kernel_launch(void* const* d_in, const int* in_sizes, int n_in,
                              void* d_out, int out_size, void* d_ws, size_t ws_size,
                              hipStream_t stream)
{
    const float* x     = (const float*)d_in[0];
    const int*   ei    = (const int*)d_in[1];
    const int*   et    = (const int*)d_in[2];
    const int*   batch = (const int*)d_in[3];

    const float *sw[3], *sb[3], *w1[3], *gmm[3], *btm[3], *w2[3], *b2[3];
    for (int l = 0; l < 3; ++l) {
        int b = 4 + l * 8;
        sw[l]  = (const float*)d_in[b + 0];
        sb[l]  = (const float*)d_in[b + 1];
        w1[l]  = (const float*)d_in[b + 2];
        // b+3 = b1 (cancels inside BatchNorm)
        gmm[l] = (const float*)d_in[b + 4];
        btm[l] = (const float*)d_in[b + 5];
        w2[l]  = (const float*)d_in[b + 6];
        b2[l]  = (const float*)d_in[b + 7];
    }
    const float* lin_w = (const float*)d_in[28];
    const float* lin_b = (const float*)d_in[29];
    float* out = (float*)d_out;
    (void)in_sizes; (void)n_in; (void)out_size;

    // ---- workspace (~186 MB) ----
    char* wsb = (char*)d_ws;
    size_t off = 0;
    auto alloc = [&](size_t bytes) { void* p = wsb + off; off = (off + bytes + 255) & ~(size_t)255; return p; };
    bf16*  Pb0    = (bf16*) alloc((size_t)kN * 256 * 2);
    bf16*  Pb1    = (bf16*) alloc((size_t)kN * 256 * 2);
    bf16*  h1     = (bf16*) alloc((size_t)kN * 1024 * 2);
    bf16*  a1b    = (bf16*) alloc((size_t)4 * kN * 32 * 2);
    bf16*  xb1    = (bf16*) alloc((size_t)kN * 128 * 2);        // padded to 128
    bf16*  w1t    = (bf16*) alloc((size_t)2 * 4 * 65536 * 2);   // layers 2,3
    bf16*  w1tL1  = (bf16*) alloc((size_t)4 * 256 * 32 * 2);
    bf16*  Bc0    = (bf16*) alloc((size_t)256 * 1152 * 2);      // [sw_pad128 | w2]
    bf16*  Bc1    = (bf16*) alloc((size_t)256 * 1280 * 2);
    bf16*  Bc2    = (bf16*) alloc((size_t)256 * 1280 * 2);
    int*   hist   = (int*)  alloc((size_t)(kSeg + 1) * 4);
    int*   row_ptr= (int*)  alloc((size_t)(kSeg + 1) * 4);
    int*   cursor = (int*)  alloc((size_t)kSeg * 4);
    int*   srcidx = (int*)  alloc((size_t)kE * 4);
    int*   bsum   = (int*)  alloc((size_t)kScanB * 4);
    int*   boff   = (int*)  alloc((size_t)kScanB * 4);
    float* stats  = (float*)alloc(2048 * 4);
    float* scl    = (float*)alloc(1024 * 4);
    float* shf    = (float*)alloc(1024 * 4);
    float* btt    = (float*)alloc(3 * 256 * 4);
    float* pooled = (float*)alloc((size_t)kG * 256 * 4);
    float* counts = (float*)alloc(kG * 4);
    if (ws_size < off) return;  // clean absmax-fail instead of OOB crash

    const dim3 gR((kN + 127) / 128, 4);   // GEMM1 grids (512 thr)
    const dim3 g2((kN + 63) / 64);        // GEMM2 grid  (256 thr, 782 blocks)

    // ---- CSR build (parallel scan) + weight prepack ----
    hipMemsetAsync(hist, 0, (size_t)(kSeg + 1) * 4, stream);
    k_hist<<<(kE + 255) / 256, 256, 0, stream>>>(ei, et, hist);
    k_scan1<<<kScanB, 256, 0, stream>>>(hist, bsum);
    k_scan2<<<1, 1024, 0, stream>>>(bsum, boff);
    k_scan3<<<kScanB, 256, 0, stream>>>(hist, boff, row_ptr, cursor);
    k_fill<<<(kE + 255) / 256, 256, 0, stream>>>(ei, et, cursor, srcidx);

    k_bias_total<<<3, 256, 0, stream>>>(sb[0], b2[0], sb[1], b2[1], sb[2], b2[2], btt);
    k_xpad<<<(int)(((long)kN * 128 + 255) / 256), 256, 0, stream>>>(x, xb1);
    k_wtL1<<<(4 * 256 * 32 + 255) / 256, 256, 0, stream>>>(w1[0], w1tL1);
    for (int l = 1; l < 3; ++l)
        for (int r = 0; r < 4; ++r)
            k_wt_s<<<256, 256, 0, stream>>>(w1[l] + (long)r * 65536,
                                            w1t + (long)(l - 1) * 4 * 65536 + (long)r * 65536,
                                            256, 256, 256, 0);
    hipMemsetAsync(Bc0, 0, (size_t)256 * 1152 * 2, stream);
    k_wt_s<<<(11 * 256 + 255) / 256, 256, 0, stream>>>(sw[0], Bc0, 11, 256, 1152, 0);
    k_wt_s<<<1024, 256, 0, stream>>>(w2[0], Bc0, 1024, 256, 1152, 128);
    k_wt_s<<<256, 256, 0, stream>>>(sw[1], Bc1, 256, 256, 1280, 0);
    k_wt_s<<<1024, 256, 0, stream>>>(w2[1], Bc1, 1024, 256, 1280, 256);
    k_wt_s<<<256, 256, 0, stream>>>(sw[2], Bc2, 256, 256, 1280, 0);
    k_wt_s<<<1024, 256, 0, stream>>>(w2[2], Bc2, 1024, 256, 1280, 256);

    k_counts<<<(kN + 255) / 256, 256, 0, stream>>>(batch, counts);  // counts poisoned -> must init
    hipMemsetAsync(pooled, 0, (size_t)kG * 256 * 4, stream);

    // ---------------- layer 1 ----------------
    k_agg11<<<(int)(((long)kSeg * 32 + 255) / 256), 256, 0, stream>>>(x, srcidx, row_ptr, a1b);
    hipMemsetAsync(stats, 0, 2048 * 4, stream);
    k_l1gemm<<<gR, 512, 0, stream>>>(a1b, w1tL1, h1, stats);
    k_bn_params<<<4, 256, 0, stream>>>(stats, gmm[0], btm[0], scl, shf);
    k_gemm2<9, 1, false><<<g2, 256, 0, stream>>>(xb1, 128, h1, Bc0,
                                                 Pb0, kN, btt + 0, scl, shf, nullptr, nullptr);

    // ---------------- layer 2 ----------------
    hipMemsetAsync(stats, 0, 2048 * 4, stream);
    k_rgin1<<<gR, 512, 0, stream>>>(Pb0, srcidx, row_ptr, w1t, h1, stats);
    k_bn_params<<<4, 256, 0, stream>>>(stats, gmm[1], btm[1], scl, shf);
    k_gemm2<10, 2, false><<<g2, 256, 0, stream>>>(Pb0, 256, h1, Bc1,
                                                  Pb1, kN, btt + 256, scl, shf, nullptr, nullptr);

    // ---------------- layer 3 (pool fused into GEMM2) ----------------
    hipMemsetAsync(stats, 0, 2048 * 4, stream);
    k_rgin1<<<gR, 512, 0, stream>>>(Pb1, srcidx, row_ptr, w1t + (size_t)4 * 65536, h1, stats);
    k_bn_params<<<4, 256, 0, stream>>>(stats, gmm[2], btm[2], scl, shf);
    k_gemm2<10, 2, true><<<g2, 256, 0, stream>>>(Pb1, 256, h1, Bc2,
                                                 nullptr, kN, btt + 512, scl, shf, batch, pooled);

    // ---------------- head ----------------
    k_head<<<kG, 64, 0, stream>>>(pooled, counts, lin_w, lin_b, out);
}

// Round 9
// 1003.727 us; speedup vs baseline: 6.4454x; 1.1500x over previous
//
#include <hip/hip_runtime.h>

static const int kN = 50000;   // nodes
static const int kE = 300000;  // edges
static const int kG = 2048;    // graphs
static const int kT = 19;      // targets
static const int kSeg = kN * 4;  // CSR segments: key = dst*4 + rel
static const int kScanB = (kSeg + 256) / 256;  // 784 blocks covers kSeg+1

typedef __bf16 bf16;
typedef __bf16 bf16x8 __attribute__((ext_vector_type(8)));
typedef __bf16 bf16x4 __attribute__((ext_vector_type(4)));
typedef float  f32x4  __attribute__((ext_vector_type(4)));

// ---------------------------------------------------------------------------
// GEMM1 layers 2/3 v2: aggregate (CSR, +self) into LDS, then MFMA vs w1t[r].
// Grid (ceil(N/64), 4=rel), 512 threads (8 waves).
// M-tile 64 -> LDS 33.8 KB -> 3-4 blocks/CU (was 2); wave aggregates only
// 8 rows (serial gather chain halved); row headers preloaded; first B frags
// issued before phase 1. Phase 2: wave = 64 rows x 32-col slice (4x2 frags).
// Layouts (m89/m91-verified): A/B idx=lane&15,k=(lane>>4)*8+j;
//                             C/D row=(lane>>4)*4+reg, col=lane&15.
// ---------------------------------------------------------------------------
__global__ __launch_bounds__(512) void k_rgin1(
    const bf16* __restrict__ Pb, const int* __restrict__ srcidx,
    const int* __restrict__ row_ptr, const bf16* __restrict__ w1t,
    bf16* __restrict__ h1, float* __restrict__ stats)
{
    __shared__ bf16 As[64][264];   // row stride 264 bf16 = 132 dwords
    const int t = threadIdx.x;
    const int r = blockIdx.y;
    const int m0 = blockIdx.x * 64;
    const int wave = t >> 6, lane = t & 63;
    const int l15 = lane & 15, lq = lane >> 4, koff = lq * 8;
    const int wn = wave * 32;

    // B pointers + first-fragment prefetch (lands during phase 1)
    const bf16* Bt = w1t + (long)r * 65536;
    const bf16* Bp[2];
#pragma unroll
    for (int j = 0; j < 2; ++j)
        Bp[j] = Bt + (long)(wn + j * 16 + l15) * 256 + koff;
    bf16x8 b0[2], b1[2];
#pragma unroll
    for (int j = 0; j < 2; ++j) b0[j] = *(const bf16x8*)(Bp[j]);

    // ---- phase 1: 8 rows per wave, headers preloaded ----
    {
        const int rbase = m0 + wave * 8;
        int i0s[8], i1s[8];
#pragma unroll
        for (int rr = 0; rr < 8; ++rr) {
            int dc = rbase + rr; if (dc >= kN) dc = kN - 1;
            int seg = dc * 4 + r;
            i0s[rr] = row_ptr[seg];
            i1s[rr] = row_ptr[seg + 1];
        }
#pragma unroll
        for (int rr = 0; rr < 8; ++rr) {
            int dc = rbase + rr; if (dc >= kN) dc = kN - 1;
            bf16x4 sv = ((const bf16x4*)(Pb + (long)dc * 256))[lane];
            f32x4 a = {(float)sv[0], (float)sv[1], (float)sv[2], (float)sv[3]};
            int i = i0s[rr], i1 = i1s[rr];
            for (; i + 1 < i1; i += 2) {
                int s0 = srcidx[i], s1 = srcidx[i + 1];
                bf16x4 v0 = ((const bf16x4*)(Pb + (long)s0 * 256))[lane];
                bf16x4 v1 = ((const bf16x4*)(Pb + (long)s1 * 256))[lane];
                a[0] += (float)v0[0] + (float)v1[0];
                a[1] += (float)v0[1] + (float)v1[1];
                a[2] += (float)v0[2] + (float)v1[2];
                a[3] += (float)v0[3] + (float)v1[3];
            }
            if (i < i1) {
                bf16x4 v0 = ((const bf16x4*)(Pb + (long)srcidx[i] * 256))[lane];
                a[0] += (float)v0[0]; a[1] += (float)v0[1];
                a[2] += (float)v0[2]; a[3] += (float)v0[3];
            }
            bf16x4 o = {(bf16)a[0], (bf16)a[1], (bf16)a[2], (bf16)a[3]};
            *(bf16x4*)&As[wave * 8 + rr][lane * 4] = o;
        }
    }
    __syncthreads();

    // ---- phase 2: MFMA from LDS, B double-buffered in regs ----
    const bf16* Ar[4];
#pragma unroll
    for (int i = 0; i < 4; ++i) Ar[i] = &As[i * 16 + l15][koff];

    f32x4 acc[4][2];
#pragma unroll
    for (int i = 0; i < 4; ++i)
#pragma unroll
        for (int j = 0; j < 2; ++j) acc[i][j] = (f32x4){0.f, 0.f, 0.f, 0.f};

#pragma unroll
    for (int kt = 0; kt < 256; kt += 32) {
        int kn = kt + 32; if (kn >= 256) kn = 0;
#pragma unroll
        for (int j = 0; j < 2; ++j) b1[j] = *(const bf16x8*)(Bp[j] + kn);
        bf16x8 a[4];
#pragma unroll
        for (int i = 0; i < 4; ++i) a[i] = *(const bf16x8*)(Ar[i] + kt);
#pragma unroll
        for (int i = 0; i < 4; ++i)
#pragma unroll
            for (int j = 0; j < 2; ++j)
                acc[i][j] = __builtin_amdgcn_mfma_f32_16x16x32_bf16(a[i], b0[j], acc[i][j], 0, 0, 0);
#pragma unroll
        for (int j = 0; j < 2; ++j) b0[j] = b1[j];
    }

    // ---- epilogue: store h1 + fused stats ----
    const int cB = r * 256;
    float sv[2] = {0, 0}, qv[2] = {0, 0};
#pragma unroll
    for (int i = 0; i < 4; ++i) {
        int rowb = m0 + i * 16 + lq * 4;
#pragma unroll
        for (int rr = 0; rr < 4; ++rr) {
            int gm = rowb + rr;
            if (gm < kN) {
#pragma unroll
                for (int j = 0; j < 2; ++j) {
                    int gn = wn + j * 16 + l15;
                    bf16 bv = (bf16)acc[i][j][rr];
                    h1[(long)gm * 1024 + cB + gn] = bv;
                    float f = (float)bv;
                    sv[j] += f; qv[j] += f * f;
                }
            }
        }
    }
#pragma unroll
    for (int j = 0; j < 2; ++j) {
        float s = sv[j], q = qv[j];
        s += __shfl_xor(s, 16); s += __shfl_xor(s, 32);
        q += __shfl_xor(q, 16); q += __shfl_xor(q, 32);
        if (lq == 0) {
            int gn = cB + wn + j * 16 + l15;
            atomicAdd(&stats[gn], s);
            atomicAdd(&stats[1024 + gn], q);
        }
    }
}

// ---------------------------------------------------------------------------
// GEMM1 layer 1: A = a1b[r] [N,32] bf16 (K=32, one MFMA step) + fused stats.
// ---------------------------------------------------------------------------
__global__ __launch_bounds__(512) void k_l1gemm(
    const bf16* __restrict__ a1b, const bf16* __restrict__ w1tL1,
    bf16* __restrict__ h1, float* __restrict__ stats)
{
    const int t = threadIdx.x;
    const int r = blockIdx.y;
    const int m0 = blockIdx.x * 128;
    const int wave = t >> 6, lane = t & 63;
    const int l15 = lane & 15, lq = lane >> 4, koff = lq * 8;
    const int wm = (wave & 1) * 64, wn = (wave >> 1) * 64;

    bf16x8 a[4], b[4];
#pragma unroll
    for (int i = 0; i < 4; ++i) {
        int gm = m0 + wm + i * 16 + l15;
        if (gm >= kN) gm = kN - 1;
        a[i] = *(const bf16x8*)(a1b + ((long)r * kN + gm) * 32 + koff);
    }
#pragma unroll
    for (int j = 0; j < 4; ++j)
        b[j] = *(const bf16x8*)(w1tL1 + (long)r * 8192 + (long)(wn + j * 16 + l15) * 32 + koff);

    f32x4 acc[4][4];
#pragma unroll
    for (int i = 0; i < 4; ++i)
#pragma unroll
        for (int j = 0; j < 4; ++j)
            acc[i][j] = __builtin_amdgcn_mfma_f32_16x16x32_bf16(a[i], b[j],
                        (f32x4){0.f, 0.f, 0.f, 0.f}, 0, 0, 0);

    const int cB = r * 256;
    float sv[4] = {0,0,0,0}, qv[4] = {0,0,0,0};
#pragma unroll
    for (int i = 0; i < 4; ++i) {
        int rowb = m0 + wm + i * 16 + lq * 4;
#pragma unroll
        for (int rr = 0; rr < 4; ++rr) {
            int gm = rowb + rr;
            if (gm < kN) {
#pragma unroll
                for (int j = 0; j < 4; ++j) {
                    int gn = wn + j * 16 + l15;
                    bf16 bv = (bf16)acc[i][j][rr];
                    h1[(long)gm * 1024 + cB + gn] = bv;
                    float f = (float)bv;
                    sv[j] += f; qv[j] += f * f;
                }
            }
        }
    }
#pragma unroll
    for (int j = 0; j < 4; ++j) {
        float s = sv[j], q = qv[j];
        s += __shfl_xor(s, 16); s += __shfl_xor(s, 32);
        q += __shfl_xor(q, 16); q += __shfl_xor(q, 32);
        if (lq == 0) {
            int gn = cB + wn + j * 16 + l15;
            atomicAdd(&stats[gn], s);
            atomicAdd(&stats[1024 + gn], q);
        }
    }
}

// ---------------------------------------------------------------------------
// GEMM2 v3 (pipelined): C = relu( [A1 | relu(BN(A2))] @ Bt^T + bias ).
// K = CHUNKS*128 compile-time; A1 spans first C1 chunks, A2 = h1 BN region.
// 256 thr, M-tile 64, LDS double-buffered, one barrier/chunk; A prefetched
// to regs over MFMA; B depth-2 reg prefetch; static unroll.
// ---------------------------------------------------------------------------
template<int CHUNKS, int C1, bool PoolOut>
__global__ __launch_bounds__(256) void k_gemm2(
    const bf16* __restrict__ A1, int lda1,
    const bf16* __restrict__ A2,
    const bf16* __restrict__ Bt,
    bf16* __restrict__ Cout,
    int M, const float* __restrict__ bias,
    const float* __restrict__ scl, const float* __restrict__ shf,
    const int* __restrict__ batch, float* __restrict__ pooled)
{
    constexpr int K = CHUNKS * 128;
    __shared__ bf16 As[2][64][136];
    const int t = threadIdx.x;
    const int wave = t >> 6, lane = t & 63;
    const int l15 = lane & 15, lq = lane >> 4, koff = lq * 8;
    const int wn = wave * 64;
    const int m0 = blockIdx.x * 64;

    const int srow = t >> 4;        // staging base row 0..15 (+i*16)
    const int kg   = (t & 15) * 8;  // staging col group within chunk

    const bf16* Bp[4];
#pragma unroll
    for (int j = 0; j < 4; ++j)
        Bp[j] = Bt + (long)(wn + j * 16 + l15) * K + koff;

    f32x4 acc[4][4];
#pragma unroll
    for (int i = 0; i < 4; ++i)
#pragma unroll
        for (int j = 0; j < 4; ++j) acc[i][j] = (f32x4){0.f, 0.f, 0.f, 0.f};

    auto ld_raw = [&](int c, bf16x8* rv, float4* sf) {
#pragma unroll
        for (int i = 0; i < 4; ++i) {
            int gm = m0 + srow + i * 16; if (gm >= M) gm = M - 1;
            if (c < C1) rv[i] = *(const bf16x8*)(A1 + (long)gm * lda1 + c * 128 + kg);
            else        rv[i] = *(const bf16x8*)(A2 + (long)gm * 1024 + (c - C1) * 128 + kg);
        }
        if (c >= C1) {
            int k2 = (c - C1) * 128 + kg;
            sf[0] = *(const float4*)(scl + k2);
            sf[1] = *(const float4*)(scl + k2 + 4);
            sf[2] = *(const float4*)(shf + k2);
            sf[3] = *(const float4*)(shf + k2 + 4);
        }
    };
    auto st_lds = [&](int c, const bf16x8* rv, const float4* sf, int sel) {
        float sa[8], ta[8];
        if (c >= C1) {
            sa[0]=sf[0].x; sa[1]=sf[0].y; sa[2]=sf[0].z; sa[3]=sf[0].w;
            sa[4]=sf[1].x; sa[5]=sf[1].y; sa[6]=sf[1].z; sa[7]=sf[1].w;
            ta[0]=sf[2].x; ta[1]=sf[2].y; ta[2]=sf[2].z; ta[3]=sf[2].w;
            ta[4]=sf[3].x; ta[5]=sf[3].y; ta[6]=sf[3].z; ta[7]=sf[3].w;
        }
#pragma unroll
        for (int i = 0; i < 4; ++i) {
            bf16x8 v = rv[i];
            if (c >= C1) {
                bf16x8 o;
#pragma unroll
                for (int u = 0; u < 8; ++u)
                    o[u] = (bf16)fmaxf(0.f, fmaf((float)v[u], sa[u], ta[u]));
                v = o;
            }
            *(bf16x8*)&As[sel][srow + i * 16][kg] = v;
        }
    };

    bf16x8 rv[4]; float4 sf[4];
    ld_raw(0, rv, sf);
    bf16x8 breg[2][4];
#pragma unroll
    for (int j = 0; j < 4; ++j) breg[0][j] = *(const bf16x8*)(Bp[j]);
#pragma unroll
    for (int j = 0; j < 4; ++j) breg[1][j] = *(const bf16x8*)(Bp[j] + 32);
    st_lds(0, rv, sf, 0);
    __syncthreads();

    for (int c = 0; c < CHUNKS; ++c) {
        const int sel = c & 1;
        if (c + 1 < CHUNKS) ld_raw(c + 1, rv, sf);
#pragma unroll
        for (int ks = 0; ks < 4; ++ks) {
            bf16x8 a[4], bu[4];
#pragma unroll
            for (int i = 0; i < 4; ++i)
                a[i] = *(const bf16x8*)&As[sel][i * 16 + l15][ks * 32 + koff];
#pragma unroll
            for (int j = 0; j < 4; ++j) bu[j] = breg[ks & 1][j];
            int knext = (c * 4 + ks + 2) * 32; if (knext >= K) knext = 0;
#pragma unroll
            for (int j = 0; j < 4; ++j) breg[ks & 1][j] = *(const bf16x8*)(Bp[j] + knext);
#pragma unroll
            for (int i = 0; i < 4; ++i)
#pragma unroll
                for (int j = 0; j < 4; ++j)
                    acc[i][j] = __builtin_amdgcn_mfma_f32_16x16x32_bf16(a[i], bu[j], acc[i][j], 0, 0, 0);
        }
        if (c + 1 < CHUNKS) {
            st_lds(c + 1, rv, sf, sel ^ 1);
            __syncthreads();
        }
    }

#pragma unroll
    for (int i = 0; i < 4; ++i) {
        int rowb = m0 + i * 16 + lq * 4;
#pragma unroll
        for (int rr = 0; rr < 4; ++rr) {
            int gm = rowb + rr;
            if (gm < M) {
                int g = PoolOut ? batch[gm] : 0;
#pragma unroll
                for (int j = 0; j < 4; ++j) {
                    int gn = wn + j * 16 + l15;
                    float v = fmaxf(acc[i][j][rr] + bias[gn], 0.f);
                    if (PoolOut) atomicAdd(&pooled[(long)g * 256 + gn], v);
                    else         Cout[(long)gm * 256 + gn] = (bf16)v;
                }
            }
        }
    }
}

// ---------------------------------------------------------------------------
// CSR build
__global__ void k_hist(const int* __restrict__ ei, const int* __restrict__ et,
                       int* __restrict__ hist)
{
    int e = blockIdx.x * 256 + threadIdx.x;
    if (e >= kE) return;
    atomicAdd(&hist[ei[kE + e] * 4 + et[e]], 1);
}

__global__ void k_scan1(const int* __restrict__ hist, int* __restrict__ bsum)
{
    __shared__ int sd[256];
    int i = blockIdx.x * 256 + threadIdx.x;
    sd[threadIdx.x] = (i < kSeg) ? hist[i] : 0;
    __syncthreads();
    for (int o = 128; o > 0; o >>= 1) {
        if (threadIdx.x < o) sd[threadIdx.x] += sd[threadIdx.x + o];
        __syncthreads();
    }
    if (threadIdx.x == 0) bsum[blockIdx.x] = sd[0];
}

__global__ __launch_bounds__(1024) void k_scan2(const int* __restrict__ bsum,
                                                int* __restrict__ boff)
{
    __shared__ int sd[1024];
    int t = threadIdx.x;
    sd[t] = (t < kScanB) ? bsum[t] : 0;
    __syncthreads();
    for (int o = 1; o < 1024; o <<= 1) {
        int v = (t >= o) ? sd[t - o] : 0;
        __syncthreads();
        sd[t] += v;
        __syncthreads();
    }
    if (t < kScanB) boff[t] = (t == 0) ? 0 : sd[t - 1];
}

__global__ void k_scan3(const int* __restrict__ hist, const int* __restrict__ boff,
                        int* __restrict__ row_ptr, int* __restrict__ cursor)
{
    __shared__ int sd[256];
    int i = blockIdx.x * 256 + threadIdx.x;
    int v = (i < kSeg) ? hist[i] : 0;
    sd[threadIdx.x] = v;
    __syncthreads();
    for (int o = 1; o < 256; o <<= 1) {
        int u = (threadIdx.x >= o) ? sd[threadIdx.x - o] : 0;
        __syncthreads();
        sd[threadIdx.x] += u;
        __syncthreads();
    }
    if (i <= kSeg) {
        int excl = boff[blockIdx.x] + sd[threadIdx.x] - v;
        row_ptr[i] = excl;
        if (i < kSeg) cursor[i] = excl;
    }
}

__global__ void k_fill(const int* __restrict__ ei, const int* __restrict__ et,
                       int* __restrict__ cursor, int* __restrict__ srcidx)
{
    int e = blockIdx.x * 256 + threadIdx.x;
    if (e >= kE) return;
    int key = ei[kE + e] * 4 + et[e];
    int pos = atomicAdd(&cursor[key], 1);
    srcidx[pos] = ei[e];
}

// ---------------------------------------------------------------------------
// layer-1 aggregate: a1b[r][d][ch] = bf16( x[d][ch] + sum_src x[src][ch] ), ch<11
__global__ void k_agg11(const float* __restrict__ x, const int* __restrict__ srcidx,
                        const int* __restrict__ row_ptr, bf16* __restrict__ a1b)
{
    long gid = (long)blockIdx.x * 256 + threadIdx.x;
    if (gid >= (long)kSeg * 32) return;
    int ch  = (int)(gid & 31);
    int seg = (int)(gid >> 5);
    int d = seg >> 2, r = seg & 3;
    float acc = 0.f;
    if (ch < 11) {
        acc = x[(long)d * 11 + ch];
        int i0 = row_ptr[seg], i1 = row_ptr[seg + 1];
        for (int i = i0; i < i1; ++i) acc += x[(long)srcidx[i] * 11 + ch];
    }
    a1b[((long)r * kN + d) * 32 + ch] = (bf16)acc;
}

// x [N,11] fp32 -> xb1 [N,128] bf16 zero-padded (chunk-aligned for k_gemm2)
__global__ void k_xpad(const float* __restrict__ x, bf16* __restrict__ xb1)
{
    long gid = (long)blockIdx.x * 256 + threadIdx.x;
    if (gid >= (long)kN * 128) return;
    int c = (int)(gid & 127); long d = gid >> 7;
    xb1[gid] = (c < 11) ? (bf16)x[d * 11 + c] : (bf16)0.f;
}

// weight transpose-pack: in [K,N] fp32 -> out[n*ldout + coff + k] bf16
__global__ void k_wt_s(const float* __restrict__ in, bf16* __restrict__ out,
                       int K, int N, int ldout, int coff)
{
    int i = blockIdx.x * 256 + threadIdx.x;
    if (i >= K * N) return;
    int n = i / K, k = i - n * K;
    out[(long)n * ldout + coff + k] = (bf16)in[(long)k * N + n];
}

// layer-1 w1 pack: [4][11][256] fp32 -> [4][256][32] bf16 zero-padded
__global__ void k_wtL1(const float* __restrict__ w1, bf16* __restrict__ out)
{
    int i = blockIdx.x * 256 + threadIdx.x;
    if (i >= 4 * 256 * 32) return;
    int r = i >> 13, rem = i & 8191, n = rem >> 5, k = rem & 31;
    out[i] = (k < 11) ? (bf16)w1[(long)r * 11 * 256 + (long)k * 256 + n] : (bf16)0.f;
}

__global__ void k_bn_params(const float* __restrict__ stats,
                            const float* __restrict__ g, const float* __restrict__ bt,
                            float* __restrict__ scl, float* __restrict__ shf)
{
    int c = blockIdx.x * 256 + threadIdx.x;  // < 1024
    const float invN = 1.0f / (float)kN;
    float mu  = stats[c] * invN;
    float var = stats[1024 + c] * invN - mu * mu;
    float sc  = g[c] * rsqrtf(var + 1e-5f);
    scl[c] = sc;
    shf[c] = bt[c] - mu * sc;
}

__global__ void k_bias_total(const float* sb0, const float* b20,
                             const float* sb1, const float* b21,
                             const float* sb2, const float* b22,
                             float* __restrict__ btt)
{
    int l = blockIdx.x, j = threadIdx.x;
    const float* sb = (l == 0) ? sb0 : (l == 1) ? sb1 : sb2;
    const float* b2 = (l == 0) ? b20 : (l == 1) ? b21 : b22;
    float v = sb[j];
#pragma unroll
    for (int r = 0; r < 4; ++r) v += b2[r * 256 + j];
    btt[l * 256 + j] = v;
}

__global__ void k_counts(const int* __restrict__ batch, float* __restrict__ counts)
{
    int v = blockIdx.x * 256 + threadIdx.x;
    if (v < kN) atomicAdd(&counts[batch[v]], 1.0f);
}

__global__ __launch_bounds__(64) void k_head(const float* __restrict__ pooled,
                                             const float* __restrict__ counts,
                                             const float* __restrict__ lw,
                                             const float* __restrict__ lb,
                                             float* __restrict__ out)
{
    int g = blockIdx.x;
    int l = threadIdx.x;
    float inv = 1.0f / fmaxf(counts[g], 1.0f);
    float acc[kT];
#pragma unroll
    for (int t = 0; t < kT; ++t) acc[t] = 0.f;
    for (int k = l; k < 256; k += 64) {
        float p = pooled[((long)g << 8) + k] * inv;
#pragma unroll
        for (int t = 0; t < kT; ++t) acc[t] = fmaf(p, lw[k * kT + t], acc[t]);
    }
#pragma unroll
    for (int off = 32; off > 0; off >>= 1)
#pragma unroll
        for (int t = 0; t < kT; ++t) acc[t] += __shfl_down(acc[t], off);
    if (l == 0) {
#pragma unroll
        for (int t = 0; t < kT; ++t) out[(long)g * kT + t] = acc[t] + lb[t];
    }
}

// ---------------------------------------------------------------------------
extern "C" void kernel_launch(void* const* d_in, const int* in_sizes, int n_in,
                              void* d_out, int out_size, void* d_ws, size_t ws_size,
                              hipStream_t stream)
{
    const float* x     = (const float*)d_in[0];
    const int*   ei    = (const int*)d_in[1];
    const int*   et    = (const int*)d_in[2];
    const int*   batch = (const int*)d_in[3];

    const float *sw[3], *sb[3], *w1[3], *gmm[3], *btm[3], *w2[3], *b2[3];
    for (int l = 0; l < 3; ++l) {
        int b = 4 + l * 8;
        sw[l]  = (const float*)d_in[b + 0];
        sb[l]  = (const float*)d_in[b + 1];
        w1[l]  = (const float*)d_in[b + 2];
        // b+3 = b1 (cancels inside BatchNorm)
        gmm[l] = (const float*)d_in[b + 4];
        btm[l] = (const float*)d_in[b + 5];
        w2[l]  = (const float*)d_in[b + 6];
        b2[l]  = (const float*)d_in[b + 7];
    }
    const float* lin_w = (const float*)d_in[28];
    const float* lin_b = (const float*)d_in[29];
    float* out = (float*)d_out;
    (void)in_sizes; (void)n_in; (void)out_size;

    // ---- workspace (~186 MB) ----
    char* wsb = (char*)d_ws;
    size_t off = 0;
    auto alloc = [&](size_t bytes) { void* p = wsb + off; off = (off + bytes + 255) & ~(size_t)255; return p; };
    bf16*  Pb0    = (bf16*) alloc((size_t)kN * 256 * 2);
    bf16*  Pb1    = (bf16*) alloc((size_t)kN * 256 * 2);
    bf16*  h1     = (bf16*) alloc((size_t)kN * 1024 * 2);
    bf16*  a1b    = (bf16*) alloc((size_t)4 * kN * 32 * 2);
    bf16*  xb1    = (bf16*) alloc((size_t)kN * 128 * 2);        // padded to 128
    bf16*  w1t    = (bf16*) alloc((size_t)2 * 4 * 65536 * 2);   // layers 2,3
    bf16*  w1tL1  = (bf16*) alloc((size_t)4 * 256 * 32 * 2);
    bf16*  Bc0    = (bf16*) alloc((size_t)256 * 1152 * 2);      // [sw_pad128 | w2]
    bf16*  Bc1    = (bf16*) alloc((size_t)256 * 1280 * 2);
    bf16*  Bc2    = (bf16*) alloc((size_t)256 * 1280 * 2);
    int*   hist   = (int*)  alloc((size_t)(kSeg + 1) * 4);
    int*   row_ptr= (int*)  alloc((size_t)(kSeg + 1) * 4);
    int*   cursor = (int*)  alloc((size_t)kSeg * 4);
    int*   srcidx = (int*)  alloc((size_t)kE * 4);
    int*   bsum   = (int*)  alloc((size_t)kScanB * 4);
    int*   boff   = (int*)  alloc((size_t)kScanB * 4);
    float* stats  = (float*)alloc(2048 * 4);
    float* scl    = (float*)alloc(1024 * 4);
    float* shf    = (float*)alloc(1024 * 4);
    float* btt    = (float*)alloc(3 * 256 * 4);
    float* pooled = (float*)alloc((size_t)kG * 256 * 4);
    float* counts = (float*)alloc(kG * 4);
    if (ws_size < off) return;  // clean absmax-fail instead of OOB crash

    const dim3 gL1((kN + 127) / 128, 4);  // l1 GEMM grid (512 thr)
    const dim3 gR((kN + 63) / 64, 4);     // rgin grid (512 thr, M-tile 64)
    const dim3 g2((kN + 63) / 64);        // GEMM2 grid (256 thr)

    // ---- CSR build (parallel scan) + weight prepack ----
    hipMemsetAsync(hist, 0, (size_t)(kSeg + 1) * 4, stream);
    k_hist<<<(kE + 255) / 256, 256, 0, stream>>>(ei, et, hist);
    k_scan1<<<kScanB, 256, 0, stream>>>(hist, bsum);
    k_scan2<<<1, 1024, 0, stream>>>(bsum, boff);
    k_scan3<<<kScanB, 256, 0, stream>>>(hist, boff, row_ptr, cursor);
    k_fill<<<(kE + 255) / 256, 256, 0, stream>>>(ei, et, cursor, srcidx);

    k_bias_total<<<3, 256, 0, stream>>>(sb[0], b2[0], sb[1], b2[1], sb[2], b2[2], btt);
    k_xpad<<<(int)(((long)kN * 128 + 255) / 256), 256, 0, stream>>>(x, xb1);
    k_wtL1<<<(4 * 256 * 32 + 255) / 256, 256, 0, stream>>>(w1[0], w1tL1);
    for (int l = 1; l < 3; ++l)
        for (int r = 0; r < 4; ++r)
            k_wt_s<<<256, 256, 0, stream>>>(w1[l] + (long)r * 65536,
                                            w1t + (long)(l - 1) * 4 * 65536 + (long)r * 65536,
                                            256, 256, 256, 0);
    hipMemsetAsync(Bc0, 0, (size_t)256 * 1152 * 2, stream);
    k_wt_s<<<(11 * 256 + 255) / 256, 256, 0, stream>>>(sw[0], Bc0, 11, 256, 1152, 0);
    k_wt_s<<<1024, 256, 0, stream>>>(w2[0], Bc0, 1024, 256, 1152, 128);
    k_wt_s<<<256, 256, 0, stream>>>(sw[1], Bc1, 256, 256, 1280, 0);
    k_wt_s<<<1024, 256, 0, stream>>>(w2[1], Bc1, 1024, 256, 1280, 256);
    k_wt_s<<<256, 256, 0, stream>>>(sw[2], Bc2, 256, 256, 1280, 0);
    k_wt_s<<<1024, 256, 0, stream>>>(w2[2], Bc2, 1024, 256, 1280, 256);

    k_counts<<<(kN + 255) / 256, 256, 0, stream>>>(batch, counts);  // counts poisoned -> must init
    hipMemsetAsync(pooled, 0, (size_t)kG * 256 * 4, stream);

    // ---------------- layer 1 ----------------
    k_agg11<<<(int)(((long)kSeg * 32 + 255) / 256), 256, 0, stream>>>(x, srcidx, row_ptr, a1b);
    hipMemsetAsync(stats, 0, 2048 * 4, stream);
    k_l1gemm<<<gL1, 512, 0, stream>>>(a1b, w1tL1, h1, stats);
    k_bn_params<<<4, 256, 0, stream>>>(stats, gmm[0], btm[0], scl, shf);
    k_gemm2<9, 1, false><<<g2, 256, 0, stream>>>(xb1, 128, h1, Bc0,
                                                 Pb0, kN, btt + 0, scl, shf, nullptr, nullptr);

    // ---------------- layer 2 ----------------
    hipMemsetAsync(stats, 0, 2048 * 4, stream);
    k_rgin1<<<gR, 512, 0, stream>>>(Pb0, srcidx, row_ptr, w1t, h1, stats);
    k_bn_params<<<4, 256, 0, stream>>>(stats, gmm[1], btm[1], scl, shf);
    k_gemm2<10, 2, false><<<g2, 256, 0, stream>>>(Pb0, 256, h1, Bc1,
                                                  Pb1, kN, btt + 256, scl, shf, nullptr, nullptr);

    // ---------------- layer 3 (pool fused into GEMM2) ----------------
    hipMemsetAsync(stats, 0, 2048 * 4, stream);
    k_rgin1<<<gR, 512, 0, stream>>>(Pb1, srcidx, row_ptr, w1t + (size_t)4 * 65536, h1, stats);
    k_bn_params<<<4, 256, 0, stream>>>(stats, gmm[2], btm[2], scl, shf);
    k_gemm2<10, 2, true><<<g2, 256, 0, stream>>>(Pb1, 256, h1, Bc2,
                                                 nullptr, kN, btt + 512, scl, shf, batch, pooled);

    // ---------------- head ----------------
    k_head<<<kG, 64, 0, stream>>>(pooled, counts, lin_w, lin_b, out);
}